// Round 2
// baseline (2333.550 us; speedup 1.0000x reference)
//
#include <hip/hip_runtime.h>
#include <hip/hip_bf16.h>
#include <math.h>

#define H_SIZE   1024
#define INTER    2048
#define NHEADS   32
#define HEAD_DIM 64
#define NSTATE   128
#define KCONV    4
#define CHUNK    256
#define CONV_DIM (INTER + 2*NSTATE)            // 2304
#define CIN_DIM  (CONV_DIM + NHEADS)           // 2336 (hBC + dt)
#define PROJ_DIM (2*INTER + 2*NSTATE + NHEADS) // 4384
#define BATCH    2
#define SEQ      4096
#define NC       (SEQ/CHUNK)                   // 16
#define EPS_F    1e-5f

// ---------------------------------------------------------------------------
// Generic C[m,n] = sum_k A[m,k] * W[n,k]   (A: MxK row-major, W: NxK row-major)
// BM=64, BN=64, BK=16, 256 threads, 4x4 micro-tile. M % 64 == 0 assumed.
// ---------------------------------------------------------------------------
__global__ __launch_bounds__(256) void gemm_nt_kernel(
    const float* __restrict__ A, const float* __restrict__ W,
    float* __restrict__ C, int M, int N, int K) {
  __shared__ float As[16][68];
  __shared__ float Ws[16][68];
  const int tid = threadIdx.x;
  const int m0 = blockIdx.y * 64;
  const int n0 = blockIdx.x * 64;
  const int ty = tid >> 4, tx = tid & 15;
  const int lr = tid >> 2;          // 0..63 (row within tile for loads)
  const int lk = (tid & 3) << 2;    // 0,4,8,12 (k within tile for loads)
  float acc[4][4] = {};
  const float* Ap = A + (size_t)(m0 + lr) * K + lk;
  const float* Wp = W + (size_t)(n0 + lr) * K + lk;
  const bool wvalid = (n0 + lr) < N;

  for (int k0 = 0; k0 < K; k0 += 16) {
    float4 av = *(const float4*)(Ap + k0);
    float4 wv = wvalid ? *(const float4*)(Wp + k0) : make_float4(0.f,0.f,0.f,0.f);
    __syncthreads();
    As[lk+0][lr] = av.x; As[lk+1][lr] = av.y; As[lk+2][lr] = av.z; As[lk+3][lr] = av.w;
    Ws[lk+0][lr] = wv.x; Ws[lk+1][lr] = wv.y; Ws[lk+2][lr] = wv.z; Ws[lk+3][lr] = wv.w;
    __syncthreads();
#pragma unroll
    for (int kk = 0; kk < 16; ++kk) {
      float4 a4 = *(const float4*)&As[kk][ty*4];
      float4 w4 = *(const float4*)&Ws[kk][tx*4];
      float ar[4] = {a4.x,a4.y,a4.z,a4.w};
      float wr[4] = {w4.x,w4.y,w4.z,w4.w};
#pragma unroll
      for (int i = 0; i < 4; ++i)
#pragma unroll
        for (int j = 0; j < 4; ++j)
          acc[i][j] = fmaf(ar[i], wr[j], acc[i][j]);
    }
  }
#pragma unroll
  for (int i = 0; i < 4; ++i) {
    int row = m0 + ty*4 + i;
    int col = n0 + tx*4;
    if (col + 3 < N) {
      *(float4*)(C + (size_t)row*N + col) =
          make_float4(acc[i][0], acc[i][1], acc[i][2], acc[i][3]);
    } else {
#pragma unroll
      for (int j = 0; j < 4; ++j)
        if (col + j < N) C[(size_t)row*N + col + j] = acc[i][j];
    }
  }
}

// ---------------------------------------------------------------------------
// Causal depthwise conv (K=4) + bias + SiLU on cin columns [0, CONV_DIM);
// softplus(cin[:, CONV_DIM + h] + dt_bias) -> dtp.
// cin row stride = CIN_DIM.
// ---------------------------------------------------------------------------
__global__ __launch_bounds__(256) void conv_kernel(
    const float* __restrict__ cin, const float* __restrict__ cw,
    const float* __restrict__ cb, const float* __restrict__ dtb,
    float* __restrict__ hbc, float* __restrict__ dtp) {
  const int bs = blockIdx.x;
  const int b = bs / SEQ, s = bs % SEQ;
  const int tid = threadIdx.x;
  const float* base = cin + (size_t)b * SEQ * CIN_DIM;
  for (int c = tid; c < CONV_DIM; c += 256) {
    float acc = cb[c];
#pragma unroll
    for (int k = 0; k < KCONV; ++k) {
      int sp = s - (KCONV-1) + k;
      if (sp >= 0) acc = fmaf(cw[c*KCONV + k], base[(size_t)sp * CIN_DIM + c], acc);
    }
    acc = acc / (1.f + expf(-acc));  // silu
    hbc[(size_t)bs * CONV_DIM + c] = acc;
  }
  if (tid < NHEADS) {
    float d = cin[(size_t)bs * CIN_DIM + CONV_DIM + tid] + dtb[tid];
    d = (d > 20.f) ? d : log1pf(expf(d));   // softplus (>=0 so clip is no-op)
    dtp[(size_t)bs * NHEADS + tid] = d;
  }
}

// ---------------------------------------------------------------------------
// Per (b,h,chunk): a[t] = dt[t]*A[h]; inclusive cumsum -> acum; g = exp(last)
// ---------------------------------------------------------------------------
__global__ __launch_bounds__(256) void cumsum_kernel(
    const float* __restrict__ dtp, const float* __restrict__ A_log,
    float* __restrict__ acum, float* __restrict__ gch) {
  const int c = blockIdx.x, h = blockIdx.y, b = blockIdx.z;
  const int tid = threadIdx.x;
  __shared__ float sm[CHUNK];
  const float A = -expf(A_log[h]);
  const int s = c * CHUNK + tid;
  float a = dtp[(size_t)(b*SEQ + s)*NHEADS + h] * A;
  sm[tid] = a;
  __syncthreads();
  for (int off = 1; off < CHUNK; off <<= 1) {
    float v = 0.f;
    if (tid >= off) v = sm[tid - off];
    __syncthreads();
    sm[tid] += v;
    __syncthreads();
  }
  float ac = sm[tid];
  acum[((size_t)(b*NHEADS + h)*NC + c)*CHUNK + tid] = ac;
  if (tid == CHUNK-1) gch[(size_t)(b*NHEADS + h)*NC + c] = expf(ac);
}

// ---------------------------------------------------------------------------
// Yd (intra-chunk) per (b, c, h, l-tile of 64 rows):
//   G[l,s] = (C_l . B_s) * exp(acum[l]-acum[s]) for l>=s;  Yd = G @ (x*dt)
//   y = Yd + D[h]*x
// ---------------------------------------------------------------------------
__global__ __launch_bounds__(256) void yd_kernel(
    const float* __restrict__ hbc, const float* __restrict__ acum,
    const float* __restrict__ dtp, const float* __restrict__ Dv,
    float* __restrict__ y) {
  const int h = blockIdx.x;
  const int c = blockIdx.y >> 2, lt = blockIdx.y & 3;
  const int b = blockIdx.z;
  const int tid = threadIdx.x;
  __shared__ float Ct[128][68];
  __shared__ float Bt[128][68];
  __shared__ float Xs[64][68];
  __shared__ float Gt[64][68];
  __shared__ float acl[64], acs[64];

  const size_t rowbase = (size_t)(b*SEQ + c*CHUNK) * CONV_DIM;
  const size_t acbase  = ((size_t)(b*NHEADS + h)*NC + c)*CHUNK;

  // stage C^T (rows lt*64.., channels 2176+n), n-major
#pragma unroll
  for (int i = 0; i < 8; ++i) {
    int f = tid + 256*i;          // 0..2047
    int l = f >> 5;               // 0..63
    int n0 = (f & 31) << 2;       // 0..124
    float4 v = *(const float4*)(hbc + rowbase + (size_t)(lt*64 + l)*CONV_DIM + (INTER + NSTATE) + n0);
    Ct[n0+0][l] = v.x; Ct[n0+1][l] = v.y; Ct[n0+2][l] = v.z; Ct[n0+3][l] = v.w;
  }
  if (tid < 64) acl[tid] = acum[acbase + lt*64 + tid];

  const int ty = tid >> 4, tx = tid & 15;
  float yd[4][4] = {};

  for (int st = 0; st <= lt; ++st) {
    __syncthreads();
    // stage B^T (rows st*64.., channels 2048+n)
#pragma unroll
    for (int i = 0; i < 8; ++i) {
      int f = tid + 256*i;
      int l = f >> 5;
      int n0 = (f & 31) << 2;
      float4 v = *(const float4*)(hbc + rowbase + (size_t)(st*64 + l)*CONV_DIM + INTER + n0);
      Bt[n0+0][l] = v.x; Bt[n0+1][l] = v.y; Bt[n0+2][l] = v.z; Bt[n0+3][l] = v.w;
    }
    // stage Xs = x * dt
#pragma unroll
    for (int i = 0; i < 4; ++i) {
      int f = tid + 256*i;        // 0..1023
      int s = f >> 4;             // 0..63
      int p0 = (f & 15) << 2;
      int sg = c*CHUNK + st*64 + s;
      float d = dtp[(size_t)(b*SEQ + sg)*NHEADS + h];
      float4 v = *(const float4*)(hbc + (size_t)(b*SEQ + sg)*CONV_DIM + h*HEAD_DIM + p0);
      *(float4*)&Xs[s][p0] = make_float4(v.x*d, v.y*d, v.z*d, v.w*d);
    }
    if (tid < 64) acs[tid] = acum[acbase + st*64 + tid];
    __syncthreads();

    // G = C_lt @ B_st^T  (64x64, K=128)
    float g[4][4] = {};
    for (int n = 0; n < 128; ++n) {
      float4 cv = *(const float4*)&Ct[n][ty*4];
      float4 bv = *(const float4*)&Bt[n][tx*4];
      float cr[4] = {cv.x,cv.y,cv.z,cv.w};
      float br[4] = {bv.x,bv.y,bv.z,bv.w};
#pragma unroll
      for (int i = 0; i < 4; ++i)
#pragma unroll
        for (int j = 0; j < 4; ++j)
          g[i][j] = fmaf(cr[i], br[j], g[i][j]);
    }
    // mask + decay, write G^T[s][l]
#pragma unroll
    for (int i = 0; i < 4; ++i) {
      int ll = ty*4 + i;
      float al = acl[ll];
#pragma unroll
      for (int j = 0; j < 4; ++j) {
        int sl = tx*4 + j;
        float val = 0.f;
        if (st < lt || ll >= sl) val = g[i][j] * expf(al - acs[sl]);
        Gt[sl][ll] = val;
      }
    }
    __syncthreads();
    // Yd += G @ Xs
    for (int s = 0; s < 64; ++s) {
      float4 g4 = *(const float4*)&Gt[s][ty*4];
      float4 x4 = *(const float4*)&Xs[s][tx*4];
      float gr[4] = {g4.x,g4.y,g4.z,g4.w};
      float xr[4] = {x4.x,x4.y,x4.z,x4.w};
#pragma unroll
      for (int i = 0; i < 4; ++i)
#pragma unroll
        for (int j = 0; j < 4; ++j)
          yd[i][j] = fmaf(gr[i], xr[j], yd[i][j]);
    }
  }

  const float Dh = Dv[h];
#pragma unroll
  for (int i = 0; i < 4; ++i) {
    int row = c*CHUNK + lt*64 + ty*4 + i;
    const float* xrow = hbc + (size_t)(b*SEQ + row)*CONV_DIM + h*HEAD_DIM;
    float* yrow = y + (size_t)(b*SEQ + row)*INTER + h*HEAD_DIM;
#pragma unroll
    for (int j = 0; j < 4; ++j) {
      int p = tx*4 + j;
      yrow[p] = yd[i][j] + Dh * xrow[p];
    }
  }
}

// ---------------------------------------------------------------------------
// states[b,c,h,p,n] = sum_l B[l,n] * exp(acum[last]-acum[l]) * dt[l] * x[l,p]
// ---------------------------------------------------------------------------
__global__ __launch_bounds__(256) void states_kernel(
    const float* __restrict__ hbc, const float* __restrict__ acum,
    const float* __restrict__ dtp, float* __restrict__ states) {
  const int h = blockIdx.x, c = blockIdx.y, b = blockIdx.z;
  const int tid = threadIdx.x;
  __shared__ float Bs[64][132];
  __shared__ float Xd[64][68];
  const int ty = tid >> 4, tx = tid & 15;
  const size_t acbase = ((size_t)(b*NHEADS + h)*NC + c)*CHUNK;
  const float aclast = acum[acbase + CHUNK - 1];
  float acc[4][8] = {};

  for (int lt = 0; lt < 4; ++lt) {
    __syncthreads();
#pragma unroll
    for (int i = 0; i < 8; ++i) {
      int f = tid + 256*i;
      int l = f >> 5, n0 = (f & 31) << 2;
      *(float4*)&Bs[l][n0] =
        *(const float4*)(hbc + (size_t)(b*SEQ + c*CHUNK + lt*64 + l)*CONV_DIM + INTER + n0);
    }
#pragma unroll
    for (int i = 0; i < 4; ++i) {
      int f = tid + 256*i;
      int s = f >> 4, p0 = (f & 15) << 2;
      int sg = c*CHUNK + lt*64 + s;
      float mult = dtp[(size_t)(b*SEQ + sg)*NHEADS + h] * expf(aclast - acum[acbase + lt*64 + s]);
      float4 v = *(const float4*)(hbc + (size_t)(b*SEQ + sg)*CONV_DIM + h*HEAD_DIM + p0);
      *(float4*)&Xd[s][p0] = make_float4(v.x*mult, v.y*mult, v.z*mult, v.w*mult);
    }
    __syncthreads();
    for (int l = 0; l < 64; ++l) {
      float4 xv = *(const float4*)&Xd[l][ty*4];
      float4 b0 = *(const float4*)&Bs[l][tx*8];
      float4 b1 = *(const float4*)&Bs[l][tx*8+4];
      float xr[4] = {xv.x,xv.y,xv.z,xv.w};
      float br[8] = {b0.x,b0.y,b0.z,b0.w,b1.x,b1.y,b1.z,b1.w};
#pragma unroll
      for (int i = 0; i < 4; ++i)
#pragma unroll
        for (int j = 0; j < 8; ++j)
          acc[i][j] = fmaf(xr[i], br[j], acc[i][j]);
    }
  }
  float* sp = states + ((size_t)(b*NC + c)*NHEADS + h)*HEAD_DIM*NSTATE;
#pragma unroll
  for (int i = 0; i < 4; ++i) {
    int p = ty*4 + i;
    *(float4*)(sp + (size_t)p*NSTATE + tx*8)     = make_float4(acc[i][0],acc[i][1],acc[i][2],acc[i][3]);
    *(float4*)(sp + (size_t)p*NSTATE + tx*8 + 4) = make_float4(acc[i][4],acc[i][5],acc[i][6],acc[i][7]);
  }
}

// ---------------------------------------------------------------------------
// Inter-chunk scan, IN PLACE: states[c] <- carry_before_c ; carry = carry*g + s
// ---------------------------------------------------------------------------
__global__ __launch_bounds__(256) void scan_kernel(
    float* __restrict__ st, const float* __restrict__ g) {
  const int bh = blockIdx.x;
  const int b = bh >> 5, h = bh & 31;
  const int tid = threadIdx.x;
  float carry[32];
#pragma unroll
  for (int i = 0; i < 32; ++i) carry[i] = 0.f;
  for (int c = 0; c < NC; ++c) {
    const float gc = g[(size_t)(b*NHEADS + h)*NC + c];
    float* base = st + ((size_t)(b*NC + c)*NHEADS + h)*HEAD_DIM*NSTATE;
#pragma unroll
    for (int i = 0; i < 32; ++i) {
      int e = i*256 + tid;
      float sv = base[e];
      base[e] = carry[i];
      carry[i] = fmaf(carry[i], gc, sv);
    }
  }
}

// ---------------------------------------------------------------------------
// Yo per (b,c,h,l-tile): y += exp(acum[l]) * (C_lt @ prev^T)
// ---------------------------------------------------------------------------
__global__ __launch_bounds__(256) void yo_kernel(
    const float* __restrict__ hbc, const float* __restrict__ acum,
    const float* __restrict__ prev, float* __restrict__ y) {
  const int h = blockIdx.x;
  const int c = blockIdx.y >> 2, lt = blockIdx.y & 3;
  const int b = blockIdx.z;
  const int tid = threadIdx.x;
  __shared__ float Ct[128][68];
  __shared__ float Pt[128][68];
  const size_t acbase = ((size_t)(b*NHEADS + h)*NC + c)*CHUNK;

#pragma unroll
  for (int i = 0; i < 8; ++i) {
    int f = tid + 256*i;
    int l = f >> 5, n0 = (f & 31) << 2;
    float e = expf(acum[acbase + lt*64 + l]);
    float4 v = *(const float4*)(hbc + (size_t)(b*SEQ + c*CHUNK + lt*64 + l)*CONV_DIM + (INTER + NSTATE) + n0);
    Ct[n0+0][l] = v.x*e; Ct[n0+1][l] = v.y*e; Ct[n0+2][l] = v.z*e; Ct[n0+3][l] = v.w*e;
  }
  const float* pv = prev + ((size_t)(b*NC + c)*NHEADS + h)*HEAD_DIM*NSTATE;
#pragma unroll
  for (int i = 0; i < 8; ++i) {
    int f = tid + 256*i;
    int p = f >> 5, n0 = (f & 31) << 2;
    float4 v = *(const float4*)(pv + (size_t)p*NSTATE + n0);
    Pt[n0+0][p] = v.x; Pt[n0+1][p] = v.y; Pt[n0+2][p] = v.z; Pt[n0+3][p] = v.w;
  }
  __syncthreads();
  const int ty = tid >> 4, tx = tid & 15;
  float yo[4][4] = {};
  for (int n = 0; n < 128; ++n) {
    float4 cv = *(const float4*)&Ct[n][ty*4];
    float4 p4 = *(const float4*)&Pt[n][tx*4];
    float cr[4] = {cv.x,cv.y,cv.z,cv.w};
    float pr[4] = {p4.x,p4.y,p4.z,p4.w};
#pragma unroll
    for (int i = 0; i < 4; ++i)
#pragma unroll
      for (int j = 0; j < 4; ++j)
        yo[i][j] = fmaf(cr[i], pr[j], yo[i][j]);
  }
#pragma unroll
  for (int i = 0; i < 4; ++i) {
    int row = c*CHUNK + lt*64 + ty*4 + i;
    float* yrow = y + (size_t)(b*SEQ + row)*INTER + h*HEAD_DIM + tx*4;
#pragma unroll
    for (int j = 0; j < 4; ++j) yrow[j] += yo[i][j];
  }
}

// ---------------------------------------------------------------------------
// Gated RMSNorm, IN PLACE on y: yf = y * silu(gate);
// y <- norm_w * yf * rsqrt(mean(yf^2)+eps).  gate row stride = INTER.
// ---------------------------------------------------------------------------
__global__ __launch_bounds__(256) void rms_kernel(
    float* __restrict__ y, const float* __restrict__ gate,
    const float* __restrict__ norm_w) {
  const int bs = blockIdx.x;
  const int tid = threadIdx.x;
  float* yrow = y + (size_t)bs * INTER;
  const float* grow = gate + (size_t)bs * INTER;
  float yf[8];
  float ss = 0.f;
#pragma unroll
  for (int i = 0; i < 8; ++i) {
    int c = tid + i*256;
    float v = yrow[c];
    float gt = grow[c];
    float f = v * (gt / (1.f + expf(-gt)));
    yf[i] = f;
    ss += f*f;
  }
#pragma unroll
  for (int off = 32; off >= 1; off >>= 1) ss += __shfl_xor(ss, off, 64);
  __shared__ float red[4];
  if ((tid & 63) == 0) red[tid >> 6] = ss;
  __syncthreads();
  float total = red[0] + red[1] + red[2] + red[3];
  float sc = rsqrtf(total * (1.f/INTER) + EPS_F);
#pragma unroll
  for (int i = 0; i < 8; ++i) {
    int c = tid + i*256;
    yrow[c] = norm_w[c] * yf[i] * sc;
  }
}

// Fallback: clean zero output instead of a fault if ws is too small.
__global__ void zero_kernel(float* p, size_t n) {
  size_t i = (size_t)blockIdx.x * blockDim.x + threadIdx.x;
  if (i < n) p[i] = 0.f;
}

// ---------------------------------------------------------------------------
extern "C" void kernel_launch(void* const* d_in, const int* in_sizes, int n_in,
                              void* d_out, int out_size, void* d_ws, size_t ws_size,
                              hipStream_t stream) {
  const float* hidden = (const float*)d_in[0];
  const float* in_w   = (const float*)d_in[1];
  const float* conv_w = (const float*)d_in[2];
  const float* conv_b = (const float*)d_in[3];
  const float* dt_b   = (const float*)d_in[4];
  const float* A_log  = (const float*)d_in[5];
  const float* Dv     = (const float*)d_in[6];
  const float* norm_w = (const float*)d_in[7];
  const float* out_w  = (const float*)d_in[8];
  float* out = (float*)d_out;

  const int M = BATCH*SEQ;

  // Workspace layout (floats). Peak ~180 MB.
  const size_t sz_cin  = (size_t)M * CIN_DIM;     // 19,136,512 (cin; later aliased by y)
  const size_t sz_hbc  = (size_t)M * CONV_DIM;    // 18,874,368 (hbc; later aliased by gate)
  const size_t sz_dtp  = (size_t)M * NHEADS;
  const size_t sz_acum = (size_t)BATCH*NHEADS*NC*CHUNK;
  const size_t sz_gch  = (size_t)BATCH*NHEADS*NC;
  const size_t sz_st   = (size_t)BATCH*NC*NHEADS*HEAD_DIM*NSTATE;
  const size_t need = (sz_cin + sz_hbc + sz_dtp + sz_acum + sz_gch + sz_st) * sizeof(float);

  if (ws_size < need) {  // can't run safely: emit zeros (clean absmax failure, no fault)
    size_t n = (size_t)out_size;
    zero_kernel<<<(unsigned)((n + 255) / 256), 256, 0, stream>>>(out, n);
    return;
  }

  float* ws = (float*)d_ws;
  size_t o = 0;
  float* cin  = ws + o; o += sz_cin;
  float* hbc  = ws + o; o += sz_hbc;
  float* dtp  = ws + o; o += sz_dtp;
  float* acum = ws + o; o += sz_acum;
  float* gch  = ws + o; o += sz_gch;
  float* st   = ws + o; o += sz_st;
  float* y    = cin;   // cin dead after conv_kernel; y (M*INTER) fits in cin (M*2336)
  float* gate = hbc;   // hbc dead after yo_kernel; gate (M*INTER) fits in hbc (M*2304)

  // 1) conv-input columns of in_proj: W rows [INTER, PROJ_DIM) -> cin[M, 2336]
  gemm_nt_kernel<<<dim3((CIN_DIM+63)/64, M/64), 256, 0, stream>>>(
      hidden, in_w + (size_t)INTER * H_SIZE, cin, M, CIN_DIM, H_SIZE);
  // 2) causal conv + SiLU; softplus(dt)
  conv_kernel<<<dim3(M), 256, 0, stream>>>(cin, conv_w, conv_b, dt_b, hbc, dtp);
  // 3) per-chunk cumsum of dt*A
  cumsum_kernel<<<dim3(NC, NHEADS, BATCH), 256, 0, stream>>>(dtp, A_log, acum, gch);
  // 4) intra-chunk Yd + D*x -> y (overwrites cin region)
  yd_kernel<<<dim3(NHEADS, NC*4, BATCH), 256, 0, stream>>>(hbc, acum, dtp, Dv, y);
  // 5) chunk states
  states_kernel<<<dim3(NHEADS, NC, BATCH), 256, 0, stream>>>(hbc, acum, dtp, st);
  // 6) inter-chunk scan (in place: st[c] <- state before chunk c)
  scan_kernel<<<dim3(BATCH*NHEADS), 256, 0, stream>>>(st, gch);
  // 7) inter-chunk contribution Yo -> y (+=)
  yo_kernel<<<dim3(NHEADS, NC*4, BATCH), 256, 0, stream>>>(hbc, acum, st, y);
  // 8) gate columns of in_proj (W rows [0, INTER)) -> gate (overwrites hbc region)
  gemm_nt_kernel<<<dim3(INTER/64, M/64), 256, 0, stream>>>(
      hidden, in_w, gate, M, INTER, H_SIZE);
  // 9) gated RMSNorm in place on y
  rms_kernel<<<dim3(M), 256, 0, stream>>>(y, gate, norm_w);
  // 10) out_proj
  gemm_nt_kernel<<<dim3(H_SIZE/64, M/64), 256, 0, stream>>>(
      y, out_w, out, M, H_SIZE, INTER);
}

// Round 6
// 1237.916 us; speedup vs baseline: 1.8851x; 1.8851x over previous
//
#include <hip/hip_runtime.h>
#include <hip/hip_bf16.h>
#include <math.h>

#define H_SIZE   1024
#define INTER    2048
#define NHEADS   32
#define HEAD_DIM 64
#define NSTATE   128
#define KCONV    4
#define CHUNK    256
#define CONV_DIM (INTER + 2*NSTATE)            // 2304
#define CIN_DIM  (CONV_DIM + NHEADS)           // 2336 (hBC + dt)
#define PROJ_DIM (2*INTER + 2*NSTATE + NHEADS) // 4384
#define BATCH    2
#define SEQ      4096
#define NC       (SEQ/CHUNK)                   // 16
#define EPS_F    1e-5f

typedef __attribute__((ext_vector_type(8))) short bf16x8;   // 8 bf16 in 4 VGPRs
typedef __attribute__((ext_vector_type(4))) float f32x4;
typedef unsigned short ushort_t;

__device__ __forceinline__ ushort_t f2bf(float x) {   // RNE float->bf16 bits
  unsigned u = __float_as_uint(x);
  u += 0x7fffu + ((u >> 16) & 1u);
  return (ushort_t)(u >> 16);
}

// ---------------------------------------------------------------------------
// Split fp32 x into hi+lo bf16 planes: x ~= hi + lo (rel err ~2^-17).
// n4 = element count / 4.
// ---------------------------------------------------------------------------
__global__ __launch_bounds__(256) void convert_hl_kernel(
    const float* __restrict__ x, ushort_t* __restrict__ hi,
    ushort_t* __restrict__ lo, int n4) {
  int idx = blockIdx.x * 256 + threadIdx.x;
  int stride = gridDim.x * 256;
  for (int i = idx; i < n4; i += stride) {
    const float* p = x + (size_t)i * 4;
    float v0 = p[0], v1 = p[1], v2 = p[2], v3 = p[3];
    ushort_t h0 = f2bf(v0), h1 = f2bf(v1), h2 = f2bf(v2), h3 = f2bf(v3);
    ushort_t l0 = f2bf(v0 - __uint_as_float((unsigned)h0 << 16));
    ushort_t l1 = f2bf(v1 - __uint_as_float((unsigned)h1 << 16));
    ushort_t l2 = f2bf(v2 - __uint_as_float((unsigned)h2 << 16));
    ushort_t l3 = f2bf(v3 - __uint_as_float((unsigned)h3 << 16));
    *(uint2*)(hi + (size_t)i * 4) =
        make_uint2((unsigned)h0 | ((unsigned)h1 << 16), (unsigned)h2 | ((unsigned)h3 << 16));
    *(uint2*)(lo + (size_t)i * 4) =
        make_uint2((unsigned)l0 | ((unsigned)l1 << 16), (unsigned)l2 | ((unsigned)l3 << 16));
  }
}

// ---------------------------------------------------------------------------
// C[m,n] = sum_k A[m,k]*W[n,k] via split-bf16 MFMA (hi*hi + hi*lo + lo*hi).
// A,W given as pre-split bf16 hi/lo planes (row-major, K contiguous).
// 128x128 tile, BK=32, 256 threads = 4 waves (2x2), wave tile 64x64.
// M % 128 == 0, K % 32 == 0; N tail guarded.
// ---------------------------------------------------------------------------
#define LROW 40   // LDS row stride in ushorts (80 B = 5x16B: uniform bank spread)
__global__ __launch_bounds__(256) void gemm_hl_mfma_kernel(
    const ushort_t* __restrict__ Ahi, const ushort_t* __restrict__ Alo,
    const ushort_t* __restrict__ Whi, const ushort_t* __restrict__ Wlo,
    float* __restrict__ C, int M, int N, int K) {
  __shared__ __align__(16) ushort_t Ah[128*LROW], Al[128*LROW];
  __shared__ __align__(16) ushort_t Wh[128*LROW], Wl[128*LROW];
  const int tid = threadIdx.x;
  const int lane = tid & 63, wid = tid >> 6;
  const int wr = wid >> 1, wc = wid & 1;         // wave grid 2x2
  const int fr = lane & 15, fg = lane >> 4;      // fragment row / k-group
  const int m0 = blockIdx.y * 128, n0 = blockIdx.x * 128;

  // staging map: thread -> rows (r0, r0+64), k-segment of 8 ushorts
  const int r0 = tid >> 2;                       // 0..63
  const int kseg = (tid & 3) * 8;                // 0,8,16,24
  const int r1 = r0 + 64;
  const size_t a0 = (size_t)(m0 + r0) * K + kseg;
  const size_t a1 = (size_t)(m0 + r1) * K + kseg;
  const size_t w0 = (size_t)(n0 + r0) * K + kseg;
  const size_t w1 = (size_t)(n0 + r1) * K + kseg;
  const bool wv0 = (n0 + r0) < N, wv1 = (n0 + r1) < N;

  bf16x8 gA0, gA1, gAl0, gAl1, gW0, gW1, gWl0, gWl1;
  const bf16x8 z8 = {};
  f32x4 acc[4][4] = {};

  auto glod = [&](int k0) {
    gA0  = *(const bf16x8*)(Ahi + a0 + k0);
    gA1  = *(const bf16x8*)(Ahi + a1 + k0);
    gAl0 = *(const bf16x8*)(Alo + a0 + k0);
    gAl1 = *(const bf16x8*)(Alo + a1 + k0);
    gW0  = wv0 ? *(const bf16x8*)(Whi + w0 + k0) : z8;
    gW1  = wv1 ? *(const bf16x8*)(Whi + w1 + k0) : z8;
    gWl0 = wv0 ? *(const bf16x8*)(Wlo + w0 + k0) : z8;
    gWl1 = wv1 ? *(const bf16x8*)(Wlo + w1 + k0) : z8;
  };

  glod(0);
  for (int k0 = 0; k0 < K; k0 += 32) {
    __syncthreads();
    *(bf16x8*)&Ah[r0*LROW + kseg] = gA0;
    *(bf16x8*)&Ah[r1*LROW + kseg] = gA1;
    *(bf16x8*)&Al[r0*LROW + kseg] = gAl0;
    *(bf16x8*)&Al[r1*LROW + kseg] = gAl1;
    *(bf16x8*)&Wh[r0*LROW + kseg] = gW0;
    *(bf16x8*)&Wh[r1*LROW + kseg] = gW1;
    *(bf16x8*)&Wl[r0*LROW + kseg] = gWl0;
    *(bf16x8*)&Wl[r1*LROW + kseg] = gWl1;
    __syncthreads();
    if (k0 + 32 < K) glod(k0 + 32);   // prefetch next tile (hides HBM under MFMA)

    bf16x8 wh[4], wl[4];
#pragma unroll
    for (int nf = 0; nf < 4; ++nf) {
      int off = (wc*64 + nf*16 + fr) * LROW + 8*fg;
      wh[nf] = *(const bf16x8*)&Wh[off];
      wl[nf] = *(const bf16x8*)&Wl[off];
    }
#pragma unroll
    for (int mf = 0; mf < 4; ++mf) {
      int aoff = (wr*64 + mf*16 + fr) * LROW + 8*fg;
      bf16x8 ah = *(const bf16x8*)&Ah[aoff];
      bf16x8 al = *(const bf16x8*)&Al[aoff];
#pragma unroll
      for (int nf = 0; nf < 4; ++nf) {
        acc[mf][nf] = __builtin_amdgcn_mfma_f32_16x16x32_bf16(ah, wh[nf], acc[mf][nf], 0, 0, 0);
        acc[mf][nf] = __builtin_amdgcn_mfma_f32_16x16x32_bf16(ah, wl[nf], acc[mf][nf], 0, 0, 0);
        acc[mf][nf] = __builtin_amdgcn_mfma_f32_16x16x32_bf16(al, wh[nf], acc[mf][nf], 0, 0, 0);
      }
    }
  }

  // C/D layout (m89-verified): col = lane&15, row = (lane>>4)*4 + reg
#pragma unroll
  for (int mf = 0; mf < 4; ++mf)
#pragma unroll
    for (int nf = 0; nf < 4; ++nf) {
      int col = n0 + wc*64 + nf*16 + fr;
      if (col < N) {
        size_t base = (size_t)(m0 + wr*64 + mf*16 + fg*4) * N + col;
        f32x4 v = acc[mf][nf];
        C[base]               = v[0];
        C[base + (size_t)N]   = v[1];
        C[base + 2*(size_t)N] = v[2];
        C[base + 3*(size_t)N] = v[3];
      }
    }
}

// ---------------------------------------------------------------------------
// Causal depthwise conv (K=4) + bias + SiLU; softplus(dt + dt_bias).
// ---------------------------------------------------------------------------
__global__ __launch_bounds__(256) void conv_kernel(
    const float* __restrict__ cin, const float* __restrict__ cw,
    const float* __restrict__ cb, const float* __restrict__ dtb,
    float* __restrict__ hbc, float* __restrict__ dtp) {
  const int bs = blockIdx.x;
  const int b = bs / SEQ, s = bs % SEQ;
  const int tid = threadIdx.x;
  const float* base = cin + (size_t)b * SEQ * CIN_DIM;
  for (int c = tid; c < CONV_DIM; c += 256) {
    float acc = cb[c];
#pragma unroll
    for (int k = 0; k < KCONV; ++k) {
      int sp = s - (KCONV-1) + k;
      if (sp >= 0) acc = fmaf(cw[c*KCONV + k], base[(size_t)sp * CIN_DIM + c], acc);
    }
    acc = acc / (1.f + expf(-acc));  // silu
    hbc[(size_t)bs * CONV_DIM + c] = acc;
  }
  if (tid < NHEADS) {
    float d = cin[(size_t)bs * CIN_DIM + CONV_DIM + tid] + dtb[tid];
    d = (d > 20.f) ? d : log1pf(expf(d));   // softplus
    dtp[(size_t)bs * NHEADS + tid] = d;
  }
}

// ---------------------------------------------------------------------------
__global__ __launch_bounds__(256) void cumsum_kernel(
    const float* __restrict__ dtp, const float* __restrict__ A_log,
    float* __restrict__ acum, float* __restrict__ gch) {
  const int c = blockIdx.x, h = blockIdx.y, b = blockIdx.z;
  const int tid = threadIdx.x;
  __shared__ float sm[CHUNK];
  const float A = -expf(A_log[h]);
  const int s = c * CHUNK + tid;
  float a = dtp[(size_t)(b*SEQ + s)*NHEADS + h] * A;
  sm[tid] = a;
  __syncthreads();
  for (int off = 1; off < CHUNK; off <<= 1) {
    float v = 0.f;
    if (tid >= off) v = sm[tid - off];
    __syncthreads();
    sm[tid] += v;
    __syncthreads();
  }
  float ac = sm[tid];
  acum[((size_t)(b*NHEADS + h)*NC + c)*CHUNK + tid] = ac;
  if (tid == CHUNK-1) gch[(size_t)(b*NHEADS + h)*NC + c] = expf(ac);
}

// ---------------------------------------------------------------------------
__global__ __launch_bounds__(256) void yd_kernel(
    const float* __restrict__ hbc, const float* __restrict__ acum,
    const float* __restrict__ dtp, const float* __restrict__ Dv,
    float* __restrict__ y) {
  const int h = blockIdx.x;
  const int c = blockIdx.y >> 2, lt = blockIdx.y & 3;
  const int b = blockIdx.z;
  const int tid = threadIdx.x;
  __shared__ float Ct[128][68];
  __shared__ float Bt[128][68];
  __shared__ float Xs[64][68];
  __shared__ float Gt[64][68];
  __shared__ float acl[64], acs[64];

  const size_t rowbase = (size_t)(b*SEQ + c*CHUNK) * CONV_DIM;
  const size_t acbase  = ((size_t)(b*NHEADS + h)*NC + c)*CHUNK;

#pragma unroll
  for (int i = 0; i < 8; ++i) {
    int f = tid + 256*i;
    int l = f >> 5;
    int n0 = (f & 31) << 2;
    float4 v = *(const float4*)(hbc + rowbase + (size_t)(lt*64 + l)*CONV_DIM + (INTER + NSTATE) + n0);
    Ct[n0+0][l] = v.x; Ct[n0+1][l] = v.y; Ct[n0+2][l] = v.z; Ct[n0+3][l] = v.w;
  }
  if (tid < 64) acl[tid] = acum[acbase + lt*64 + tid];

  const int ty = tid >> 4, tx = tid & 15;
  float yd[4][4] = {};

  for (int st = 0; st <= lt; ++st) {
    __syncthreads();
#pragma unroll
    for (int i = 0; i < 8; ++i) {
      int f = tid + 256*i;
      int l = f >> 5;
      int n0 = (f & 31) << 2;
      float4 v = *(const float4*)(hbc + rowbase + (size_t)(st*64 + l)*CONV_DIM + INTER + n0);
      Bt[n0+0][l] = v.x; Bt[n0+1][l] = v.y; Bt[n0+2][l] = v.z; Bt[n0+3][l] = v.w;
    }
#pragma unroll
    for (int i = 0; i < 4; ++i) {
      int f = tid + 256*i;
      int s = f >> 4;
      int p0 = (f & 15) << 2;
      int sg = c*CHUNK + st*64 + s;
      float d = dtp[(size_t)(b*SEQ + sg)*NHEADS + h];
      float4 v = *(const float4*)(hbc + (size_t)(b*SEQ + sg)*CONV_DIM + h*HEAD_DIM + p0);
      *(float4*)&Xs[s][p0] = make_float4(v.x*d, v.y*d, v.z*d, v.w*d);
    }
    if (tid < 64) acs[tid] = acum[acbase + st*64 + tid];
    __syncthreads();

    float g[4][4] = {};
    for (int n = 0; n < 128; ++n) {
      float4 cv = *(const float4*)&Ct[n][ty*4];
      float4 bv = *(const float4*)&Bt[n][tx*4];
      float cr[4] = {cv.x,cv.y,cv.z,cv.w};
      float br[4] = {bv.x,bv.y,bv.z,bv.w};
#pragma unroll
      for (int i = 0; i < 4; ++i)
#pragma unroll
        for (int j = 0; j < 4; ++j)
          g[i][j] = fmaf(cr[i], br[j], g[i][j]);
    }
#pragma unroll
    for (int i = 0; i < 4; ++i) {
      int ll = ty*4 + i;
      float al = acl[ll];
#pragma unroll
      for (int j = 0; j < 4; ++j) {
        int sl = tx*4 + j;
        float val = 0.f;
        if (st < lt || ll >= sl) val = g[i][j] * expf(al - acs[sl]);
        Gt[sl][ll] = val;
      }
    }
    __syncthreads();
    for (int s = 0; s < 64; ++s) {
      float4 g4 = *(const float4*)&Gt[s][ty*4];
      float4 x4 = *(const float4*)&Xs[s][tx*4];
      float gr[4] = {g4.x,g4.y,g4.z,g4.w};
      float xr[4] = {x4.x,x4.y,x4.z,x4.w};
#pragma unroll
      for (int i = 0; i < 4; ++i)
#pragma unroll
        for (int j = 0; j < 4; ++j)
          yd[i][j] = fmaf(gr[i], xr[j], yd[i][j]);
    }
  }

  const float Dh = Dv[h];
#pragma unroll
  for (int i = 0; i < 4; ++i) {
    int row = c*CHUNK + lt*64 + ty*4 + i;
    const float* xrow = hbc + (size_t)(b*SEQ + row)*CONV_DIM + h*HEAD_DIM;
    float* yrow = y + (size_t)(b*SEQ + row)*INTER + h*HEAD_DIM;
#pragma unroll
    for (int j = 0; j < 4; ++j) {
      int p = tx*4 + j;
      yrow[p] = yd[i][j] + Dh * xrow[p];
    }
  }
}

// ---------------------------------------------------------------------------
__global__ __launch_bounds__(256) void states_kernel(
    const float* __restrict__ hbc, const float* __restrict__ acum,
    const float* __restrict__ dtp, float* __restrict__ states) {
  const int h = blockIdx.x, c = blockIdx.y, b = blockIdx.z;
  const int tid = threadIdx.x;
  __shared__ float Bs[64][132];
  __shared__ float Xd[64][68];
  const int ty = tid >> 4, tx = tid & 15;
  const size_t acbase = ((size_t)(b*NHEADS + h)*NC + c)*CHUNK;
  const float aclast = acum[acbase + CHUNK - 1];
  float acc[4][8] = {};

  for (int lt = 0; lt < 4; ++lt) {
    __syncthreads();
#pragma unroll
    for (int i = 0; i < 8; ++i) {
      int f = tid + 256*i;
      int l = f >> 5, n0 = (f & 31) << 2;
      *(float4*)&Bs[l][n0] =
        *(const float4*)(hbc + (size_t)(b*SEQ + c*CHUNK + lt*64 + l)*CONV_DIM + INTER + n0);
    }
#pragma unroll
    for (int i = 0; i < 4; ++i) {
      int f = tid + 256*i;
      int s = f >> 4, p0 = (f & 15) << 2;
      int sg = c*CHUNK + lt*64 + s;
      float mult = dtp[(size_t)(b*SEQ + sg)*NHEADS + h] * expf(aclast - acum[acbase + lt*64 + s]);
      float4 v = *(const float4*)(hbc + (size_t)(b*SEQ + sg)*CONV_DIM + h*HEAD_DIM + p0);
      *(float4*)&Xd[s][p0] = make_float4(v.x*mult, v.y*mult, v.z*mult, v.w*mult);
    }
    __syncthreads();
    for (int l = 0; l < 64; ++l) {
      float4 xv = *(const float4*)&Xd[l][ty*4];
      float4 b0 = *(const float4*)&Bs[l][tx*8];
      float4 b1 = *(const float4*)&Bs[l][tx*8+4];
      float xr[4] = {xv.x,xv.y,xv.z,xv.w};
      float br[8] = {b0.x,b0.y,b0.z,b0.w,b1.x,b1.y,b1.z,b1.w};
#pragma unroll
      for (int i = 0; i < 4; ++i)
#pragma unroll
        for (int j = 0; j < 8; ++j)
          acc[i][j] = fmaf(xr[i], br[j], acc[i][j]);
    }
  }
  float* sp = states + ((size_t)(b*NC + c)*NHEADS + h)*HEAD_DIM*NSTATE;
#pragma unroll
  for (int i = 0; i < 4; ++i) {
    int p = ty*4 + i;
    *(float4*)(sp + (size_t)p*NSTATE + tx*8)     = make_float4(acc[i][0],acc[i][1],acc[i][2],acc[i][3]);
    *(float4*)(sp + (size_t)p*NSTATE + tx*8 + 4) = make_float4(acc[i][4],acc[i][5],acc[i][6],acc[i][7]);
  }
}

// ---------------------------------------------------------------------------
__global__ __launch_bounds__(256) void scan_kernel(
    float* __restrict__ st, const float* __restrict__ g) {
  const int bh = blockIdx.x;
  const int b = bh >> 5, h = bh & 31;
  const int tid = threadIdx.x;
  float carry[32];
#pragma unroll
  for (int i = 0; i < 32; ++i) carry[i] = 0.f;
  for (int c = 0; c < NC; ++c) {
    const float gc = g[(size_t)(b*NHEADS + h)*NC + c];
    float* base = st + ((size_t)(b*NC + c)*NHEADS + h)*HEAD_DIM*NSTATE;
#pragma unroll
    for (int i = 0; i < 32; ++i) {
      int e = i*256 + tid;
      float sv = base[e];
      base[e] = carry[i];
      carry[i] = fmaf(carry[i], gc, sv);
    }
  }
}

// ---------------------------------------------------------------------------
__global__ __launch_bounds__(256) void yo_kernel(
    const float* __restrict__ hbc, const float* __restrict__ acum,
    const float* __restrict__ prev, float* __restrict__ y) {
  const int h = blockIdx.x;
  const int c = blockIdx.y >> 2, lt = blockIdx.y & 3;
  const int b = blockIdx.z;
  const int tid = threadIdx.x;
  __shared__ float Ct[128][68];
  __shared__ float Pt[128][68];
  const size_t acbase = ((size_t)(b*NHEADS + h)*NC + c)*CHUNK;

#pragma unroll
  for (int i = 0; i < 8; ++i) {
    int f = tid + 256*i;
    int l = f >> 5, n0 = (f & 31) << 2;
    float e = expf(acum[acbase + lt*64 + l]);
    float4 v = *(const float4*)(hbc + (size_t)(b*SEQ + c*CHUNK + lt*64 + l)*CONV_DIM + (INTER + NSTATE) + n0);
    Ct[n0+0][l] = v.x*e; Ct[n0+1][l] = v.y*e; Ct[n0+2][l] = v.z*e; Ct[n0+3][l] = v.w*e;
  }
  const float* pv = prev + ((size_t)(b*NC + c)*NHEADS + h)*HEAD_DIM*NSTATE;
#pragma unroll
  for (int i = 0; i < 8; ++i) {
    int f = tid + 256*i;
    int p = f >> 5, n0 = (f & 31) << 2;
    float4 v = *(const float4*)(pv + (size_t)p*NSTATE + n0);
    Pt[n0+0][p] = v.x; Pt[n0+1][p] = v.y; Pt[n0+2][p] = v.z; Pt[n0+3][p] = v.w;
  }
  __syncthreads();
  const int ty = tid >> 4, tx = tid & 15;
  float yo[4][4] = {};
  for (int n = 0; n < 128; ++n) {
    float4 cv = *(const float4*)&Ct[n][ty*4];
    float4 p4 = *(const float4*)&Pt[n][tx*4];
    float cr[4] = {cv.x,cv.y,cv.z,cv.w};
    float pr[4] = {p4.x,p4.y,p4.z,p4.w};
#pragma unroll
    for (int i = 0; i < 4; ++i)
#pragma unroll
      for (int j = 0; j < 4; ++j)
        yo[i][j] = fmaf(cr[i], pr[j], yo[i][j]);
  }
#pragma unroll
  for (int i = 0; i < 4; ++i) {
    int row = c*CHUNK + lt*64 + ty*4 + i;
    float* yrow = y + (size_t)(b*SEQ + row)*INTER + h*HEAD_DIM + tx*4;
#pragma unroll
    for (int j = 0; j < 4; ++j) yrow[j] += yo[i][j];
  }
}

// ---------------------------------------------------------------------------
__global__ __launch_bounds__(256) void rms_kernel(
    float* __restrict__ y, const float* __restrict__ gate,
    const float* __restrict__ norm_w) {
  const int bs = blockIdx.x;
  const int tid = threadIdx.x;
  float* yrow = y + (size_t)bs * INTER;
  const float* grow = gate + (size_t)bs * INTER;
  float yf[8];
  float ss = 0.f;
#pragma unroll
  for (int i = 0; i < 8; ++i) {
    int c = tid + i*256;
    float v = yrow[c];
    float gt = grow[c];
    float f = v * (gt / (1.f + expf(-gt)));
    yf[i] = f;
    ss += f*f;
  }
#pragma unroll
  for (int off = 32; off >= 1; off >>= 1) ss += __shfl_xor(ss, off, 64);
  __shared__ float red[4];
  if ((tid & 63) == 0) red[tid >> 6] = ss;
  __syncthreads();
  float total = red[0] + red[1] + red[2] + red[3];
  float sc = rsqrtf(total * (1.f/INTER) + EPS_F);
#pragma unroll
  for (int i = 0; i < 8; ++i) {
    int c = tid + i*256;
    yrow[c] = norm_w[c] * yf[i] * sc;
  }
}

__global__ void zero_kernel(float* p, size_t n) {
  size_t i = (size_t)blockIdx.x * blockDim.x + threadIdx.x;
  if (i < n) p[i] = 0.f;
}

// ---------------------------------------------------------------------------
extern "C" void kernel_launch(void* const* d_in, const int* in_sizes, int n_in,
                              void* d_out, int out_size, void* d_ws, size_t ws_size,
                              hipStream_t stream) {
  const float* hidden = (const float*)d_in[0];
  const float* in_w   = (const float*)d_in[1];
  const float* conv_w = (const float*)d_in[2];
  const float* conv_b = (const float*)d_in[3];
  const float* dt_b   = (const float*)d_in[4];
  const float* A_log  = (const float*)d_in[5];
  const float* Dv     = (const float*)d_in[6];
  const float* norm_w = (const float*)d_in[7];
  const float* out_w  = (const float*)d_in[8];
  float* out = (float*)d_out;

  const int M = BATCH*SEQ;

  // Workspace (floats). Peak == round-2's proven-safe 188 MB.
  const size_t sz_cin  = (size_t)M * CIN_DIM;                     // y aliases later
  const size_t sz_hbc  = (size_t)M * CONV_DIM;                    // gate/yHL alias later
  const size_t sz_dtp  = (size_t)M * NHEADS;
  const size_t sz_acum = (size_t)BATCH*NHEADS*NC*CHUNK;
  const size_t sz_gch  = (size_t)BATCH*NHEADS*NC;
  const size_t sz_R    = (size_t)BATCH*NC*NHEADS*HEAD_DIM*NSTATE; // st / hiddenHL union
  const size_t need = (sz_cin + sz_hbc + sz_dtp + sz_acum + sz_gch + sz_R) * sizeof(float);

  if (ws_size < need) {
    size_t n = (size_t)out_size;
    zero_kernel<<<(unsigned)((n + 255) / 256), 256, 0, stream>>>(out, n);
    return;
  }

  float* ws = (float*)d_ws;
  size_t o = 0;
  float* cin  = ws + o; o += sz_cin;
  float* hbc  = ws + o; o += sz_hbc;
  float* dtp  = ws + o; o += sz_dtp;
  float* acum = ws + o; o += sz_acum;
  float* gch  = ws + o; o += sz_gch;
  float* R    = ws + o; o += sz_R;

  float* y    = cin;   // cin dead after conv_kernel
  float* gate = hbc;   // hbc dead after yo_kernel
  float* st   = R;     // R free between gemms (hiddenHL dead after each gemm)

  ushort_t* hidhi = (ushort_t*)R;                    // fills R exactly (hi+lo)
  ushort_t* hidlo = hidhi + (size_t)M * H_SIZE;
  ushort_t* yhi   = (ushort_t*)hbc;                  // out_proj A planes (hbc dead post-rms)
  ushort_t* ylo   = yhi + (size_t)M * INTER;

  // Weight hi/lo staging: d_out (33.5 MB scratch, re-poisoned by harness,
  // fully overwritten by step 10) for gemms 1 and 8; R region for gemm 10.
  ushort_t* wscr  = (ushort_t*)out;

  // 1) in_proj conv-input columns: rows [INTER, INTER+CIN_DIM) of in_w
  {
    int nA4 = (M * H_SIZE) / 4;
    int nW  = CIN_DIM * H_SIZE;                      // 2.39M el; hi+lo = 9.6 MB in d_out
    convert_hl_kernel<<<2048, 256, 0, stream>>>(hidden, hidhi, hidlo, nA4);
    convert_hl_kernel<<<2048, 256, 0, stream>>>(in_w + (size_t)INTER*H_SIZE, wscr, wscr + nW, nW/4);
    gemm_hl_mfma_kernel<<<dim3((CIN_DIM+127)/128, M/128), 256, 0, stream>>>(
        hidhi, hidlo, wscr, wscr + nW, cin, M, CIN_DIM, H_SIZE);
  }
  // 2) causal conv + SiLU; softplus(dt)
  conv_kernel<<<dim3(M), 256, 0, stream>>>(cin, conv_w, conv_b, dt_b, hbc, dtp);
  // 3) per-chunk cumsum of dt*A
  cumsum_kernel<<<dim3(NC, NHEADS, BATCH), 256, 0, stream>>>(dtp, A_log, acum, gch);
  // 4) intra-chunk Yd + D*x -> y
  yd_kernel<<<dim3(NHEADS, NC*4, BATCH), 256, 0, stream>>>(hbc, acum, dtp, Dv, y);
  // 5) chunk states -> st (R region; hiddenHL dead)
  states_kernel<<<dim3(NHEADS, NC, BATCH), 256, 0, stream>>>(hbc, acum, dtp, st);
  // 6) inter-chunk scan
  scan_kernel<<<dim3(BATCH*NHEADS), 256, 0, stream>>>(st, gch);
  // 7) inter-chunk Yo -> y (+=)
  yo_kernel<<<dim3(NHEADS, NC*4, BATCH), 256, 0, stream>>>(hbc, acum, st, y);
  // 8) gate columns of in_proj (rows [0, INTER)); st dead, reconvert hidden
  {
    int nA4 = (M * H_SIZE) / 4;
    int nW  = INTER * H_SIZE;                        // hi+lo = 8.4 MB in d_out
    convert_hl_kernel<<<2048, 256, 0, stream>>>(hidden, hidhi, hidlo, nA4);
    convert_hl_kernel<<<2048, 256, 0, stream>>>(in_w, wscr, wscr + nW, nW/4);
    gemm_hl_mfma_kernel<<<dim3(INTER/128, M/128), 256, 0, stream>>>(
        hidhi, hidlo, wscr, wscr + nW, gate, M, INTER, H_SIZE);
  }
  // 9) gated RMSNorm in place on y
  rms_kernel<<<dim3(M), 256, 0, stream>>>(y, gate, norm_w);
  // 10) out_proj: y (M x INTER) @ out_w^T (H_SIZE x INTER); weights in R (free)
  {
    int nY4 = (M * INTER) / 4;
    int nW  = H_SIZE * INTER;                        // hi+lo = 8.4 MB in R
    ushort_t* whi2 = (ushort_t*)R;
    convert_hl_kernel<<<2048, 256, 0, stream>>>(y, yhi, ylo, nY4);
    convert_hl_kernel<<<2048, 256, 0, stream>>>(out_w, whi2, whi2 + nW, nW/4);
    gemm_hl_mfma_kernel<<<dim3(H_SIZE/128, M/128), 256, 0, stream>>>(
        yhi, ylo, whi2, whi2 + nW, out, M, H_SIZE, INTER);
  }
}

// Round 7
// 972.207 us; speedup vs baseline: 2.4003x; 1.2733x over previous
//
#include <hip/hip_runtime.h>
#include <hip/hip_bf16.h>
#include <math.h>

#define H_SIZE   1024
#define INTER    2048
#define NHEADS   32
#define HEAD_DIM 64
#define NSTATE   128
#define KCONV    4
#define CHUNK    256
#define CONV_DIM (INTER + 2*NSTATE)            // 2304
#define CIN_DIM  (CONV_DIM + NHEADS)           // 2336 (hBC + dt)
#define PROJ_DIM (2*INTER + 2*NSTATE + NHEADS) // 4384
#define BATCH    2
#define SEQ      4096
#define NC       (SEQ/CHUNK)                   // 16
#define EPS_F    1e-5f

typedef __attribute__((ext_vector_type(8))) short bf16x8;   // 8 bf16 in 4 VGPRs
typedef __attribute__((ext_vector_type(4))) float f32x4;
typedef unsigned short ushort_t;

__device__ __forceinline__ ushort_t f2bf(float x) {   // RNE float->bf16 bits
  unsigned u = __float_as_uint(x);
  u += 0x7fffu + ((u >> 16) & 1u);
  return (ushort_t)(u >> 16);
}
__device__ __forceinline__ float bf2f(ushort_t h) {
  return __uint_as_float((unsigned)h << 16);
}

// ---------------------------------------------------------------------------
// Split fp32 x into hi+lo bf16 planes: x ~= hi + lo (rel err ~2^-17).
// ---------------------------------------------------------------------------
__global__ __launch_bounds__(256) void convert_hl_kernel(
    const float* __restrict__ x, ushort_t* __restrict__ hi,
    ushort_t* __restrict__ lo, int n4) {
  int idx = blockIdx.x * 256 + threadIdx.x;
  int stride = gridDim.x * 256;
  for (int i = idx; i < n4; i += stride) {
    const float* p = x + (size_t)i * 4;
    float v0 = p[0], v1 = p[1], v2 = p[2], v3 = p[3];
    ushort_t h0 = f2bf(v0), h1 = f2bf(v1), h2 = f2bf(v2), h3 = f2bf(v3);
    ushort_t l0 = f2bf(v0 - bf2f(h0));
    ushort_t l1 = f2bf(v1 - bf2f(h1));
    ushort_t l2 = f2bf(v2 - bf2f(h2));
    ushort_t l3 = f2bf(v3 - bf2f(h3));
    *(uint2*)(hi + (size_t)i * 4) =
        make_uint2((unsigned)h0 | ((unsigned)h1 << 16), (unsigned)h2 | ((unsigned)h3 << 16));
    *(uint2*)(lo + (size_t)i * 4) =
        make_uint2((unsigned)l0 | ((unsigned)l1 << 16), (unsigned)l2 | ((unsigned)l3 << 16));
  }
}

// ---------------------------------------------------------------------------
// Pre-split the B (cols 2048..2176) and C (cols 2176..2304) slabs of hbc
// into bf16 hi/lo planes [M][128] each.
// ---------------------------------------------------------------------------
__global__ __launch_bounds__(256) void convert_bc_kernel(
    const float* __restrict__ hbc, ushort_t* __restrict__ Bph,
    ushort_t* __restrict__ Bpl, ushort_t* __restrict__ Cph,
    ushort_t* __restrict__ Cpl) {
  const int n4 = (BATCH*SEQ) * 64;  // 64 float4 per row (256 floats B+C)
  int idx = blockIdx.x * 256 + threadIdx.x;
  int stride = gridDim.x * 256;
  for (int i = idx; i < n4; i += stride) {
    int row = i >> 6;
    int c4 = (i & 63) * 4;
    float4 v = *(const float4*)(hbc + (size_t)row*CONV_DIM + INTER + c4);
    ushort_t h0 = f2bf(v.x), h1 = f2bf(v.y), h2 = f2bf(v.z), h3 = f2bf(v.w);
    ushort_t l0 = f2bf(v.x - bf2f(h0)), l1 = f2bf(v.y - bf2f(h1));
    ushort_t l2 = f2bf(v.z - bf2f(h2)), l3 = f2bf(v.w - bf2f(h3));
    uint2 hp = make_uint2((unsigned)h0 | ((unsigned)h1 << 16), (unsigned)h2 | ((unsigned)h3 << 16));
    uint2 lp = make_uint2((unsigned)l0 | ((unsigned)l1 << 16), (unsigned)l2 | ((unsigned)l3 << 16));
    if (c4 < 128) {
      *(uint2*)(Bph + (size_t)row*128 + c4) = hp;
      *(uint2*)(Bpl + (size_t)row*128 + c4) = lp;
    } else {
      *(uint2*)(Cph + (size_t)row*128 + (c4 - 128)) = hp;
      *(uint2*)(Cpl + (size_t)row*128 + (c4 - 128)) = lp;
    }
  }
}

// ---------------------------------------------------------------------------
// C[m,n] = sum_k A[m,k]*W[n,k] via split-bf16 MFMA (hi*hi + hi*lo + lo*hi).
// 128x128 tile, BK=32, 256 threads = 4 waves (2x2), wave tile 64x64.
// ---------------------------------------------------------------------------
#define LROW 40
__global__ __launch_bounds__(256) void gemm_hl_mfma_kernel(
    const ushort_t* __restrict__ Ahi, const ushort_t* __restrict__ Alo,
    const ushort_t* __restrict__ Whi, const ushort_t* __restrict__ Wlo,
    float* __restrict__ C, int M, int N, int K) {
  __shared__ __align__(16) ushort_t Ah[128*LROW], Al[128*LROW];
  __shared__ __align__(16) ushort_t Wh[128*LROW], Wl[128*LROW];
  const int tid = threadIdx.x;
  const int lane = tid & 63, wid = tid >> 6;
  const int wr = wid >> 1, wc = wid & 1;
  const int fr = lane & 15, fg = lane >> 4;
  const int m0 = blockIdx.y * 128, n0 = blockIdx.x * 128;

  const int r0 = tid >> 2;
  const int kseg = (tid & 3) * 8;
  const int r1 = r0 + 64;
  const size_t a0 = (size_t)(m0 + r0) * K + kseg;
  const size_t a1 = (size_t)(m0 + r1) * K + kseg;
  const size_t w0 = (size_t)(n0 + r0) * K + kseg;
  const size_t w1 = (size_t)(n0 + r1) * K + kseg;
  const bool wv0 = (n0 + r0) < N, wv1 = (n0 + r1) < N;

  bf16x8 gA0, gA1, gAl0, gAl1, gW0, gW1, gWl0, gWl1;
  const bf16x8 z8 = {};
  f32x4 acc[4][4] = {};

  auto glod = [&](int k0) {
    gA0  = *(const bf16x8*)(Ahi + a0 + k0);
    gA1  = *(const bf16x8*)(Ahi + a1 + k0);
    gAl0 = *(const bf16x8*)(Alo + a0 + k0);
    gAl1 = *(const bf16x8*)(Alo + a1 + k0);
    gW0  = wv0 ? *(const bf16x8*)(Whi + w0 + k0) : z8;
    gW1  = wv1 ? *(const bf16x8*)(Whi + w1 + k0) : z8;
    gWl0 = wv0 ? *(const bf16x8*)(Wlo + w0 + k0) : z8;
    gWl1 = wv1 ? *(const bf16x8*)(Wlo + w1 + k0) : z8;
  };

  glod(0);
  for (int k0 = 0; k0 < K; k0 += 32) {
    __syncthreads();
    *(bf16x8*)&Ah[r0*LROW + kseg] = gA0;
    *(bf16x8*)&Ah[r1*LROW + kseg] = gA1;
    *(bf16x8*)&Al[r0*LROW + kseg] = gAl0;
    *(bf16x8*)&Al[r1*LROW + kseg] = gAl1;
    *(bf16x8*)&Wh[r0*LROW + kseg] = gW0;
    *(bf16x8*)&Wh[r1*LROW + kseg] = gW1;
    *(bf16x8*)&Wl[r0*LROW + kseg] = gWl0;
    *(bf16x8*)&Wl[r1*LROW + kseg] = gWl1;
    __syncthreads();
    if (k0 + 32 < K) glod(k0 + 32);

    bf16x8 wh[4], wl[4];
#pragma unroll
    for (int nf = 0; nf < 4; ++nf) {
      int off = (wc*64 + nf*16 + fr) * LROW + 8*fg;
      wh[nf] = *(const bf16x8*)&Wh[off];
      wl[nf] = *(const bf16x8*)&Wl[off];
    }
#pragma unroll
    for (int mf = 0; mf < 4; ++mf) {
      int aoff = (wr*64 + mf*16 + fr) * LROW + 8*fg;
      bf16x8 ah = *(const bf16x8*)&Ah[aoff];
      bf16x8 al = *(const bf16x8*)&Al[aoff];
#pragma unroll
      for (int nf = 0; nf < 4; ++nf) {
        acc[mf][nf] = __builtin_amdgcn_mfma_f32_16x16x32_bf16(ah, wh[nf], acc[mf][nf], 0, 0, 0);
        acc[mf][nf] = __builtin_amdgcn_mfma_f32_16x16x32_bf16(ah, wl[nf], acc[mf][nf], 0, 0, 0);
        acc[mf][nf] = __builtin_amdgcn_mfma_f32_16x16x32_bf16(al, wh[nf], acc[mf][nf], 0, 0, 0);
      }
    }
  }

#pragma unroll
  for (int mf = 0; mf < 4; ++mf)
#pragma unroll
    for (int nf = 0; nf < 4; ++nf) {
      int col = n0 + wc*64 + nf*16 + fr;
      if (col < N) {
        size_t base = (size_t)(m0 + wr*64 + mf*16 + fg*4) * N + col;
        f32x4 v = acc[mf][nf];
        C[base]               = v[0];
        C[base + (size_t)N]   = v[1];
        C[base + 2*(size_t)N] = v[2];
        C[base + 3*(size_t)N] = v[3];
      }
    }
}

// ---------------------------------------------------------------------------
// Causal depthwise conv (K=4) + bias + SiLU; softplus(dt + dt_bias).
// ---------------------------------------------------------------------------
__global__ __launch_bounds__(256) void conv_kernel(
    const float* __restrict__ cin, const float* __restrict__ cw,
    const float* __restrict__ cb, const float* __restrict__ dtb,
    float* __restrict__ hbc, float* __restrict__ dtp) {
  const int bs = blockIdx.x;
  const int b = bs / SEQ, s = bs % SEQ;
  const int tid = threadIdx.x;
  const float* base = cin + (size_t)b * SEQ * CIN_DIM;
  for (int c = tid; c < CONV_DIM; c += 256) {
    float acc = cb[c];
#pragma unroll
    for (int k = 0; k < KCONV; ++k) {
      int sp = s - (KCONV-1) + k;
      if (sp >= 0) acc = fmaf(cw[c*KCONV + k], base[(size_t)sp * CIN_DIM + c], acc);
    }
    acc = acc / (1.f + expf(-acc));  // silu
    hbc[(size_t)bs * CONV_DIM + c] = acc;
  }
  if (tid < NHEADS) {
    float d = cin[(size_t)bs * CIN_DIM + CONV_DIM + tid] + dtb[tid];
    d = (d > 20.f) ? d : log1pf(expf(d));   // softplus
    dtp[(size_t)bs * NHEADS + tid] = d;
  }
}

// ---------------------------------------------------------------------------
__global__ __launch_bounds__(256) void cumsum_kernel(
    const float* __restrict__ dtp, const float* __restrict__ A_log,
    float* __restrict__ acum, float* __restrict__ gch) {
  const int c = blockIdx.x, h = blockIdx.y, b = blockIdx.z;
  const int tid = threadIdx.x;
  __shared__ float sm[CHUNK];
  const float A = -expf(A_log[h]);
  const int s = c * CHUNK + tid;
  float a = dtp[(size_t)(b*SEQ + s)*NHEADS + h] * A;
  sm[tid] = a;
  __syncthreads();
  for (int off = 1; off < CHUNK; off <<= 1) {
    float v = 0.f;
    if (tid >= off) v = sm[tid - off];
    __syncthreads();
    sm[tid] += v;
    __syncthreads();
  }
  float ac = sm[tid];
  acum[((size_t)(b*NHEADS + h)*NC + c)*CHUNK + tid] = ac;
  if (tid == CHUNK-1) gch[(size_t)(b*NHEADS + h)*NC + c] = expf(ac);
}

// ---------------------------------------------------------------------------
// Yd (intra-chunk) via MFMA, per (b, c, lt, h). 4 waves, each a 16-row strip.
//   stage1: G = C·B^T (K=128, split-bf16, 3 MFMA planes)
//   stage2: mask + exp(acum_l - acum_s) on C/D fragments; split G to bf16
//   stage3: Yd += G·X (K=64, 3 planes);  epilogue: + D*x
// LDS layouts: C/B rows stride 136 ush (2-way max); Xt transposed with XOR
// swizzle s^=((p>>2)&7)<<3 so writes and b128 reads stay ~2-way.
// ---------------------------------------------------------------------------
#define CBROW 136
#define XROW2 72
__global__ __launch_bounds__(256) void yd_mfma_kernel(
    const ushort_t* __restrict__ Bph, const ushort_t* __restrict__ Bpl,
    const ushort_t* __restrict__ Cph, const ushort_t* __restrict__ Cpl,
    const float* __restrict__ hbc, const float* __restrict__ acum,
    const float* __restrict__ dtp, const float* __restrict__ Dv,
    float* __restrict__ y) {
  __shared__ __align__(16) ushort_t ChS[64*CBROW], ClS[64*CBROW];
  __shared__ __align__(16) ushort_t BhS[64*CBROW], BlS[64*CBROW];
  __shared__ __align__(16) ushort_t XhS[64*XROW2], XlS[64*XROW2];
  __shared__ __align__(16) ushort_t GhS[4][16*XROW2], GlS[4][16*XROW2];
  __shared__ float acLs[64], acSs[64];

  const int h = blockIdx.x;
  const int c = blockIdx.y >> 2, lt = blockIdx.y & 3;
  const int b = blockIdx.z;
  const int tid = threadIdx.x;
  const int lane = tid & 63, w = tid >> 6;
  const int fr = lane & 15, fg = lane >> 4;

  const size_t seqbase = (size_t)(b*SEQ + c*CHUNK);
  const size_t acbase  = ((size_t)(b*NHEADS + h)*NC + c)*CHUNK;

  // stage C strip (64 x 128) from pre-split planes
  {
    const size_t g0 = (seqbase + lt*64) * 128;
#pragma unroll
    for (int i = 0; i < 4; ++i) {
      int f = tid + 256*i; int r = f >> 4; int k8 = (f & 15) * 8;
      *(bf16x8*)&ChS[r*CBROW + k8] = *(const bf16x8*)(Cph + g0 + (size_t)r*128 + k8);
      *(bf16x8*)&ClS[r*CBROW + k8] = *(const bf16x8*)(Cpl + g0 + (size_t)r*128 + k8);
    }
  }
  if (tid < 64) acLs[tid] = acum[acbase + lt*64 + tid];

  f32x4 acc[4] = {};

  for (int st = 0; st <= lt; ++st) {
    __syncthreads();   // protects B/X/acS (and first-iter C/acL visibility)
    {
      const size_t g0 = (seqbase + st*64) * 128;
#pragma unroll
      for (int i = 0; i < 4; ++i) {
        int f = tid + 256*i; int r = f >> 4; int k8 = (f & 15) * 8;
        *(bf16x8*)&BhS[r*CBROW + k8] = *(const bf16x8*)(Bph + g0 + (size_t)r*128 + k8);
        *(bf16x8*)&BlS[r*CBROW + k8] = *(const bf16x8*)(Bpl + g0 + (size_t)r*128 + k8);
      }
    }
    // X = x*dt, split, store transposed+swizzled: XhS[p][s ^ swz(p)]
#pragma unroll
    for (int i = 0; i < 4; ++i) {
      int f = tid + 256*i; int s = f >> 4; int p0 = (f & 15) * 4;
      size_t row = seqbase + st*64 + s;
      float dtv = dtp[row*NHEADS + h];
      float4 xv = *(const float4*)(hbc + row*CONV_DIM + h*HEAD_DIM + p0);
      float vals[4] = {xv.x*dtv, xv.y*dtv, xv.z*dtv, xv.w*dtv};
#pragma unroll
      for (int j = 0; j < 4; ++j) {
        int p = p0 + j;
        int sw = s ^ (((p >> 2) & 7) << 3);
        ushort_t hh = f2bf(vals[j]);
        ushort_t ll = f2bf(vals[j] - bf2f(hh));
        XhS[p*XROW2 + sw] = hh;
        XlS[p*XROW2 + sw] = ll;
      }
    }
    if (tid < 64) acSs[tid] = acum[acbase + st*64 + tid];
    __syncthreads();

    // stage1: G(16x64 strip) = C · B^T, K=128, 3 planes
    f32x4 g[4] = {};
    {
      const int ra = (w*16 + fr) * CBROW;
#pragma unroll
      for (int ks = 0; ks < 4; ++ks) {
        const int ko = ks*32 + fg*8;
        bf16x8 ah = *(const bf16x8*)&ChS[ra + ko];
        bf16x8 al = *(const bf16x8*)&ClS[ra + ko];
#pragma unroll
        for (int nf = 0; nf < 4; ++nf) {
          const int rb = (nf*16 + fr) * CBROW + ko;
          bf16x8 bh = *(const bf16x8*)&BhS[rb];
          bf16x8 bl = *(const bf16x8*)&BlS[rb];
          g[nf] = __builtin_amdgcn_mfma_f32_16x16x32_bf16(ah, bh, g[nf], 0, 0, 0);
          g[nf] = __builtin_amdgcn_mfma_f32_16x16x32_bf16(ah, bl, g[nf], 0, 0, 0);
          g[nf] = __builtin_amdgcn_mfma_f32_16x16x32_bf16(al, bh, g[nf], 0, 0, 0);
        }
      }
    }
    // stage2: mask + decay on C/D frags (col=fr, row=fg*4+r), split to bf16
    {
      const bool full = (st < lt);
#pragma unroll
      for (int nf = 0; nf < 4; ++nf) {
        int sl = nf*16 + fr;
        float aS = acSs[sl];
#pragma unroll
        for (int r = 0; r < 4; ++r) {
          int ll = w*16 + fg*4 + r;
          float v = 0.f;
          if (full || ll >= sl) v = g[nf][r] * __expf(acLs[ll] - aS);
          ushort_t hh = f2bf(v);
          ushort_t lo2 = f2bf(v - bf2f(hh));
          GhS[w][(fg*4 + r)*XROW2 + sl] = hh;
          GlS[w][(fg*4 + r)*XROW2 + sl] = lo2;
        }
      }
    }
    __syncthreads();   // G visible (cross-lane) before stage3 reads
    // stage3: acc += G(16x64) · X^T, K=64, 3 planes
#pragma unroll
    for (int ks = 0; ks < 2; ++ks) {
      const int ko = ks*32 + fg*8;
      bf16x8 gh = *(const bf16x8*)&GhS[w][fr*XROW2 + ko];
      bf16x8 gl = *(const bf16x8*)&GlS[w][fr*XROW2 + ko];
#pragma unroll
      for (int nf = 0; nf < 4; ++nf) {
        int p = nf*16 + fr;
        int kb = ko ^ (((p >> 2) & 7) << 3);
        bf16x8 xh = *(const bf16x8*)&XhS[p*XROW2 + kb];
        bf16x8 xl = *(const bf16x8*)&XlS[p*XROW2 + kb];
        acc[nf] = __builtin_amdgcn_mfma_f32_16x16x32_bf16(gh, xh, acc[nf], 0, 0, 0);
        acc[nf] = __builtin_amdgcn_mfma_f32_16x16x32_bf16(gh, xl, acc[nf], 0, 0, 0);
        acc[nf] = __builtin_amdgcn_mfma_f32_16x16x32_bf16(gl, xh, acc[nf], 0, 0, 0);
      }
    }
  }

  // epilogue: + D*x, store
  const float Dh = Dv[h];
#pragma unroll
  for (int nf = 0; nf < 4; ++nf) {
    int p = nf*16 + fr;
#pragma unroll
    for (int r = 0; r < 4; ++r) {
      size_t row = seqbase + lt*64 + w*16 + fg*4 + r;
      float xval = hbc[row*CONV_DIM + h*HEAD_DIM + p];
      y[row*INTER + h*HEAD_DIM + p] = acc[nf][r] + Dh * xval;
    }
  }
}

// ---------------------------------------------------------------------------
__global__ __launch_bounds__(256) void states_kernel(
    const float* __restrict__ hbc, const float* __restrict__ acum,
    const float* __restrict__ dtp, float* __restrict__ states) {
  const int h = blockIdx.x, c = blockIdx.y, b = blockIdx.z;
  const int tid = threadIdx.x;
  __shared__ float Bs[64][132];
  __shared__ float Xd[64][68];
  const int ty = tid >> 4, tx = tid & 15;
  const size_t acbase = ((size_t)(b*NHEADS + h)*NC + c)*CHUNK;
  const float aclast = acum[acbase + CHUNK - 1];
  float acc[4][8] = {};

  for (int lt = 0; lt < 4; ++lt) {
    __syncthreads();
#pragma unroll
    for (int i = 0; i < 8; ++i) {
      int f = tid + 256*i;
      int l = f >> 5, n0 = (f & 31) << 2;
      *(float4*)&Bs[l][n0] =
        *(const float4*)(hbc + (size_t)(b*SEQ + c*CHUNK + lt*64 + l)*CONV_DIM + INTER + n0);
    }
#pragma unroll
    for (int i = 0; i < 4; ++i) {
      int f = tid + 256*i;
      int s = f >> 4, p0 = (f & 15) << 2;
      int sg = c*CHUNK + lt*64 + s;
      float mult = dtp[(size_t)(b*SEQ + sg)*NHEADS + h] * expf(aclast - acum[acbase + lt*64 + s]);
      float4 v = *(const float4*)(hbc + (size_t)(b*SEQ + sg)*CONV_DIM + h*HEAD_DIM + p0);
      *(float4*)&Xd[s][p0] = make_float4(v.x*mult, v.y*mult, v.z*mult, v.w*mult);
    }
    __syncthreads();
    for (int l = 0; l < 64; ++l) {
      float4 xv = *(const float4*)&Xd[l][ty*4];
      float4 b0 = *(const float4*)&Bs[l][tx*8];
      float4 b1 = *(const float4*)&Bs[l][tx*8+4];
      float xr[4] = {xv.x,xv.y,xv.z,xv.w};
      float br[8] = {b0.x,b0.y,b0.z,b0.w,b1.x,b1.y,b1.z,b1.w};
#pragma unroll
      for (int i = 0; i < 4; ++i)
#pragma unroll
        for (int j = 0; j < 8; ++j)
          acc[i][j] = fmaf(xr[i], br[j], acc[i][j]);
    }
  }
  float* sp = states + ((size_t)(b*NC + c)*NHEADS + h)*HEAD_DIM*NSTATE;
#pragma unroll
  for (int i = 0; i < 4; ++i) {
    int p = ty*4 + i;
    *(float4*)(sp + (size_t)p*NSTATE + tx*8)     = make_float4(acc[i][0],acc[i][1],acc[i][2],acc[i][3]);
    *(float4*)(sp + (size_t)p*NSTATE + tx*8 + 4) = make_float4(acc[i][4],acc[i][5],acc[i][6],acc[i][7]);
  }
}

// ---------------------------------------------------------------------------
__global__ __launch_bounds__(256) void scan_kernel(
    float* __restrict__ st, const float* __restrict__ g) {
  const int bh = blockIdx.x;
  const int b = bh >> 5, h = bh & 31;
  const int tid = threadIdx.x;
  float carry[32];
#pragma unroll
  for (int i = 0; i < 32; ++i) carry[i] = 0.f;
  for (int c = 0; c < NC; ++c) {
    const float gc = g[(size_t)(b*NHEADS + h)*NC + c];
    float* base = st + ((size_t)(b*NC + c)*NHEADS + h)*HEAD_DIM*NSTATE;
#pragma unroll
    for (int i = 0; i < 32; ++i) {
      int e = i*256 + tid;
      float sv = base[e];
      base[e] = carry[i];
      carry[i] = fmaf(carry[i], gc, sv);
    }
  }
}

// ---------------------------------------------------------------------------
__global__ __launch_bounds__(256) void yo_kernel(
    const float* __restrict__ hbc, const float* __restrict__ acum,
    const float* __restrict__ prev, float* __restrict__ y) {
  const int h = blockIdx.x;
  const int c = blockIdx.y >> 2, lt = blockIdx.y & 3;
  const int b = blockIdx.z;
  const int tid = threadIdx.x;
  __shared__ float Ct[128][68];
  __shared__ float Pt[128][68];
  const size_t acbase = ((size_t)(b*NHEADS + h)*NC + c)*CHUNK;

#pragma unroll
  for (int i = 0; i < 8; ++i) {
    int f = tid + 256*i;
    int l = f >> 5, n0 = (f & 31) << 2;
    float e = expf(acum[acbase + lt*64 + l]);
    float4 v = *(const float4*)(hbc + (size_t)(b*SEQ + c*CHUNK + lt*64 + l)*CONV_DIM + (INTER + NSTATE) + n0);
    Ct[n0+0][l] = v.x*e; Ct[n0+1][l] = v.y*e; Ct[n0+2][l] = v.z*e; Ct[n0+3][l] = v.w*e;
  }
  const float* pv = prev + ((size_t)(b*NC + c)*NHEADS + h)*HEAD_DIM*NSTATE;
#pragma unroll
  for (int i = 0; i < 8; ++i) {
    int f = tid + 256*i;
    int p = f >> 5, n0 = (f & 31) << 2;
    float4 v = *(const float4*)(pv + (size_t)p*NSTATE + n0);
    Pt[n0+0][p] = v.x; Pt[n0+1][p] = v.y; Pt[n0+2][p] = v.z; Pt[n0+3][p] = v.w;
  }
  __syncthreads();
  const int ty = tid >> 4, tx = tid & 15;
  float yo[4][4] = {};
  for (int n = 0; n < 128; ++n) {
    float4 cv = *(const float4*)&Ct[n][ty*4];
    float4 p4 = *(const float4*)&Pt[n][tx*4];
    float cr[4] = {cv.x,cv.y,cv.z,cv.w};
    float pr[4] = {p4.x,p4.y,p4.z,p4.w};
#pragma unroll
    for (int i = 0; i < 4; ++i)
#pragma unroll
      for (int j = 0; j < 4; ++j)
        yo[i][j] = fmaf(cr[i], pr[j], yo[i][j]);
  }
#pragma unroll
  for (int i = 0; i < 4; ++i) {
    int row = c*CHUNK + lt*64 + ty*4 + i;
    float* yrow = y + (size_t)(b*SEQ + row)*INTER + h*HEAD_DIM + tx*4;
#pragma unroll
    for (int j = 0; j < 4; ++j) yrow[j] += yo[i][j];
  }
}

// ---------------------------------------------------------------------------
__global__ __launch_bounds__(256) void rms_kernel(
    float* __restrict__ y, const float* __restrict__ gate,
    const float* __restrict__ norm_w) {
  const int bs = blockIdx.x;
  const int tid = threadIdx.x;
  float* yrow = y + (size_t)bs * INTER;
  const float* grow = gate + (size_t)bs * INTER;
  float yf[8];
  float ss = 0.f;
#pragma unroll
  for (int i = 0; i < 8; ++i) {
    int c = tid + i*256;
    float v = yrow[c];
    float gt = grow[c];
    float f = v * (gt / (1.f + expf(-gt)));
    yf[i] = f;
    ss += f*f;
  }
#pragma unroll
  for (int off = 32; off >= 1; off >>= 1) ss += __shfl_xor(ss, off, 64);
  __shared__ float red[4];
  if ((tid & 63) == 0) red[tid >> 6] = ss;
  __syncthreads();
  float total = red[0] + red[1] + red[2] + red[3];
  float sc = rsqrtf(total * (1.f/INTER) + EPS_F);
#pragma unroll
  for (int i = 0; i < 8; ++i) {
    int c = tid + i*256;
    yrow[c] = norm_w[c] * yf[i] * sc;
  }
}

__global__ void zero_kernel(float* p, size_t n) {
  size_t i = (size_t)blockIdx.x * blockDim.x + threadIdx.x;
  if (i < n) p[i] = 0.f;
}

// ---------------------------------------------------------------------------
extern "C" void kernel_launch(void* const* d_in, const int* in_sizes, int n_in,
                              void* d_out, int out_size, void* d_ws, size_t ws_size,
                              hipStream_t stream) {
  const float* hidden = (const float*)d_in[0];
  const float* in_w   = (const float*)d_in[1];
  const float* conv_w = (const float*)d_in[2];
  const float* conv_b = (const float*)d_in[3];
  const float* dt_b   = (const float*)d_in[4];
  const float* A_log  = (const float*)d_in[5];
  const float* Dv     = (const float*)d_in[6];
  const float* norm_w = (const float*)d_in[7];
  const float* out_w  = (const float*)d_in[8];
  float* out = (float*)d_out;

  const int M = BATCH*SEQ;

  // Workspace (floats). Peak == round-2's proven-safe 188 MB.
  const size_t sz_cin  = (size_t)M * CIN_DIM;
  const size_t sz_hbc  = (size_t)M * CONV_DIM;
  const size_t sz_dtp  = (size_t)M * NHEADS;
  const size_t sz_acum = (size_t)BATCH*NHEADS*NC*CHUNK;
  const size_t sz_gch  = (size_t)BATCH*NHEADS*NC;
  const size_t sz_R    = (size_t)BATCH*NC*NHEADS*HEAD_DIM*NSTATE;
  const size_t need = (sz_cin + sz_hbc + sz_dtp + sz_acum + sz_gch + sz_R) * sizeof(float);

  if (ws_size < need) {
    size_t n = (size_t)out_size;
    zero_kernel<<<(unsigned)((n + 255) / 256), 256, 0, stream>>>(out, n);
    return;
  }

  float* ws = (float*)d_ws;
  size_t o = 0;
  float* cin  = ws + o; o += sz_cin;
  float* hbc  = ws + o; o += sz_hbc;
  float* dtp  = ws + o; o += sz_dtp;
  float* acum = ws + o; o += sz_acum;
  float* gch  = ws + o; o += sz_gch;
  float* R    = ws + o; o += sz_R;

  float* y    = cin;   // cin dead after conv_kernel
  float* gate = hbc;   // hbc dead after yo_kernel
  float* st   = R;     // R free between gemms

  ushort_t* hidhi = (ushort_t*)R;
  ushort_t* hidlo = hidhi + (size_t)M * H_SIZE;
  ushort_t* yhi   = (ushort_t*)hbc;
  ushort_t* ylo   = yhi + (size_t)M * INTER;

  // d_out scratch: weights at offset 0 (steps 1,8); B/C bf16 planes at +16MB
  ushort_t* wscr = (ushort_t*)out;
  const size_t MP = (size_t)M * 128;
  ushort_t* bcp  = (ushort_t*)((char*)d_out + (size_t)(16u << 20));
  ushort_t* Bph = bcp;
  ushort_t* Bpl = bcp + MP;
  ushort_t* Cph = bcp + 2*MP;
  ushort_t* Cpl = bcp + 3*MP;

  // 1) in_proj conv-input columns
  {
    int nA4 = (M * H_SIZE) / 4;
    int nW  = CIN_DIM * H_SIZE;
    convert_hl_kernel<<<2048, 256, 0, stream>>>(hidden, hidhi, hidlo, nA4);
    convert_hl_kernel<<<2048, 256, 0, stream>>>(in_w + (size_t)INTER*H_SIZE, wscr, wscr + nW, nW/4);
    gemm_hl_mfma_kernel<<<dim3((CIN_DIM+127)/128, M/128), 256, 0, stream>>>(
        hidhi, hidlo, wscr, wscr + nW, cin, M, CIN_DIM, H_SIZE);
  }
  // 2) causal conv + SiLU; softplus(dt)
  conv_kernel<<<dim3(M), 256, 0, stream>>>(cin, conv_w, conv_b, dt_b, hbc, dtp);
  // 2.5) pre-split B/C slabs of hbc to bf16 hi/lo planes
  convert_bc_kernel<<<2048, 256, 0, stream>>>(hbc, Bph, Bpl, Cph, Cpl);
  // 3) per-chunk cumsum of dt*A
  cumsum_kernel<<<dim3(NC, NHEADS, BATCH), 256, 0, stream>>>(dtp, A_log, acum, gch);
  // 4) intra-chunk Yd + D*x -> y  (MFMA)
  yd_mfma_kernel<<<dim3(NHEADS, NC*4, BATCH), 256, 0, stream>>>(
      Bph, Bpl, Cph, Cpl, hbc, acum, dtp, Dv, y);
  // 5) chunk states -> st
  states_kernel<<<dim3(NHEADS, NC, BATCH), 256, 0, stream>>>(hbc, acum, dtp, st);
  // 6) inter-chunk scan
  scan_kernel<<<dim3(BATCH*NHEADS), 256, 0, stream>>>(st, gch);
  // 7) inter-chunk Yo -> y (+=)
  yo_kernel<<<dim3(NHEADS, NC*4, BATCH), 256, 0, stream>>>(hbc, acum, st, y);
  // 8) gate columns of in_proj
  {
    int nA4 = (M * H_SIZE) / 4;
    int nW  = INTER * H_SIZE;
    convert_hl_kernel<<<2048, 256, 0, stream>>>(hidden, hidhi, hidlo, nA4);
    convert_hl_kernel<<<2048, 256, 0, stream>>>(in_w, wscr, wscr + nW, nW/4);
    gemm_hl_mfma_kernel<<<dim3(INTER/128, M/128), 256, 0, stream>>>(
        hidhi, hidlo, wscr, wscr + nW, gate, M, INTER, H_SIZE);
  }
  // 9) gated RMSNorm in place on y
  rms_kernel<<<dim3(M), 256, 0, stream>>>(y, gate, norm_w);
  // 10) out_proj (weights staged in R, free now)
  {
    int nY4 = (M * INTER) / 4;
    int nW  = H_SIZE * INTER;
    ushort_t* whi2 = (ushort_t*)R;
    convert_hl_kernel<<<2048, 256, 0, stream>>>(y, yhi, ylo, nY4);
    convert_hl_kernel<<<2048, 256, 0, stream>>>(out_w, whi2, whi2 + nW, nW/4);
    gemm_hl_mfma_kernel<<<dim3(H_SIZE/128, M/128), 256, 0, stream>>>(
        yhi, ylo, whi2, whi2 + nW, out, M, H_SIZE, INTER);
  }
}

// Round 8
// 828.620 us; speedup vs baseline: 2.8162x; 1.1733x over previous
//
#include <hip/hip_runtime.h>
#include <hip/hip_bf16.h>
#include <math.h>

#define H_SIZE   1024
#define INTER    2048
#define NHEADS   32
#define HEAD_DIM 64
#define NSTATE   128
#define KCONV    4
#define CHUNK    256
#define CONV_DIM (INTER + 2*NSTATE)            // 2304
#define CIN_DIM  (CONV_DIM + NHEADS)           // 2336 (hBC + dt)
#define PROJ_DIM (2*INTER + 2*NSTATE + NHEADS) // 4384
#define BATCH    2
#define SEQ      4096
#define NC       (SEQ/CHUNK)                   // 16
#define EPS_F    1e-5f

typedef __attribute__((ext_vector_type(8))) short bf16x8;   // 8 bf16 in 4 VGPRs
typedef __attribute__((ext_vector_type(4))) float f32x4;
typedef unsigned short ushort_t;

__device__ __forceinline__ ushort_t f2bf(float x) {   // RNE float->bf16 bits
  unsigned u = __float_as_uint(x);
  u += 0x7fffu + ((u >> 16) & 1u);
  return (ushort_t)(u >> 16);
}
__device__ __forceinline__ float bf2f(ushort_t h) {
  return __uint_as_float((unsigned)h << 16);
}

// ---------------------------------------------------------------------------
// Split fp32 x into hi+lo bf16 planes: x ~= hi + lo (rel err ~2^-17).
// ---------------------------------------------------------------------------
__global__ __launch_bounds__(256) void convert_hl_kernel(
    const float* __restrict__ x, ushort_t* __restrict__ hi,
    ushort_t* __restrict__ lo, int n4) {
  int idx = blockIdx.x * 256 + threadIdx.x;
  int stride = gridDim.x * 256;
  for (int i = idx; i < n4; i += stride) {
    const float* p = x + (size_t)i * 4;
    float v0 = p[0], v1 = p[1], v2 = p[2], v3 = p[3];
    ushort_t h0 = f2bf(v0), h1 = f2bf(v1), h2 = f2bf(v2), h3 = f2bf(v3);
    ushort_t l0 = f2bf(v0 - bf2f(h0));
    ushort_t l1 = f2bf(v1 - bf2f(h1));
    ushort_t l2 = f2bf(v2 - bf2f(h2));
    ushort_t l3 = f2bf(v3 - bf2f(h3));
    *(uint2*)(hi + (size_t)i * 4) =
        make_uint2((unsigned)h0 | ((unsigned)h1 << 16), (unsigned)h2 | ((unsigned)h3 << 16));
    *(uint2*)(lo + (size_t)i * 4) =
        make_uint2((unsigned)l0 | ((unsigned)l1 << 16), (unsigned)l2 | ((unsigned)l3 << 16));
  }
}

// ---------------------------------------------------------------------------
// Pre-split the B (cols 2048..2176) and C (cols 2176..2304) slabs of hbc
// into bf16 hi/lo planes [M][128] each.
// ---------------------------------------------------------------------------
__global__ __launch_bounds__(256) void convert_bc_kernel(
    const float* __restrict__ hbc, ushort_t* __restrict__ Bph,
    ushort_t* __restrict__ Bpl, ushort_t* __restrict__ Cph,
    ushort_t* __restrict__ Cpl) {
  const int n4 = (BATCH*SEQ) * 64;
  int idx = blockIdx.x * 256 + threadIdx.x;
  int stride = gridDim.x * 256;
  for (int i = idx; i < n4; i += stride) {
    int row = i >> 6;
    int c4 = (i & 63) * 4;
    float4 v = *(const float4*)(hbc + (size_t)row*CONV_DIM + INTER + c4);
    ushort_t h0 = f2bf(v.x), h1 = f2bf(v.y), h2 = f2bf(v.z), h3 = f2bf(v.w);
    ushort_t l0 = f2bf(v.x - bf2f(h0)), l1 = f2bf(v.y - bf2f(h1));
    ushort_t l2 = f2bf(v.z - bf2f(h2)), l3 = f2bf(v.w - bf2f(h3));
    uint2 hp = make_uint2((unsigned)h0 | ((unsigned)h1 << 16), (unsigned)h2 | ((unsigned)h3 << 16));
    uint2 lp = make_uint2((unsigned)l0 | ((unsigned)l1 << 16), (unsigned)l2 | ((unsigned)l3 << 16));
    if (c4 < 128) {
      *(uint2*)(Bph + (size_t)row*128 + c4) = hp;
      *(uint2*)(Bpl + (size_t)row*128 + c4) = lp;
    } else {
      *(uint2*)(Cph + (size_t)row*128 + (c4 - 128)) = hp;
      *(uint2*)(Cpl + (size_t)row*128 + (c4 - 128)) = lp;
    }
  }
}

// ---------------------------------------------------------------------------
// C[m,n] = sum_k A[m,k]*W[n,k] via split-bf16 MFMA (hi*hi + hi*lo + lo*hi).
// 128x128 tile, BK=32, 256 threads = 4 waves (2x2), wave tile 64x64.
// ---------------------------------------------------------------------------
#define LROW 40
__global__ __launch_bounds__(256) void gemm_hl_mfma_kernel(
    const ushort_t* __restrict__ Ahi, const ushort_t* __restrict__ Alo,
    const ushort_t* __restrict__ Whi, const ushort_t* __restrict__ Wlo,
    float* __restrict__ C, int M, int N, int K) {
  __shared__ __align__(16) ushort_t Ah[128*LROW], Al[128*LROW];
  __shared__ __align__(16) ushort_t Wh[128*LROW], Wl[128*LROW];
  const int tid = threadIdx.x;
  const int lane = tid & 63, wid = tid >> 6;
  const int wr = wid >> 1, wc = wid & 1;
  const int fr = lane & 15, fg = lane >> 4;
  const int m0 = blockIdx.y * 128, n0 = blockIdx.x * 128;

  const int r0 = tid >> 2;
  const int kseg = (tid & 3) * 8;
  const int r1 = r0 + 64;
  const size_t a0 = (size_t)(m0 + r0) * K + kseg;
  const size_t a1 = (size_t)(m0 + r1) * K + kseg;
  const size_t w0 = (size_t)(n0 + r0) * K + kseg;
  const size_t w1 = (size_t)(n0 + r1) * K + kseg;
  const bool wv0 = (n0 + r0) < N, wv1 = (n0 + r1) < N;

  bf16x8 gA0, gA1, gAl0, gAl1, gW0, gW1, gWl0, gWl1;
  const bf16x8 z8 = {};
  f32x4 acc[4][4] = {};

  auto glod = [&](int k0) {
    gA0  = *(const bf16x8*)(Ahi + a0 + k0);
    gA1  = *(const bf16x8*)(Ahi + a1 + k0);
    gAl0 = *(const bf16x8*)(Alo + a0 + k0);
    gAl1 = *(const bf16x8*)(Alo + a1 + k0);
    gW0  = wv0 ? *(const bf16x8*)(Whi + w0 + k0) : z8;
    gW1  = wv1 ? *(const bf16x8*)(Whi + w1 + k0) : z8;
    gWl0 = wv0 ? *(const bf16x8*)(Wlo + w0 + k0) : z8;
    gWl1 = wv1 ? *(const bf16x8*)(Wlo + w1 + k0) : z8;
  };

  glod(0);
  for (int k0 = 0; k0 < K; k0 += 32) {
    __syncthreads();
    *(bf16x8*)&Ah[r0*LROW + kseg] = gA0;
    *(bf16x8*)&Ah[r1*LROW + kseg] = gA1;
    *(bf16x8*)&Al[r0*LROW + kseg] = gAl0;
    *(bf16x8*)&Al[r1*LROW + kseg] = gAl1;
    *(bf16x8*)&Wh[r0*LROW + kseg] = gW0;
    *(bf16x8*)&Wh[r1*LROW + kseg] = gW1;
    *(bf16x8*)&Wl[r0*LROW + kseg] = gWl0;
    *(bf16x8*)&Wl[r1*LROW + kseg] = gWl1;
    __syncthreads();
    if (k0 + 32 < K) glod(k0 + 32);

    bf16x8 wh[4], wl[4];
#pragma unroll
    for (int nf = 0; nf < 4; ++nf) {
      int off = (wc*64 + nf*16 + fr) * LROW + 8*fg;
      wh[nf] = *(const bf16x8*)&Wh[off];
      wl[nf] = *(const bf16x8*)&Wl[off];
    }
#pragma unroll
    for (int mf = 0; mf < 4; ++mf) {
      int aoff = (wr*64 + mf*16 + fr) * LROW + 8*fg;
      bf16x8 ah = *(const bf16x8*)&Ah[aoff];
      bf16x8 al = *(const bf16x8*)&Al[aoff];
#pragma unroll
      for (int nf = 0; nf < 4; ++nf) {
        acc[mf][nf] = __builtin_amdgcn_mfma_f32_16x16x32_bf16(ah, wh[nf], acc[mf][nf], 0, 0, 0);
        acc[mf][nf] = __builtin_amdgcn_mfma_f32_16x16x32_bf16(ah, wl[nf], acc[mf][nf], 0, 0, 0);
        acc[mf][nf] = __builtin_amdgcn_mfma_f32_16x16x32_bf16(al, wh[nf], acc[mf][nf], 0, 0, 0);
      }
    }
  }

#pragma unroll
  for (int mf = 0; mf < 4; ++mf)
#pragma unroll
    for (int nf = 0; nf < 4; ++nf) {
      int col = n0 + wc*64 + nf*16 + fr;
      if (col < N) {
        size_t base = (size_t)(m0 + wr*64 + mf*16 + fg*4) * N + col;
        f32x4 v = acc[mf][nf];
        C[base]               = v[0];
        C[base + (size_t)N]   = v[1];
        C[base + 2*(size_t)N] = v[2];
        C[base + 3*(size_t)N] = v[3];
      }
    }
}

// ---------------------------------------------------------------------------
// Causal depthwise conv (K=4) + bias + SiLU; softplus(dt + dt_bias).
// ---------------------------------------------------------------------------
__global__ __launch_bounds__(256) void conv_kernel(
    const float* __restrict__ cin, const float* __restrict__ cw,
    const float* __restrict__ cb, const float* __restrict__ dtb,
    float* __restrict__ hbc, float* __restrict__ dtp) {
  const int bs = blockIdx.x;
  const int b = bs / SEQ, s = bs % SEQ;
  const int tid = threadIdx.x;
  const float* base = cin + (size_t)b * SEQ * CIN_DIM;
  for (int c = tid; c < CONV_DIM; c += 256) {
    float acc = cb[c];
#pragma unroll
    for (int k = 0; k < KCONV; ++k) {
      int sp = s - (KCONV-1) + k;
      if (sp >= 0) acc = fmaf(cw[c*KCONV + k], base[(size_t)sp * CIN_DIM + c], acc);
    }
    acc = acc / (1.f + expf(-acc));  // silu
    hbc[(size_t)bs * CONV_DIM + c] = acc;
  }
  if (tid < NHEADS) {
    float d = cin[(size_t)bs * CIN_DIM + CONV_DIM + tid] + dtb[tid];
    d = (d > 20.f) ? d : log1pf(expf(d));   // softplus
    dtp[(size_t)bs * NHEADS + tid] = d;
  }
}

// ---------------------------------------------------------------------------
__global__ __launch_bounds__(256) void cumsum_kernel(
    const float* __restrict__ dtp, const float* __restrict__ A_log,
    float* __restrict__ acum, float* __restrict__ gch) {
  const int c = blockIdx.x, h = blockIdx.y, b = blockIdx.z;
  const int tid = threadIdx.x;
  __shared__ float sm[CHUNK];
  const float A = -expf(A_log[h]);
  const int s = c * CHUNK + tid;
  float a = dtp[(size_t)(b*SEQ + s)*NHEADS + h] * A;
  sm[tid] = a;
  __syncthreads();
  for (int off = 1; off < CHUNK; off <<= 1) {
    float v = 0.f;
    if (tid >= off) v = sm[tid - off];
    __syncthreads();
    sm[tid] += v;
    __syncthreads();
  }
  float ac = sm[tid];
  acum[((size_t)(b*NHEADS + h)*NC + c)*CHUNK + tid] = ac;
  if (tid == CHUNK-1) gch[(size_t)(b*NHEADS + h)*NC + c] = expf(ac);
}

// ---------------------------------------------------------------------------
// Yd (intra-chunk) via MFMA, per (b, c, lt, h). 4 waves, each a 16-row strip.
// C fragments (loop-invariant) held in REGISTERS from global planes; B in LDS.
//   stage1: G = C·B^T (K=128, 3 planes)
//   stage2: mask + exp(acum_l - acum_s) on C/D frags; split G to bf16
//   stage3: Yd += G·X (K=64, 3 planes);  epilogue: + D*x
// LDS ~70.5 KB -> 2 blocks/CU.
// ---------------------------------------------------------------------------
#define CBROW 136
#define XROW2 72
__global__ __launch_bounds__(256) void yd_mfma_kernel(
    const ushort_t* __restrict__ Bph, const ushort_t* __restrict__ Bpl,
    const ushort_t* __restrict__ Cph, const ushort_t* __restrict__ Cpl,
    const float* __restrict__ hbc, const float* __restrict__ acum,
    const float* __restrict__ dtp, const float* __restrict__ Dv,
    float* __restrict__ y) {
  __shared__ __align__(16) ushort_t BhS[64*CBROW], BlS[64*CBROW];
  __shared__ __align__(16) ushort_t XhS[64*XROW2], XlS[64*XROW2];
  __shared__ __align__(16) ushort_t GhS[4][16*XROW2], GlS[4][16*XROW2];
  __shared__ float acLs[64], acSs[64];

  const int h = blockIdx.x;
  const int c = blockIdx.y >> 2, lt = blockIdx.y & 3;
  const int b = blockIdx.z;
  const int tid = threadIdx.x;
  const int lane = tid & 63, w = tid >> 6;
  const int fr = lane & 15, fg = lane >> 4;

  const size_t seqbase = (size_t)(b*SEQ + c*CHUNK);
  const size_t acbase  = ((size_t)(b*NHEADS + h)*NC + c)*CHUNK;

  // C fragments (A-operand), loop-invariant: 4 ks x hi/lo in registers
  bf16x8 cfh[4], cfl[4];
  {
    const size_t cg = (seqbase + lt*64 + w*16 + fr) * 128;
#pragma unroll
    for (int ks = 0; ks < 4; ++ks) {
      int ko = ks*32 + fg*8;
      cfh[ks] = *(const bf16x8*)(Cph + cg + ko);
      cfl[ks] = *(const bf16x8*)(Cpl + cg + ko);
    }
  }
  if (tid < 64) acLs[tid] = acum[acbase + lt*64 + tid];

  f32x4 acc[4] = {};

  for (int st = 0; st <= lt; ++st) {
    __syncthreads();   // protects B/X/acS (and first-iter acL visibility)
    {
      const size_t g0 = (seqbase + st*64) * 128;
#pragma unroll
      for (int i = 0; i < 4; ++i) {
        int f = tid + 256*i; int r = f >> 4; int k8 = (f & 15) * 8;
        *(bf16x8*)&BhS[r*CBROW + k8] = *(const bf16x8*)(Bph + g0 + (size_t)r*128 + k8);
        *(bf16x8*)&BlS[r*CBROW + k8] = *(const bf16x8*)(Bpl + g0 + (size_t)r*128 + k8);
      }
    }
    // X = x*dt, split, store transposed+swizzled: XhS[p][s ^ swz(p)]
#pragma unroll
    for (int i = 0; i < 4; ++i) {
      int f = tid + 256*i; int s = f >> 4; int p0 = (f & 15) * 4;
      size_t row = seqbase + st*64 + s;
      float dtv = dtp[row*NHEADS + h];
      float4 xv = *(const float4*)(hbc + row*CONV_DIM + h*HEAD_DIM + p0);
      float vals[4] = {xv.x*dtv, xv.y*dtv, xv.z*dtv, xv.w*dtv};
#pragma unroll
      for (int j = 0; j < 4; ++j) {
        int p = p0 + j;
        int sw = s ^ (((p >> 2) & 7) << 3);
        ushort_t hh = f2bf(vals[j]);
        ushort_t ll = f2bf(vals[j] - bf2f(hh));
        XhS[p*XROW2 + sw] = hh;
        XlS[p*XROW2 + sw] = ll;
      }
    }
    if (tid < 64) acSs[tid] = acum[acbase + st*64 + tid];
    __syncthreads();

    // stage1: G(16x64 strip) = C · B^T, K=128, 3 planes
    f32x4 g[4] = {};
#pragma unroll
    for (int ks = 0; ks < 4; ++ks) {
      const int ko = ks*32 + fg*8;
#pragma unroll
      for (int nf = 0; nf < 4; ++nf) {
        const int rb = (nf*16 + fr) * CBROW + ko;
        bf16x8 bh = *(const bf16x8*)&BhS[rb];
        bf16x8 bl = *(const bf16x8*)&BlS[rb];
        g[nf] = __builtin_amdgcn_mfma_f32_16x16x32_bf16(cfh[ks], bh, g[nf], 0, 0, 0);
        g[nf] = __builtin_amdgcn_mfma_f32_16x16x32_bf16(cfh[ks], bl, g[nf], 0, 0, 0);
        g[nf] = __builtin_amdgcn_mfma_f32_16x16x32_bf16(cfl[ks], bh, g[nf], 0, 0, 0);
      }
    }
    // stage2: mask + decay on C/D frags (col=fr, row=fg*4+r), split to bf16
    {
      const bool full = (st < lt);
#pragma unroll
      for (int nf = 0; nf < 4; ++nf) {
        int sl = nf*16 + fr;
        float aS = acSs[sl];
#pragma unroll
        for (int r = 0; r < 4; ++r) {
          int ll = w*16 + fg*4 + r;
          float v = 0.f;
          if (full || ll >= sl) v = g[nf][r] * __expf(acLs[ll] - aS);
          ushort_t hh = f2bf(v);
          ushort_t lo2 = f2bf(v - bf2f(hh));
          GhS[w][(fg*4 + r)*XROW2 + sl] = hh;
          GlS[w][(fg*4 + r)*XROW2 + sl] = lo2;
        }
      }
    }
    __syncthreads();   // G visible (cross-lane) before stage3 reads
    // stage3: acc += G(16x64) · X^T, K=64, 3 planes
#pragma unroll
    for (int ks = 0; ks < 2; ++ks) {
      const int ko = ks*32 + fg*8;
      bf16x8 gh = *(const bf16x8*)&GhS[w][fr*XROW2 + ko];
      bf16x8 gl = *(const bf16x8*)&GlS[w][fr*XROW2 + ko];
#pragma unroll
      for (int nf = 0; nf < 4; ++nf) {
        int p = nf*16 + fr;
        int kb = ko ^ (((p >> 2) & 7) << 3);
        bf16x8 xh = *(const bf16x8*)&XhS[p*XROW2 + kb];
        bf16x8 xl = *(const bf16x8*)&XlS[p*XROW2 + kb];
        acc[nf] = __builtin_amdgcn_mfma_f32_16x16x32_bf16(gh, xh, acc[nf], 0, 0, 0);
        acc[nf] = __builtin_amdgcn_mfma_f32_16x16x32_bf16(gh, xl, acc[nf], 0, 0, 0);
        acc[nf] = __builtin_amdgcn_mfma_f32_16x16x32_bf16(gl, xh, acc[nf], 0, 0, 0);
      }
    }
  }

  // epilogue: + D*x, store
  const float Dh = Dv[h];
#pragma unroll
  for (int nf = 0; nf < 4; ++nf) {
    int p = nf*16 + fr;
#pragma unroll
    for (int r = 0; r < 4; ++r) {
      size_t row = seqbase + lt*64 + w*16 + fg*4 + r;
      float xval = hbc[row*CONV_DIM + h*HEAD_DIM + p];
      y[row*INTER + h*HEAD_DIM + p] = acc[nf][r] + Dh * xval;
    }
  }
}

// ---------------------------------------------------------------------------
__global__ __launch_bounds__(256) void states_kernel(
    const float* __restrict__ hbc, const float* __restrict__ acum,
    const float* __restrict__ dtp, float* __restrict__ states) {
  const int h = blockIdx.x, c = blockIdx.y, b = blockIdx.z;
  const int tid = threadIdx.x;
  __shared__ float Bs[64][132];
  __shared__ float Xd[64][68];
  const int ty = tid >> 4, tx = tid & 15;
  const size_t acbase = ((size_t)(b*NHEADS + h)*NC + c)*CHUNK;
  const float aclast = acum[acbase + CHUNK - 1];
  float acc[4][8] = {};

  for (int lt = 0; lt < 4; ++lt) {
    __syncthreads();
#pragma unroll
    for (int i = 0; i < 8; ++i) {
      int f = tid + 256*i;
      int l = f >> 5, n0 = (f & 31) << 2;
      *(float4*)&Bs[l][n0] =
        *(const float4*)(hbc + (size_t)(b*SEQ + c*CHUNK + lt*64 + l)*CONV_DIM + INTER + n0);
    }
#pragma unroll
    for (int i = 0; i < 4; ++i) {
      int f = tid + 256*i;
      int s = f >> 4, p0 = (f & 15) << 2;
      int sg = c*CHUNK + lt*64 + s;
      float mult = dtp[(size_t)(b*SEQ + sg)*NHEADS + h] * expf(aclast - acum[acbase + lt*64 + s]);
      float4 v = *(const float4*)(hbc + (size_t)(b*SEQ + sg)*CONV_DIM + h*HEAD_DIM + p0);
      *(float4*)&Xd[s][p0] = make_float4(v.x*mult, v.y*mult, v.z*mult, v.w*mult);
    }
    __syncthreads();
    for (int l = 0; l < 64; ++l) {
      float4 xv = *(const float4*)&Xd[l][ty*4];
      float4 b0 = *(const float4*)&Bs[l][tx*8];
      float4 b1 = *(const float4*)&Bs[l][tx*8+4];
      float xr[4] = {xv.x,xv.y,xv.z,xv.w};
      float br[8] = {b0.x,b0.y,b0.z,b0.w,b1.x,b1.y,b1.z,b1.w};
#pragma unroll
      for (int i = 0; i < 4; ++i)
#pragma unroll
        for (int j = 0; j < 8; ++j)
          acc[i][j] = fmaf(xr[i], br[j], acc[i][j]);
    }
  }
  float* sp = states + ((size_t)(b*NC + c)*NHEADS + h)*HEAD_DIM*NSTATE;
#pragma unroll
  for (int i = 0; i < 4; ++i) {
    int p = ty*4 + i;
    *(float4*)(sp + (size_t)p*NSTATE + tx*8)     = make_float4(acc[i][0],acc[i][1],acc[i][2],acc[i][3]);
    *(float4*)(sp + (size_t)p*NSTATE + tx*8 + 4) = make_float4(acc[i][4],acc[i][5],acc[i][6],acc[i][7]);
  }
}

// ---------------------------------------------------------------------------
// Inter-chunk scan, IN PLACE. Writes the carry (state BEFORE chunk c) as
// split-bf16 hi/lo planes into the same 32KB block: hi at ushort [0,8192),
// lo at [8192,16384). Read-all -> barrier -> write avoids the in-place race.
// ---------------------------------------------------------------------------
__global__ __launch_bounds__(256) void scan_kernel(
    float* __restrict__ st, const float* __restrict__ g) {
  const int bh = blockIdx.x;
  const int b = bh >> 5, h = bh & 31;
  const int tid = threadIdx.x;
  float carry[32];
#pragma unroll
  for (int i = 0; i < 32; ++i) carry[i] = 0.f;
  for (int c = 0; c < NC; ++c) {
    const float gc = g[(size_t)(b*NHEADS + h)*NC + c];
    float* base = st + ((size_t)(b*NC + c)*NHEADS + h)*HEAD_DIM*NSTATE;
    ushort_t* ub = (ushort_t*)base;
    float sv[32];
#pragma unroll
    for (int i = 0; i < 32; ++i) sv[i] = base[i*256 + tid];
    __syncthreads();   // all reads of this block done before plane writes
#pragma unroll
    for (int i = 0; i < 32; ++i) {
      int e = i*256 + tid;
      ushort_t hh = f2bf(carry[i]);
      ub[e]        = hh;
      ub[8192 + e] = f2bf(carry[i] - bf2f(hh));
      carry[i] = fmaf(carry[i], gc, sv[i]);
    }
  }
}

// ---------------------------------------------------------------------------
// Yo via MFMA, per (b,c,h): y[l,p] += exp(acum[l]) * sum_n C[l,n]*prev[p,n].
// Both operands K-contiguous: C from pre-split planes (global->reg frags),
// prev planes staged in LDS (~34.5 KB -> 4 blocks/CU). 4 lt strips per block.
// ---------------------------------------------------------------------------
#define PROW 136
__global__ __launch_bounds__(256) void yo_mfma_kernel(
    const ushort_t* __restrict__ Cph, const ushort_t* __restrict__ Cpl,
    const ushort_t* __restrict__ stp, const float* __restrict__ acum,
    float* __restrict__ y) {
  __shared__ __align__(16) ushort_t PhS[64*PROW], PlS[64*PROW];
  const int h = blockIdx.x, c = blockIdx.y, b = blockIdx.z;
  const int tid = threadIdx.x;
  const int lane = tid & 63, w = tid >> 6;
  const int fr = lane & 15, fg = lane >> 4;
  const size_t seqbase = (size_t)(b*SEQ + c*CHUNK);
  const size_t acbase  = ((size_t)(b*NHEADS + h)*NC + c)*CHUNK;

  // stage prev planes: 64 rows (p) x 128 (n), hi then lo
  const ushort_t* pb = stp + ((size_t)(b*NC + c)*NHEADS + h) * (size_t)(2*HEAD_DIM*NSTATE);
#pragma unroll
  for (int i = 0; i < 4; ++i) {
    int f = tid + 256*i; int r = f >> 4; int k8 = (f & 15) * 8;
    *(bf16x8*)&PhS[r*PROW + k8] = *(const bf16x8*)(pb + (size_t)r*128 + k8);
    *(bf16x8*)&PlS[r*PROW + k8] = *(const bf16x8*)(pb + 8192 + (size_t)r*128 + k8);
  }
  __syncthreads();

  for (int lt = 0; lt < 4; ++lt) {
    const size_t cg = (seqbase + lt*64 + w*16 + fr) * 128;
    f32x4 acc[4] = {};
#pragma unroll
    for (int ks = 0; ks < 4; ++ks) {
      int ko = ks*32 + fg*8;
      bf16x8 ah = *(const bf16x8*)(Cph + cg + ko);
      bf16x8 al = *(const bf16x8*)(Cpl + cg + ko);
#pragma unroll
      for (int nf = 0; nf < 4; ++nf) {
        const int rb = (nf*16 + fr) * PROW + ko;
        bf16x8 bh = *(const bf16x8*)&PhS[rb];
        bf16x8 bl = *(const bf16x8*)&PlS[rb];
        acc[nf] = __builtin_amdgcn_mfma_f32_16x16x32_bf16(ah, bh, acc[nf], 0, 0, 0);
        acc[nf] = __builtin_amdgcn_mfma_f32_16x16x32_bf16(ah, bl, acc[nf], 0, 0, 0);
        acc[nf] = __builtin_amdgcn_mfma_f32_16x16x32_bf16(al, bh, acc[nf], 0, 0, 0);
      }
    }
    // epilogue: y += exp(acum[l]) * acc   (C/D map: col=fr, row=fg*4+r)
#pragma unroll
    for (int r = 0; r < 4; ++r) {
      int lrow = lt*64 + w*16 + fg*4 + r;
      float e = __expf(acum[acbase + lrow]);
      float* yrow = y + (seqbase + lrow)*INTER + h*HEAD_DIM;
#pragma unroll
      for (int nf = 0; nf < 4; ++nf) {
        int p = nf*16 + fr;
        yrow[p] += e * acc[nf][r];
      }
    }
  }
}

// ---------------------------------------------------------------------------
__global__ __launch_bounds__(256) void rms_kernel(
    float* __restrict__ y, const float* __restrict__ gate,
    const float* __restrict__ norm_w) {
  const int bs = blockIdx.x;
  const int tid = threadIdx.x;
  float* yrow = y + (size_t)bs * INTER;
  const float* grow = gate + (size_t)bs * INTER;
  float yf[8];
  float ss = 0.f;
#pragma unroll
  for (int i = 0; i < 8; ++i) {
    int c = tid + i*256;
    float v = yrow[c];
    float gt = grow[c];
    float f = v * (gt / (1.f + expf(-gt)));
    yf[i] = f;
    ss += f*f;
  }
#pragma unroll
  for (int off = 32; off >= 1; off >>= 1) ss += __shfl_xor(ss, off, 64);
  __shared__ float red[4];
  if ((tid & 63) == 0) red[tid >> 6] = ss;
  __syncthreads();
  float total = red[0] + red[1] + red[2] + red[3];
  float sc = rsqrtf(total * (1.f/INTER) + EPS_F);
#pragma unroll
  for (int i = 0; i < 8; ++i) {
    int c = tid + i*256;
    yrow[c] = norm_w[c] * yf[i] * sc;
  }
}

__global__ void zero_kernel(float* p, size_t n) {
  size_t i = (size_t)blockIdx.x * blockDim.x + threadIdx.x;
  if (i < n) p[i] = 0.f;
}

// ---------------------------------------------------------------------------
extern "C" void kernel_launch(void* const* d_in, const int* in_sizes, int n_in,
                              void* d_out, int out_size, void* d_ws, size_t ws_size,
                              hipStream_t stream) {
  const float* hidden = (const float*)d_in[0];
  const float* in_w   = (const float*)d_in[1];
  const float* conv_w = (const float*)d_in[2];
  const float* conv_b = (const float*)d_in[3];
  const float* dt_b   = (const float*)d_in[4];
  const float* A_log  = (const float*)d_in[5];
  const float* Dv     = (const float*)d_in[6];
  const float* norm_w = (const float*)d_in[7];
  const float* out_w  = (const float*)d_in[8];
  float* out = (float*)d_out;

  const int M = BATCH*SEQ;

  const size_t sz_cin  = (size_t)M * CIN_DIM;
  const size_t sz_hbc  = (size_t)M * CONV_DIM;
  const size_t sz_dtp  = (size_t)M * NHEADS;
  const size_t sz_acum = (size_t)BATCH*NHEADS*NC*CHUNK;
  const size_t sz_gch  = (size_t)BATCH*NHEADS*NC;
  const size_t sz_R    = (size_t)BATCH*NC*NHEADS*HEAD_DIM*NSTATE;
  const size_t need = (sz_cin + sz_hbc + sz_dtp + sz_acum + sz_gch + sz_R) * sizeof(float);

  if (ws_size < need) {
    size_t n = (size_t)out_size;
    zero_kernel<<<(unsigned)((n + 255) / 256), 256, 0, stream>>>(out, n);
    return;
  }

  float* ws = (float*)d_ws;
  size_t o = 0;
  float* cin  = ws + o; o += sz_cin;
  float* hbc  = ws + o; o += sz_hbc;
  float* dtp  = ws + o; o += sz_dtp;
  float* acum = ws + o; o += sz_acum;
  float* gch  = ws + o; o += sz_gch;
  float* R    = ws + o; o += sz_R;

  float* y    = cin;   // cin dead after conv_kernel
  float* gate = hbc;   // hbc dead after step 8
  float* st   = R;     // R free for HL staging after yo

  ushort_t* hidhi = (ushort_t*)R;
  ushort_t* hidlo = hidhi + (size_t)M * H_SIZE;
  ushort_t* yhi   = (ushort_t*)hbc;
  ushort_t* ylo   = yhi + (size_t)M * INTER;

  // d_out scratch: weights at offset 0 (steps 1,8); B/C bf16 planes at +16MB
  ushort_t* wscr = (ushort_t*)out;
  const size_t MP = (size_t)M * 128;
  ushort_t* bcp  = (ushort_t*)((char*)d_out + (size_t)(16u << 20));
  ushort_t* Bph = bcp;
  ushort_t* Bpl = bcp + MP;
  ushort_t* Cph = bcp + 2*MP;
  ushort_t* Cpl = bcp + 3*MP;

  // 1) in_proj conv-input columns
  {
    int nA4 = (M * H_SIZE) / 4;
    int nW  = CIN_DIM * H_SIZE;
    convert_hl_kernel<<<2048, 256, 0, stream>>>(hidden, hidhi, hidlo, nA4);
    convert_hl_kernel<<<2048, 256, 0, stream>>>(in_w + (size_t)INTER*H_SIZE, wscr, wscr + nW, nW/4);
    gemm_hl_mfma_kernel<<<dim3((CIN_DIM+127)/128, M/128), 256, 0, stream>>>(
        hidhi, hidlo, wscr, wscr + nW, cin, M, CIN_DIM, H_SIZE);
  }
  // 2) causal conv + SiLU; softplus(dt)
  conv_kernel<<<dim3(M), 256, 0, stream>>>(cin, conv_w, conv_b, dt_b, hbc, dtp);
  // 2.5) pre-split B/C slabs of hbc to bf16 hi/lo planes
  convert_bc_kernel<<<2048, 256, 0, stream>>>(hbc, Bph, Bpl, Cph, Cpl);
  // 3) per-chunk cumsum of dt*A
  cumsum_kernel<<<dim3(NC, NHEADS, BATCH), 256, 0, stream>>>(dtp, A_log, acum, gch);
  // 4) intra-chunk Yd + D*x -> y  (MFMA, C-frags in regs)
  yd_mfma_kernel<<<dim3(NHEADS, NC*4, BATCH), 256, 0, stream>>>(
      Bph, Bpl, Cph, Cpl, hbc, acum, dtp, Dv, y);
  // 5) chunk states -> st
  states_kernel<<<dim3(NHEADS, NC, BATCH), 256, 0, stream>>>(hbc, acum, dtp, st);
  // 6) inter-chunk scan; prev written as split-bf16 planes in place
  scan_kernel<<<dim3(BATCH*NHEADS), 256, 0, stream>>>(st, gch);
  // 7) inter-chunk Yo -> y (+=)  (MFMA)
  yo_mfma_kernel<<<dim3(NHEADS, NC, BATCH), 256, 0, stream>>>(
      Cph, Cpl, (const ushort_t*)st, acum, y);
  // 8) gate columns of in_proj
  {
    int nA4 = (M * H_SIZE) / 4;
    int nW  = INTER * H_SIZE;
    convert_hl_kernel<<<2048, 256, 0, stream>>>(hidden, hidhi, hidlo, nA4);
    convert_hl_kernel<<<2048, 256, 0, stream>>>(in_w, wscr, wscr + nW, nW/4);
    gemm_hl_mfma_kernel<<<dim3(INTER/128, M/128), 256, 0, stream>>>(
        hidhi, hidlo, wscr, wscr + nW, gate, M, INTER, H_SIZE);
  }
  // 9) gated RMSNorm in place on y
  rms_kernel<<<dim3(M), 256, 0, stream>>>(y, gate, norm_w);
  // 10) out_proj (weights staged in R, free now)
  {
    int nY4 = (M * INTER) / 4;
    int nW  = H_SIZE * INTER;
    ushort_t* whi2 = (ushort_t*)R;
    convert_hl_kernel<<<2048, 256, 0, stream>>>(y, yhi, ylo, nY4);
    convert_hl_kernel<<<2048, 256, 0, stream>>>(out_w, whi2, whi2 + nW, nW/4);
    gemm_hl_mfma_kernel<<<dim3(H_SIZE/128, M/128), 256, 0, stream>>>(
        yhi, ylo, whi2, whi2 + nW, out, M, H_SIZE, INTER);
  }
}

// Round 9
// 812.092 us; speedup vs baseline: 2.8735x; 1.0204x over previous
//
#include <hip/hip_runtime.h>
#include <hip/hip_bf16.h>
#include <math.h>

#define H_SIZE   1024
#define INTER    2048
#define NHEADS   32
#define HEAD_DIM 64
#define NSTATE   128
#define KCONV    4
#define CHUNK    256
#define CONV_DIM (INTER + 2*NSTATE)            // 2304
#define CIN_DIM  (CONV_DIM + NHEADS)           // 2336 (hBC + dt)
#define PROJ_DIM (2*INTER + 2*NSTATE + NHEADS) // 4384
#define BATCH    2
#define SEQ      4096
#define NC       (SEQ/CHUNK)                   // 16
#define EPS_F    1e-5f

typedef __attribute__((ext_vector_type(8))) short bf16x8;   // 8 bf16 in 4 VGPRs
typedef __attribute__((ext_vector_type(4))) float f32x4;
typedef unsigned short ushort_t;

__device__ __forceinline__ ushort_t f2bf(float x) {   // RNE float->bf16 bits
  unsigned u = __float_as_uint(x);
  u += 0x7fffu + ((u >> 16) & 1u);
  return (ushort_t)(u >> 16);
}
__device__ __forceinline__ float bf2f(ushort_t h) {
  return __uint_as_float((unsigned)h << 16);
}

// ---------------------------------------------------------------------------
// Split fp32 x into hi+lo bf16 planes: x ~= hi + lo (rel err ~2^-17).
// ---------------------------------------------------------------------------
__global__ __launch_bounds__(256) void convert_hl_kernel(
    const float* __restrict__ x, ushort_t* __restrict__ hi,
    ushort_t* __restrict__ lo, int n4) {
  int idx = blockIdx.x * 256 + threadIdx.x;
  int stride = gridDim.x * 256;
  for (int i = idx; i < n4; i += stride) {
    const float* p = x + (size_t)i * 4;
    float v0 = p[0], v1 = p[1], v2 = p[2], v3 = p[3];
    ushort_t h0 = f2bf(v0), h1 = f2bf(v1), h2 = f2bf(v2), h3 = f2bf(v3);
    ushort_t l0 = f2bf(v0 - bf2f(h0));
    ushort_t l1 = f2bf(v1 - bf2f(h1));
    ushort_t l2 = f2bf(v2 - bf2f(h2));
    ushort_t l3 = f2bf(v3 - bf2f(h3));
    *(uint2*)(hi + (size_t)i * 4) =
        make_uint2((unsigned)h0 | ((unsigned)h1 << 16), (unsigned)h2 | ((unsigned)h3 << 16));
    *(uint2*)(lo + (size_t)i * 4) =
        make_uint2((unsigned)l0 | ((unsigned)l1 << 16), (unsigned)l2 | ((unsigned)l3 << 16));
  }
}

// ---------------------------------------------------------------------------
// Pre-split the B (cols 2048..2176) and C (cols 2176..2304) slabs of hbc
// into bf16 hi/lo planes [M][128] each.
// ---------------------------------------------------------------------------
__global__ __launch_bounds__(256) void convert_bc_kernel(
    const float* __restrict__ hbc, ushort_t* __restrict__ Bph,
    ushort_t* __restrict__ Bpl, ushort_t* __restrict__ Cph,
    ushort_t* __restrict__ Cpl) {
  const int n4 = (BATCH*SEQ) * 64;
  int idx = blockIdx.x * 256 + threadIdx.x;
  int stride = gridDim.x * 256;
  for (int i = idx; i < n4; i += stride) {
    int row = i >> 6;
    int c4 = (i & 63) * 4;
    float4 v = *(const float4*)(hbc + (size_t)row*CONV_DIM + INTER + c4);
    ushort_t h0 = f2bf(v.x), h1 = f2bf(v.y), h2 = f2bf(v.z), h3 = f2bf(v.w);
    ushort_t l0 = f2bf(v.x - bf2f(h0)), l1 = f2bf(v.y - bf2f(h1));
    ushort_t l2 = f2bf(v.z - bf2f(h2)), l3 = f2bf(v.w - bf2f(h3));
    uint2 hp = make_uint2((unsigned)h0 | ((unsigned)h1 << 16), (unsigned)h2 | ((unsigned)h3 << 16));
    uint2 lp = make_uint2((unsigned)l0 | ((unsigned)l1 << 16), (unsigned)l2 | ((unsigned)l3 << 16));
    if (c4 < 128) {
      *(uint2*)(Bph + (size_t)row*128 + c4) = hp;
      *(uint2*)(Bpl + (size_t)row*128 + c4) = lp;
    } else {
      *(uint2*)(Cph + (size_t)row*128 + (c4 - 128)) = hp;
      *(uint2*)(Cpl + (size_t)row*128 + (c4 - 128)) = lp;
    }
  }
}

// ---------------------------------------------------------------------------
// C[m,n] = sum_k A[m,k]*W[n,k] via split-bf16 MFMA (hi*hi + hi*lo + lo*hi).
// 128x128 tile, BK=32, 256 threads = 4 waves (2x2), wave tile 64x64.
// 1D grid with bijective XCD chunking + G=4 M-grouping for L2 locality:
// working set/XCD ~ 4 A-panels + 1 W-panel ~ 2.5MB < 4MB L2.
// Requires nwg % 8 == 0 and (M/128) % 4 == 0 (all call sites satisfy).
// ---------------------------------------------------------------------------
#define LROW 40
__global__ __launch_bounds__(256) void gemm_hl_mfma_kernel(
    const ushort_t* __restrict__ Ahi, const ushort_t* __restrict__ Alo,
    const ushort_t* __restrict__ Whi, const ushort_t* __restrict__ Wlo,
    float* __restrict__ C, int M, int N, int K, int nx) {
  __shared__ __align__(16) ushort_t Ah[128*LROW], Al[128*LROW];
  __shared__ __align__(16) ushort_t Wh[128*LROW], Wl[128*LROW];
  const int tid = threadIdx.x;
  const int lane = tid & 63, wid = tid >> 6;
  const int wr = wid >> 1, wc = wid & 1;
  const int fr = lane & 15, fg = lane >> 4;

  // XCD-bijective swizzle (consecutive HW blocks round-robin XCDs ->
  // give each XCD a contiguous logical chunk), then G=4 M-grouping.
  const int cpx = gridDim.x >> 3;
  const int logical = (blockIdx.x & 7) * cpx + (blockIdx.x >> 3);
  const int grp = logical / (nx * 4);
  const int rem = logical - grp * (nx * 4);
  const int bx = rem >> 2;
  const int by = grp * 4 + (rem & 3);
  const int m0 = by * 128, n0 = bx * 128;

  const int r0 = tid >> 2;
  const int kseg = (tid & 3) * 8;
  const int r1 = r0 + 64;
  const size_t a0 = (size_t)(m0 + r0) * K + kseg;
  const size_t a1 = (size_t)(m0 + r1) * K + kseg;
  const size_t w0 = (size_t)(n0 + r0) * K + kseg;
  const size_t w1 = (size_t)(n0 + r1) * K + kseg;
  const bool wv0 = (n0 + r0) < N, wv1 = (n0 + r1) < N;

  bf16x8 gA0, gA1, gAl0, gAl1, gW0, gW1, gWl0, gWl1;
  const bf16x8 z8 = {};
  f32x4 acc[4][4] = {};

  auto glod = [&](int k0) {
    gA0  = *(const bf16x8*)(Ahi + a0 + k0);
    gA1  = *(const bf16x8*)(Ahi + a1 + k0);
    gAl0 = *(const bf16x8*)(Alo + a0 + k0);
    gAl1 = *(const bf16x8*)(Alo + a1 + k0);
    gW0  = wv0 ? *(const bf16x8*)(Whi + w0 + k0) : z8;
    gW1  = wv1 ? *(const bf16x8*)(Whi + w1 + k0) : z8;
    gWl0 = wv0 ? *(const bf16x8*)(Wlo + w0 + k0) : z8;
    gWl1 = wv1 ? *(const bf16x8*)(Wlo + w1 + k0) : z8;
  };

  glod(0);
  for (int k0 = 0; k0 < K; k0 += 32) {
    __syncthreads();
    *(bf16x8*)&Ah[r0*LROW + kseg] = gA0;
    *(bf16x8*)&Ah[r1*LROW + kseg] = gA1;
    *(bf16x8*)&Al[r0*LROW + kseg] = gAl0;
    *(bf16x8*)&Al[r1*LROW + kseg] = gAl1;
    *(bf16x8*)&Wh[r0*LROW + kseg] = gW0;
    *(bf16x8*)&Wh[r1*LROW + kseg] = gW1;
    *(bf16x8*)&Wl[r0*LROW + kseg] = gWl0;
    *(bf16x8*)&Wl[r1*LROW + kseg] = gWl1;
    __syncthreads();
    if (k0 + 32 < K) glod(k0 + 32);

    bf16x8 wh[4], wl[4];
#pragma unroll
    for (int nf = 0; nf < 4; ++nf) {
      int off = (wc*64 + nf*16 + fr) * LROW + 8*fg;
      wh[nf] = *(const bf16x8*)&Wh[off];
      wl[nf] = *(const bf16x8*)&Wl[off];
    }
#pragma unroll
    for (int mf = 0; mf < 4; ++mf) {
      int aoff = (wr*64 + mf*16 + fr) * LROW + 8*fg;
      bf16x8 ah = *(const bf16x8*)&Ah[aoff];
      bf16x8 al = *(const bf16x8*)&Al[aoff];
#pragma unroll
      for (int nf = 0; nf < 4; ++nf) {
        acc[mf][nf] = __builtin_amdgcn_mfma_f32_16x16x32_bf16(ah, wh[nf], acc[mf][nf], 0, 0, 0);
        acc[mf][nf] = __builtin_amdgcn_mfma_f32_16x16x32_bf16(ah, wl[nf], acc[mf][nf], 0, 0, 0);
        acc[mf][nf] = __builtin_amdgcn_mfma_f32_16x16x32_bf16(al, wh[nf], acc[mf][nf], 0, 0, 0);
      }
    }
  }

#pragma unroll
  for (int mf = 0; mf < 4; ++mf)
#pragma unroll
    for (int nf = 0; nf < 4; ++nf) {
      int col = n0 + wc*64 + nf*16 + fr;
      if (col < N) {
        size_t base = (size_t)(m0 + wr*64 + mf*16 + fg*4) * N + col;
        f32x4 v = acc[mf][nf];
        C[base]               = v[0];
        C[base + (size_t)N]   = v[1];
        C[base + 2*(size_t)N] = v[2];
        C[base + 3*(size_t)N] = v[3];
      }
    }
}

// ---------------------------------------------------------------------------
// Causal depthwise conv (K=4) + bias + SiLU; softplus(dt + dt_bias).
// ---------------------------------------------------------------------------
__global__ __launch_bounds__(256) void conv_kernel(
    const float* __restrict__ cin, const float* __restrict__ cw,
    const float* __restrict__ cb, const float* __restrict__ dtb,
    float* __restrict__ hbc, float* __restrict__ dtp) {
  const int bs = blockIdx.x;
  const int b = bs / SEQ, s = bs % SEQ;
  const int tid = threadIdx.x;
  const float* base = cin + (size_t)b * SEQ * CIN_DIM;
  for (int c = tid; c < CONV_DIM; c += 256) {
    float acc = cb[c];
#pragma unroll
    for (int k = 0; k < KCONV; ++k) {
      int sp = s - (KCONV-1) + k;
      if (sp >= 0) acc = fmaf(cw[c*KCONV + k], base[(size_t)sp * CIN_DIM + c], acc);
    }
    acc = acc / (1.f + expf(-acc));  // silu
    hbc[(size_t)bs * CONV_DIM + c] = acc;
  }
  if (tid < NHEADS) {
    float d = cin[(size_t)bs * CIN_DIM + CONV_DIM + tid] + dtb[tid];
    d = (d > 20.f) ? d : log1pf(expf(d));   // softplus
    dtp[(size_t)bs * NHEADS + tid] = d;
  }
}

// ---------------------------------------------------------------------------
__global__ __launch_bounds__(256) void cumsum_kernel(
    const float* __restrict__ dtp, const float* __restrict__ A_log,
    float* __restrict__ acum, float* __restrict__ gch) {
  const int c = blockIdx.x, h = blockIdx.y, b = blockIdx.z;
  const int tid = threadIdx.x;
  __shared__ float sm[CHUNK];
  const float A = -expf(A_log[h]);
  const int s = c * CHUNK + tid;
  float a = dtp[(size_t)(b*SEQ + s)*NHEADS + h] * A;
  sm[tid] = a;
  __syncthreads();
  for (int off = 1; off < CHUNK; off <<= 1) {
    float v = 0.f;
    if (tid >= off) v = sm[tid - off];
    __syncthreads();
    sm[tid] += v;
    __syncthreads();
  }
  float ac = sm[tid];
  acum[((size_t)(b*NHEADS + h)*NC + c)*CHUNK + tid] = ac;
  if (tid == CHUNK-1) gch[(size_t)(b*NHEADS + h)*NC + c] = expf(ac);
}

// ---------------------------------------------------------------------------
// Yd (intra-chunk) via MFMA, per (b, c, lt, h). 4 waves, each a 16-row strip.
// C fragments in registers; B in LDS; X transposed+swizzled in LDS.
// ---------------------------------------------------------------------------
#define CBROW 136
#define XROW2 72
__global__ __launch_bounds__(256) void yd_mfma_kernel(
    const ushort_t* __restrict__ Bph, const ushort_t* __restrict__ Bpl,
    const ushort_t* __restrict__ Cph, const ushort_t* __restrict__ Cpl,
    const float* __restrict__ hbc, const float* __restrict__ acum,
    const float* __restrict__ dtp, const float* __restrict__ Dv,
    float* __restrict__ y) {
  __shared__ __align__(16) ushort_t BhS[64*CBROW], BlS[64*CBROW];
  __shared__ __align__(16) ushort_t XhS[64*XROW2], XlS[64*XROW2];
  __shared__ __align__(16) ushort_t GhS[4][16*XROW2], GlS[4][16*XROW2];
  __shared__ float acLs[64], acSs[64];

  const int h = blockIdx.x;
  const int c = blockIdx.y >> 2, lt = blockIdx.y & 3;
  const int b = blockIdx.z;
  const int tid = threadIdx.x;
  const int lane = tid & 63, w = tid >> 6;
  const int fr = lane & 15, fg = lane >> 4;

  const size_t seqbase = (size_t)(b*SEQ + c*CHUNK);
  const size_t acbase  = ((size_t)(b*NHEADS + h)*NC + c)*CHUNK;

  bf16x8 cfh[4], cfl[4];
  {
    const size_t cg = (seqbase + lt*64 + w*16 + fr) * 128;
#pragma unroll
    for (int ks = 0; ks < 4; ++ks) {
      int ko = ks*32 + fg*8;
      cfh[ks] = *(const bf16x8*)(Cph + cg + ko);
      cfl[ks] = *(const bf16x8*)(Cpl + cg + ko);
    }
  }
  if (tid < 64) acLs[tid] = acum[acbase + lt*64 + tid];

  f32x4 acc[4] = {};

  for (int st = 0; st <= lt; ++st) {
    __syncthreads();
    {
      const size_t g0 = (seqbase + st*64) * 128;
#pragma unroll
      for (int i = 0; i < 4; ++i) {
        int f = tid + 256*i; int r = f >> 4; int k8 = (f & 15) * 8;
        *(bf16x8*)&BhS[r*CBROW + k8] = *(const bf16x8*)(Bph + g0 + (size_t)r*128 + k8);
        *(bf16x8*)&BlS[r*CBROW + k8] = *(const bf16x8*)(Bpl + g0 + (size_t)r*128 + k8);
      }
    }
#pragma unroll
    for (int i = 0; i < 4; ++i) {
      int f = tid + 256*i; int s = f >> 4; int p0 = (f & 15) * 4;
      size_t row = seqbase + st*64 + s;
      float dtv = dtp[row*NHEADS + h];
      float4 xv = *(const float4*)(hbc + row*CONV_DIM + h*HEAD_DIM + p0);
      float vals[4] = {xv.x*dtv, xv.y*dtv, xv.z*dtv, xv.w*dtv};
#pragma unroll
      for (int j = 0; j < 4; ++j) {
        int p = p0 + j;
        int sw = s ^ (((p >> 2) & 7) << 3);
        ushort_t hh = f2bf(vals[j]);
        ushort_t ll = f2bf(vals[j] - bf2f(hh));
        XhS[p*XROW2 + sw] = hh;
        XlS[p*XROW2 + sw] = ll;
      }
    }
    if (tid < 64) acSs[tid] = acum[acbase + st*64 + tid];
    __syncthreads();

    f32x4 g[4] = {};
#pragma unroll
    for (int ks = 0; ks < 4; ++ks) {
      const int ko = ks*32 + fg*8;
#pragma unroll
      for (int nf = 0; nf < 4; ++nf) {
        const int rb = (nf*16 + fr) * CBROW + ko;
        bf16x8 bh = *(const bf16x8*)&BhS[rb];
        bf16x8 bl = *(const bf16x8*)&BlS[rb];
        g[nf] = __builtin_amdgcn_mfma_f32_16x16x32_bf16(cfh[ks], bh, g[nf], 0, 0, 0);
        g[nf] = __builtin_amdgcn_mfma_f32_16x16x32_bf16(cfh[ks], bl, g[nf], 0, 0, 0);
        g[nf] = __builtin_amdgcn_mfma_f32_16x16x32_bf16(cfl[ks], bh, g[nf], 0, 0, 0);
      }
    }
    {
      const bool full = (st < lt);
#pragma unroll
      for (int nf = 0; nf < 4; ++nf) {
        int sl = nf*16 + fr;
        float aS = acSs[sl];
#pragma unroll
        for (int r = 0; r < 4; ++r) {
          int ll = w*16 + fg*4 + r;
          float v = 0.f;
          if (full || ll >= sl) v = g[nf][r] * __expf(acLs[ll] - aS);
          ushort_t hh = f2bf(v);
          ushort_t lo2 = f2bf(v - bf2f(hh));
          GhS[w][(fg*4 + r)*XROW2 + sl] = hh;
          GlS[w][(fg*4 + r)*XROW2 + sl] = lo2;
        }
      }
    }
    __syncthreads();
#pragma unroll
    for (int ks = 0; ks < 2; ++ks) {
      const int ko = ks*32 + fg*8;
      bf16x8 gh = *(const bf16x8*)&GhS[w][fr*XROW2 + ko];
      bf16x8 gl = *(const bf16x8*)&GlS[w][fr*XROW2 + ko];
#pragma unroll
      for (int nf = 0; nf < 4; ++nf) {
        int p = nf*16 + fr;
        int kb = ko ^ (((p >> 2) & 7) << 3);
        bf16x8 xh = *(const bf16x8*)&XhS[p*XROW2 + kb];
        bf16x8 xl = *(const bf16x8*)&XlS[p*XROW2 + kb];
        acc[nf] = __builtin_amdgcn_mfma_f32_16x16x32_bf16(gh, xh, acc[nf], 0, 0, 0);
        acc[nf] = __builtin_amdgcn_mfma_f32_16x16x32_bf16(gh, xl, acc[nf], 0, 0, 0);
        acc[nf] = __builtin_amdgcn_mfma_f32_16x16x32_bf16(gl, xh, acc[nf], 0, 0, 0);
      }
    }
  }

  const float Dh = Dv[h];
#pragma unroll
  for (int nf = 0; nf < 4; ++nf) {
    int p = nf*16 + fr;
#pragma unroll
    for (int r = 0; r < 4; ++r) {
      size_t row = seqbase + lt*64 + w*16 + fg*4 + r;
      float xval = hbc[row*CONV_DIM + h*HEAD_DIM + p];
      y[row*INTER + h*HEAD_DIM + p] = acc[nf][r] + Dh * xval;
    }
  }
}

// ---------------------------------------------------------------------------
// states via MFMA, per (b,c,h): states[p,n] = sum_l X'[p,l]*B[l,n], where
// X'[p,l] = x[l,p]*dt[l]*exp(aclast-acum[l]). Both operands staged transposed
// (l-contiguous) in LDS with the yd-validated XOR swizzle. 4 waves: wave w
// owns p-strip w*16..w*16+16; acc[8] covers n=0..128. 3-plane split-bf16.
// LDS ~55 KB -> 2 blocks/CU.
// ---------------------------------------------------------------------------
#define SXROW 72
__global__ __launch_bounds__(256) void states_mfma_kernel(
    const ushort_t* __restrict__ Bph, const ushort_t* __restrict__ Bpl,
    const float* __restrict__ hbc, const float* __restrict__ acum,
    const float* __restrict__ dtp, float* __restrict__ states) {
  __shared__ __align__(16) ushort_t XhS[64*SXROW], XlS[64*SXROW];   // [p][l]
  __shared__ __align__(16) ushort_t BhS[128*SXROW], BlS[128*SXROW]; // [n][l]
  const int h = blockIdx.x, c = blockIdx.y, b = blockIdx.z;
  const int tid = threadIdx.x;
  const int lane = tid & 63, w = tid >> 6;
  const int fr = lane & 15, fg = lane >> 4;
  const size_t seqbase = (size_t)(b*SEQ + c*CHUNK);
  const size_t acbase  = ((size_t)(b*NHEADS + h)*NC + c)*CHUNK;
  const float aclast = acum[acbase + CHUNK - 1];
  f32x4 acc[8] = {};

  for (int lt = 0; lt < 4; ++lt) {
    __syncthreads();
    // stage X^T[p][l]: thread item = (l, p-seg of 4)
#pragma unroll
    for (int i = 0; i < 4; ++i) {
      int f = tid + 256*i; int l = f >> 4; int p0 = (f & 15) * 4;
      size_t row = seqbase + lt*64 + l;
      float mult = dtp[row*NHEADS + h] * __expf(aclast - acum[acbase + lt*64 + l]);
      float4 xv = *(const float4*)(hbc + row*CONV_DIM + h*HEAD_DIM + p0);
      float vals[4] = {xv.x*mult, xv.y*mult, xv.z*mult, xv.w*mult};
#pragma unroll
      for (int j = 0; j < 4; ++j) {
        int p = p0 + j;
        int sw = l ^ (((p >> 2) & 7) << 3);
        ushort_t hh = f2bf(vals[j]);
        XhS[p*SXROW + sw] = hh;
        XlS[p*SXROW + sw] = f2bf(vals[j] - bf2f(hh));
      }
    }
    // stage B^T[n][l] from planes: thread item = (l, n-seg of 8)
#pragma unroll
    for (int i = 0; i < 4; ++i) {
      int f = tid + 256*i; int l = f >> 4; int n8 = (f & 15) * 8;
      size_t g0 = (seqbase + lt*64 + l) * 128 + n8;
      bf16x8 bh = *(const bf16x8*)(Bph + g0);
      bf16x8 bl = *(const bf16x8*)(Bpl + g0);
#pragma unroll
      for (int j = 0; j < 8; ++j) {
        int n = n8 + j;
        int sw = l ^ (((n >> 2) & 7) << 3);
        BhS[n*SXROW + sw] = (ushort_t)bh[j];
        BlS[n*SXROW + sw] = (ushort_t)bl[j];
      }
    }
    __syncthreads();
    // MFMA: K=64 (2 x 32), 3 planes, 8 n-fragments
#pragma unroll
    for (int ks = 0; ks < 2; ++ks) {
      const int ko = ks*32 + fg*8;
      const int pa = w*16 + fr;
      const int ka = ko ^ (((pa >> 2) & 7) << 3);
      bf16x8 ah = *(const bf16x8*)&XhS[pa*SXROW + ka];
      bf16x8 al = *(const bf16x8*)&XlS[pa*SXROW + ka];
#pragma unroll
      for (int nf = 0; nf < 8; ++nf) {
        const int nb = nf*16 + fr;
        const int kb = ko ^ (((nb >> 2) & 7) << 3);
        bf16x8 bh = *(const bf16x8*)&BhS[nb*SXROW + kb];
        bf16x8 bl = *(const bf16x8*)&BlS[nb*SXROW + kb];
        acc[nf] = __builtin_amdgcn_mfma_f32_16x16x32_bf16(ah, bh, acc[nf], 0, 0, 0);
        acc[nf] = __builtin_amdgcn_mfma_f32_16x16x32_bf16(ah, bl, acc[nf], 0, 0, 0);
        acc[nf] = __builtin_amdgcn_mfma_f32_16x16x32_bf16(al, bh, acc[nf], 0, 0, 0);
      }
    }
  }
  // epilogue: states[p][n]; C/D map col=fr -> n, row=fg*4+r -> p (within strip)
  float* sp = states + ((size_t)(b*NC + c)*NHEADS + h)*HEAD_DIM*NSTATE;
#pragma unroll
  for (int nf = 0; nf < 8; ++nf) {
    int n = nf*16 + fr;
#pragma unroll
    for (int r = 0; r < 4; ++r) {
      int p = w*16 + fg*4 + r;
      sp[(size_t)p*NSTATE + n] = acc[nf][r];
    }
  }
}

// ---------------------------------------------------------------------------
// Inter-chunk scan, IN PLACE. Writes the carry (state BEFORE chunk c) as
// split-bf16 hi/lo planes into the same 32KB block.
// ---------------------------------------------------------------------------
__global__ __launch_bounds__(256) void scan_kernel(
    float* __restrict__ st, const float* __restrict__ g) {
  const int bh = blockIdx.x;
  const int b = bh >> 5, h = bh & 31;
  const int tid = threadIdx.x;
  float carry[32];
#pragma unroll
  for (int i = 0; i < 32; ++i) carry[i] = 0.f;
  for (int c = 0; c < NC; ++c) {
    const float gc = g[(size_t)(b*NHEADS + h)*NC + c];
    float* base = st + ((size_t)(b*NC + c)*NHEADS + h)*HEAD_DIM*NSTATE;
    ushort_t* ub = (ushort_t*)base;
    float sv[32];
#pragma unroll
    for (int i = 0; i < 32; ++i) sv[i] = base[i*256 + tid];
    __syncthreads();
#pragma unroll
    for (int i = 0; i < 32; ++i) {
      int e = i*256 + tid;
      ushort_t hh = f2bf(carry[i]);
      ub[e]        = hh;
      ub[8192 + e] = f2bf(carry[i] - bf2f(hh));
      carry[i] = fmaf(carry[i], gc, sv[i]);
    }
  }
}

// ---------------------------------------------------------------------------
// Yo via MFMA, per (b,c,h): y[l,p] += exp(acum[l]) * sum_n C[l,n]*prev[p,n].
// ---------------------------------------------------------------------------
#define PROW 136
__global__ __launch_bounds__(256) void yo_mfma_kernel(
    const ushort_t* __restrict__ Cph, const ushort_t* __restrict__ Cpl,
    const ushort_t* __restrict__ stp, const float* __restrict__ acum,
    float* __restrict__ y) {
  __shared__ __align__(16) ushort_t PhS[64*PROW], PlS[64*PROW];
  const int h = blockIdx.x, c = blockIdx.y, b = blockIdx.z;
  const int tid = threadIdx.x;
  const int lane = tid & 63, w = tid >> 6;
  const int fr = lane & 15, fg = lane >> 4;
  const size_t seqbase = (size_t)(b*SEQ + c*CHUNK);
  const size_t acbase  = ((size_t)(b*NHEADS + h)*NC + c)*CHUNK;

  const ushort_t* pb = stp + ((size_t)(b*NC + c)*NHEADS + h) * (size_t)(2*HEAD_DIM*NSTATE);
#pragma unroll
  for (int i = 0; i < 4; ++i) {
    int f = tid + 256*i; int r = f >> 4; int k8 = (f & 15) * 8;
    *(bf16x8*)&PhS[r*PROW + k8] = *(const bf16x8*)(pb + (size_t)r*128 + k8);
    *(bf16x8*)&PlS[r*PROW + k8] = *(const bf16x8*)(pb + 8192 + (size_t)r*128 + k8);
  }
  __syncthreads();

  for (int lt = 0; lt < 4; ++lt) {
    const size_t cg = (seqbase + lt*64 + w*16 + fr) * 128;
    f32x4 acc[4] = {};
#pragma unroll
    for (int ks = 0; ks < 4; ++ks) {
      int ko = ks*32 + fg*8;
      bf16x8 ah = *(const bf16x8*)(Cph + cg + ko);
      bf16x8 al = *(const bf16x8*)(Cpl + cg + ko);
#pragma unroll
      for (int nf = 0; nf < 4; ++nf) {
        const int rb = (nf*16 + fr) * PROW + ko;
        bf16x8 bh = *(const bf16x8*)&PhS[rb];
        bf16x8 bl = *(const bf16x8*)&PlS[rb];
        acc[nf] = __builtin_amdgcn_mfma_f32_16x16x32_bf16(ah, bh, acc[nf], 0, 0, 0);
        acc[nf] = __builtin_amdgcn_mfma_f32_16x16x32_bf16(ah, bl, acc[nf], 0, 0, 0);
        acc[nf] = __builtin_amdgcn_mfma_f32_16x16x32_bf16(al, bh, acc[nf], 0, 0, 0);
      }
    }
#pragma unroll
    for (int r = 0; r < 4; ++r) {
      int lrow = lt*64 + w*16 + fg*4 + r;
      float e = __expf(acum[acbase + lrow]);
      float* yrow = y + (seqbase + lrow)*INTER + h*HEAD_DIM;
#pragma unroll
      for (int nf = 0; nf < 4; ++nf) {
        int p = nf*16 + fr;
        yrow[p] += e * acc[nf][r];
      }
    }
  }
}

// ---------------------------------------------------------------------------
__global__ __launch_bounds__(256) void rms_kernel(
    float* __restrict__ y, const float* __restrict__ gate,
    const float* __restrict__ norm_w) {
  const int bs = blockIdx.x;
  const int tid = threadIdx.x;
  float* yrow = y + (size_t)bs * INTER;
  const float* grow = gate + (size_t)bs * INTER;
  float yf[8];
  float ss = 0.f;
#pragma unroll
  for (int i = 0; i < 8; ++i) {
    int c = tid + i*256;
    float v = yrow[c];
    float gt = grow[c];
    float f = v * (gt / (1.f + expf(-gt)));
    yf[i] = f;
    ss += f*f;
  }
#pragma unroll
  for (int off = 32; off >= 1; off >>= 1) ss += __shfl_xor(ss, off, 64);
  __shared__ float red[4];
  if ((tid & 63) == 0) red[tid >> 6] = ss;
  __syncthreads();
  float total = red[0] + red[1] + red[2] + red[3];
  float sc = rsqrtf(total * (1.f/INTER) + EPS_F);
#pragma unroll
  for (int i = 0; i < 8; ++i) {
    int c = tid + i*256;
    yrow[c] = norm_w[c] * yf[i] * sc;
  }
}

__global__ void zero_kernel(float* p, size_t n) {
  size_t i = (size_t)blockIdx.x * blockDim.x + threadIdx.x;
  if (i < n) p[i] = 0.f;
}

// ---------------------------------------------------------------------------
extern "C" void kernel_launch(void* const* d_in, const int* in_sizes, int n_in,
                              void* d_out, int out_size, void* d_ws, size_t ws_size,
                              hipStream_t stream) {
  const float* hidden = (const float*)d_in[0];
  const float* in_w   = (const float*)d_in[1];
  const float* conv_w = (const float*)d_in[2];
  const float* conv_b = (const float*)d_in[3];
  const float* dt_b   = (const float*)d_in[4];
  const float* A_log  = (const float*)d_in[5];
  const float* Dv     = (const float*)d_in[6];
  const float* norm_w = (const float*)d_in[7];
  const float* out_w  = (const float*)d_in[8];
  float* out = (float*)d_out;

  const int M = BATCH*SEQ;

  const size_t sz_cin  = (size_t)M * CIN_DIM;
  const size_t sz_hbc  = (size_t)M * CONV_DIM;
  const size_t sz_dtp  = (size_t)M * NHEADS;
  const size_t sz_acum = (size_t)BATCH*NHEADS*NC*CHUNK;
  const size_t sz_gch  = (size_t)BATCH*NHEADS*NC;
  const size_t sz_R    = (size_t)BATCH*NC*NHEADS*HEAD_DIM*NSTATE;
  const size_t need = (sz_cin + sz_hbc + sz_dtp + sz_acum + sz_gch + sz_R) * sizeof(float);

  if (ws_size < need) {
    size_t n = (size_t)out_size;
    zero_kernel<<<(unsigned)((n + 255) / 256), 256, 0, stream>>>(out, n);
    return;
  }

  float* ws = (float*)d_ws;
  size_t o = 0;
  float* cin  = ws + o; o += sz_cin;
  float* hbc  = ws + o; o += sz_hbc;
  float* dtp  = ws + o; o += sz_dtp;
  float* acum = ws + o; o += sz_acum;
  float* gch  = ws + o; o += sz_gch;
  float* R    = ws + o; o += sz_R;

  float* y    = cin;   // cin dead after conv_kernel
  float* gate = hbc;   // hbc dead after step 8
  float* st   = R;     // R free between gemms

  ushort_t* hidhi = (ushort_t*)R;
  ushort_t* hidlo = hidhi + (size_t)M * H_SIZE;
  ushort_t* yhi   = (ushort_t*)hbc;
  ushort_t* ylo   = yhi + (size_t)M * INTER;

  // d_out scratch: weights at offset 0 (steps 1,8); B/C bf16 planes at +16MB
  ushort_t* wscr = (ushort_t*)out;
  const size_t MP = (size_t)M * 128;
  ushort_t* bcp  = (ushort_t*)((char*)d_out + (size_t)(16u << 20));
  ushort_t* Bph = bcp;
  ushort_t* Bpl = bcp + MP;
  ushort_t* Cph = bcp + 2*MP;
  ushort_t* Cpl = bcp + 3*MP;

  // 1) in_proj conv-input columns
  {
    int nA4 = (M * H_SIZE) / 4;
    int nW  = CIN_DIM * H_SIZE;
    int nx = (CIN_DIM + 127) / 128;
    convert_hl_kernel<<<2048, 256, 0, stream>>>(hidden, hidhi, hidlo, nA4);
    convert_hl_kernel<<<2048, 256, 0, stream>>>(in_w + (size_t)INTER*H_SIZE, wscr, wscr + nW, nW/4);
    gemm_hl_mfma_kernel<<<nx * (M/128), 256, 0, stream>>>(
        hidhi, hidlo, wscr, wscr + nW, cin, M, CIN_DIM, H_SIZE, nx);
  }
  // 2) causal conv + SiLU; softplus(dt)
  conv_kernel<<<dim3(M), 256, 0, stream>>>(cin, conv_w, conv_b, dt_b, hbc, dtp);
  // 2.5) pre-split B/C slabs of hbc to bf16 hi/lo planes
  convert_bc_kernel<<<2048, 256, 0, stream>>>(hbc, Bph, Bpl, Cph, Cpl);
  // 3) per-chunk cumsum of dt*A
  cumsum_kernel<<<dim3(NC, NHEADS, BATCH), 256, 0, stream>>>(dtp, A_log, acum, gch);
  // 4) intra-chunk Yd + D*x -> y  (MFMA)
  yd_mfma_kernel<<<dim3(NHEADS, NC*4, BATCH), 256, 0, stream>>>(
      Bph, Bpl, Cph, Cpl, hbc, acum, dtp, Dv, y);
  // 5) chunk states -> st  (MFMA)
  states_mfma_kernel<<<dim3(NHEADS, NC, BATCH), 256, 0, stream>>>(
      Bph, Bpl, hbc, acum, dtp, st);
  // 6) inter-chunk scan; prev written as split-bf16 planes in place
  scan_kernel<<<dim3(BATCH*NHEADS), 256, 0, stream>>>(st, gch);
  // 7) inter-chunk Yo -> y (+=)  (MFMA)
  yo_mfma_kernel<<<dim3(NHEADS, NC, BATCH), 256, 0, stream>>>(
      Cph, Cpl, (const ushort_t*)st, acum, y);
  // 8) gate columns of in_proj
  {
    int nA4 = (M * H_SIZE) / 4;
    int nW  = INTER * H_SIZE;
    int nx = INTER / 128;
    convert_hl_kernel<<<2048, 256, 0, stream>>>(hidden, hidhi, hidlo, nA4);
    convert_hl_kernel<<<2048, 256, 0, stream>>>(in_w, wscr, wscr + nW, nW/4);
    gemm_hl_mfma_kernel<<<nx * (M/128), 256, 0, stream>>>(
        hidhi, hidlo, wscr, wscr + nW, gate, M, INTER, H_SIZE, nx);
  }
  // 9) gated RMSNorm in place on y
  rms_kernel<<<dim3(M), 256, 0, stream>>>(y, gate, norm_w);
  // 10) out_proj (weights staged in R, free now)
  {
    int nY4 = (M * INTER) / 4;
    int nW  = H_SIZE * INTER;
    int nx = H_SIZE / 128;
    ushort_t* whi2 = (ushort_t*)R;
    convert_hl_kernel<<<2048, 256, 0, stream>>>(y, yhi, ylo, nY4);
    convert_hl_kernel<<<2048, 256, 0, stream>>>(out_w, whi2, whi2 + nW, nW/4);
    gemm_hl_mfma_kernel<<<nx * (M/128), 256, 0, stream>>>(
        yhi, ylo, whi2, whi2 + nW, out, M, H_SIZE, INTER, nx);
  }
}

// Round 11
// 734.954 us; speedup vs baseline: 3.1751x; 1.1050x over previous
//
#include <hip/hip_runtime.h>
#include <hip/hip_bf16.h>
#include <math.h>

#define H_SIZE   1024
#define INTER    2048
#define NHEADS   32
#define HEAD_DIM 64
#define NSTATE   128
#define KCONV    4
#define CHUNK    256
#define CONV_DIM (INTER + 2*NSTATE)            // 2304
#define CIN_DIM  (CONV_DIM + NHEADS)           // 2336 (hBC + dt)
#define PROJ_DIM (2*INTER + 2*NSTATE + NHEADS) // 4384
#define BATCH    2
#define SEQ      4096
#define NC       (SEQ/CHUNK)                   // 16
#define EPS_F    1e-5f

typedef __attribute__((ext_vector_type(8))) short bf16x8;   // 8 bf16 in 4 VGPRs
typedef __attribute__((ext_vector_type(4))) float f32x4;
typedef unsigned short ushort_t;

__device__ __forceinline__ ushort_t f2bf(float x) {   // RNE float->bf16 bits
  unsigned u = __float_as_uint(x);
  u += 0x7fffu + ((u >> 16) & 1u);
  return (ushort_t)(u >> 16);
}
__device__ __forceinline__ float bf2f(ushort_t h) {
  return __uint_as_float((unsigned)h << 16);
}

// ---------------------------------------------------------------------------
// Split fp32 x into hi+lo bf16 planes: x ~= hi + lo (rel err ~2^-17).
// ---------------------------------------------------------------------------
__global__ __launch_bounds__(256) void convert_hl_kernel(
    const float* __restrict__ x, ushort_t* __restrict__ hi,
    ushort_t* __restrict__ lo, int n4) {
  int idx = blockIdx.x * 256 + threadIdx.x;
  int stride = gridDim.x * 256;
  for (int i = idx; i < n4; i += stride) {
    const float* p = x + (size_t)i * 4;
    float v0 = p[0], v1 = p[1], v2 = p[2], v3 = p[3];
    ushort_t h0 = f2bf(v0), h1 = f2bf(v1), h2 = f2bf(v2), h3 = f2bf(v3);
    ushort_t l0 = f2bf(v0 - bf2f(h0));
    ushort_t l1 = f2bf(v1 - bf2f(h1));
    ushort_t l2 = f2bf(v2 - bf2f(h2));
    ushort_t l3 = f2bf(v3 - bf2f(h3));
    *(uint2*)(hi + (size_t)i * 4) =
        make_uint2((unsigned)h0 | ((unsigned)h1 << 16), (unsigned)h2 | ((unsigned)h3 << 16));
    *(uint2*)(lo + (size_t)i * 4) =
        make_uint2((unsigned)l0 | ((unsigned)l1 << 16), (unsigned)l2 | ((unsigned)l3 << 16));
  }
}

// ---------------------------------------------------------------------------
// Pre-split the B (cols 2048..2176) and C (cols 2176..2304) slabs of hbc
// into bf16 hi/lo planes [M][128] each.
// ---------------------------------------------------------------------------
__global__ __launch_bounds__(256) void convert_bc_kernel(
    const float* __restrict__ hbc, ushort_t* __restrict__ Bph,
    ushort_t* __restrict__ Bpl, ushort_t* __restrict__ Cph,
    ushort_t* __restrict__ Cpl) {
  const int n4 = (BATCH*SEQ) * 64;
  int idx = blockIdx.x * 256 + threadIdx.x;
  int stride = gridDim.x * 256;
  for (int i = idx; i < n4; i += stride) {
    int row = i >> 6;
    int c4 = (i & 63) * 4;
    float4 v = *(const float4*)(hbc + (size_t)row*CONV_DIM + INTER + c4);
    ushort_t h0 = f2bf(v.x), h1 = f2bf(v.y), h2 = f2bf(v.z), h3 = f2bf(v.w);
    ushort_t l0 = f2bf(v.x - bf2f(h0)), l1 = f2bf(v.y - bf2f(h1));
    ushort_t l2 = f2bf(v.z - bf2f(h2)), l3 = f2bf(v.w - bf2f(h3));
    uint2 hp = make_uint2((unsigned)h0 | ((unsigned)h1 << 16), (unsigned)h2 | ((unsigned)h3 << 16));
    uint2 lp = make_uint2((unsigned)l0 | ((unsigned)l1 << 16), (unsigned)l2 | ((unsigned)l3 << 16));
    if (c4 < 128) {
      *(uint2*)(Bph + (size_t)row*128 + c4) = hp;
      *(uint2*)(Bpl + (size_t)row*128 + c4) = lp;
    } else {
      *(uint2*)(Cph + (size_t)row*128 + (c4 - 128)) = hp;
      *(uint2*)(Cpl + (size_t)row*128 + (c4 - 128)) = lp;
    }
  }
}

// ---------------------------------------------------------------------------
// C[m,n] = sum_k A[m,k]*W[n,k] via split-bf16 MFMA.
// PLANES=3: Ah*Wh + Ah*Wl + Al*Wh (rel err ~2^-17).
// PLANES=2: Ah*Wh + Ah*Wl        (rel err ~2^-9; A-lo never loaded).
// 128x128 tile, BK=32, 256 threads = 4 waves (2x2), wave tile 64x64.
// 1D grid, bijective XCD chunking + G=4 M-grouping (nwg%8==0, (M/128)%4==0).
// ---------------------------------------------------------------------------
#define LROW 40
template<int PLANES>
__global__ __launch_bounds__(256) void gemm_hl_mfma_kernel(
    const ushort_t* __restrict__ Ahi, const ushort_t* __restrict__ Alo,
    const ushort_t* __restrict__ Whi, const ushort_t* __restrict__ Wlo,
    float* __restrict__ C, int M, int N, int K, int nx) {
  __shared__ __align__(16) ushort_t Ah[128*LROW];
  __shared__ __align__(16) ushort_t Al[(PLANES==3) ? 128*LROW : 8];
  __shared__ __align__(16) ushort_t Wh[128*LROW], Wl[128*LROW];
  const int tid = threadIdx.x;
  const int lane = tid & 63, wid = tid >> 6;
  const int wr = wid >> 1, wc = wid & 1;
  const int fr = lane & 15, fg = lane >> 4;

  const int cpx = gridDim.x >> 3;
  const int logical = (blockIdx.x & 7) * cpx + (blockIdx.x >> 3);
  const int grp = logical / (nx * 4);
  const int rem = logical - grp * (nx * 4);
  const int bx = rem >> 2;
  const int by = grp * 4 + (rem & 3);
  const int m0 = by * 128, n0 = bx * 128;

  const int r0 = tid >> 2;
  const int kseg = (tid & 3) * 8;
  const int r1 = r0 + 64;
  const size_t a0 = (size_t)(m0 + r0) * K + kseg;
  const size_t a1 = (size_t)(m0 + r1) * K + kseg;
  const size_t w0 = (size_t)(n0 + r0) * K + kseg;
  const size_t w1 = (size_t)(n0 + r1) * K + kseg;
  const bool wv0 = (n0 + r0) < N, wv1 = (n0 + r1) < N;

  bf16x8 gA0, gA1, gAl0, gAl1, gW0, gW1, gWl0, gWl1;
  const bf16x8 z8 = {};
  f32x4 acc[4][4] = {};

  auto glod = [&](int k0) {
    gA0  = *(const bf16x8*)(Ahi + a0 + k0);
    gA1  = *(const bf16x8*)(Ahi + a1 + k0);
    if constexpr (PLANES == 3) {
      gAl0 = *(const bf16x8*)(Alo + a0 + k0);
      gAl1 = *(const bf16x8*)(Alo + a1 + k0);
    }
    gW0  = wv0 ? *(const bf16x8*)(Whi + w0 + k0) : z8;
    gW1  = wv1 ? *(const bf16x8*)(Whi + w1 + k0) : z8;
    gWl0 = wv0 ? *(const bf16x8*)(Wlo + w0 + k0) : z8;
    gWl1 = wv1 ? *(const bf16x8*)(Wlo + w1 + k0) : z8;
  };

  glod(0);
  for (int k0 = 0; k0 < K; k0 += 32) {
    __syncthreads();
    *(bf16x8*)&Ah[r0*LROW + kseg] = gA0;
    *(bf16x8*)&Ah[r1*LROW + kseg] = gA1;
    if constexpr (PLANES == 3) {
      *(bf16x8*)&Al[r0*LROW + kseg] = gAl0;
      *(bf16x8*)&Al[r1*LROW + kseg] = gAl1;
    }
    *(bf16x8*)&Wh[r0*LROW + kseg] = gW0;
    *(bf16x8*)&Wh[r1*LROW + kseg] = gW1;
    *(bf16x8*)&Wl[r0*LROW + kseg] = gWl0;
    *(bf16x8*)&Wl[r1*LROW + kseg] = gWl1;
    __syncthreads();
    if (k0 + 32 < K) glod(k0 + 32);

    bf16x8 wh[4], wl[4];
#pragma unroll
    for (int nf = 0; nf < 4; ++nf) {
      int off = (wc*64 + nf*16 + fr) * LROW + 8*fg;
      wh[nf] = *(const bf16x8*)&Wh[off];
      wl[nf] = *(const bf16x8*)&Wl[off];
    }
#pragma unroll
    for (int mf = 0; mf < 4; ++mf) {
      int aoff = (wr*64 + mf*16 + fr) * LROW + 8*fg;
      bf16x8 ah = *(const bf16x8*)&Ah[aoff];
      bf16x8 al;
      if constexpr (PLANES == 3) al = *(const bf16x8*)&Al[aoff];
#pragma unroll
      for (int nf = 0; nf < 4; ++nf) {
        acc[mf][nf] = __builtin_amdgcn_mfma_f32_16x16x32_bf16(ah, wh[nf], acc[mf][nf], 0, 0, 0);
        acc[mf][nf] = __builtin_amdgcn_mfma_f32_16x16x32_bf16(ah, wl[nf], acc[mf][nf], 0, 0, 0);
        if constexpr (PLANES == 3)
          acc[mf][nf] = __builtin_amdgcn_mfma_f32_16x16x32_bf16(al, wh[nf], acc[mf][nf], 0, 0, 0);
      }
    }
  }

#pragma unroll
  for (int mf = 0; mf < 4; ++mf)
#pragma unroll
    for (int nf = 0; nf < 4; ++nf) {
      int col = n0 + wc*64 + nf*16 + fr;
      if (col < N) {
        size_t base = (size_t)(m0 + wr*64 + mf*16 + fg*4) * N + col;
        f32x4 v = acc[mf][nf];
        C[base]               = v[0];
        C[base + (size_t)N]   = v[1];
        C[base + 2*(size_t)N] = v[2];
        C[base + 3*(size_t)N] = v[3];
      }
    }
}

// ---------------------------------------------------------------------------
// Causal depthwise conv (K=4) + bias + SiLU; softplus(dt + dt_bias).
// ---------------------------------------------------------------------------
__global__ __launch_bounds__(256) void conv_kernel(
    const float* __restrict__ cin, const float* __restrict__ cw,
    const float* __restrict__ cb, const float* __restrict__ dtb,
    float* __restrict__ hbc, float* __restrict__ dtp) {
  const int bs = blockIdx.x;
  const int b = bs / SEQ, s = bs % SEQ;
  const int tid = threadIdx.x;
  const float* base = cin + (size_t)b * SEQ * CIN_DIM;
  for (int c = tid; c < CONV_DIM; c += 256) {
    float acc = cb[c];
#pragma unroll
    for (int k = 0; k < KCONV; ++k) {
      int sp = s - (KCONV-1) + k;
      if (sp >= 0) acc = fmaf(cw[c*KCONV + k], base[(size_t)sp * CIN_DIM + c], acc);
    }
    acc = acc / (1.f + expf(-acc));  // silu
    hbc[(size_t)bs * CONV_DIM + c] = acc;
  }
  if (tid < NHEADS) {
    float d = cin[(size_t)bs * CIN_DIM + CONV_DIM + tid] + dtb[tid];
    d = (d > 20.f) ? d : log1pf(expf(d));   // softplus
    dtp[(size_t)bs * NHEADS + tid] = d;
  }
}

// ---------------------------------------------------------------------------
__global__ __launch_bounds__(256) void cumsum_kernel(
    const float* __restrict__ dtp, const float* __restrict__ A_log,
    float* __restrict__ acum, float* __restrict__ gch) {
  const int c = blockIdx.x, h = blockIdx.y, b = blockIdx.z;
  const int tid = threadIdx.x;
  __shared__ float sm[CHUNK];
  const float A = -expf(A_log[h]);
  const int s = c * CHUNK + tid;
  float a = dtp[(size_t)(b*SEQ + s)*NHEADS + h] * A;
  sm[tid] = a;
  __syncthreads();
  for (int off = 1; off < CHUNK; off <<= 1) {
    float v = 0.f;
    if (tid >= off) v = sm[tid - off];
    __syncthreads();
    sm[tid] += v;
    __syncthreads();
  }
  float ac = sm[tid];
  acum[((size_t)(b*NHEADS + h)*NC + c)*CHUNK + tid] = ac;
  if (tid == CHUNK-1) gch[(size_t)(b*NHEADS + h)*NC + c] = expf(ac);
}

// ---------------------------------------------------------------------------
// Yd (intra-chunk) via MFMA, per (b, c, lt, h). 4 waves, each a 16-row strip.
// C fragments in registers; B in LDS; X transposed+swizzled in LDS.
// ---------------------------------------------------------------------------
#define CBROW 136
#define XROW2 72
__global__ __launch_bounds__(256) void yd_mfma_kernel(
    const ushort_t* __restrict__ Bph, const ushort_t* __restrict__ Bpl,
    const ushort_t* __restrict__ Cph, const ushort_t* __restrict__ Cpl,
    const float* __restrict__ hbc, const float* __restrict__ acum,
    const float* __restrict__ dtp, const float* __restrict__ Dv,
    float* __restrict__ y) {
  __shared__ __align__(16) ushort_t BhS[64*CBROW], BlS[64*CBROW];
  __shared__ __align__(16) ushort_t XhS[64*XROW2], XlS[64*XROW2];
  __shared__ __align__(16) ushort_t GhS[4][16*XROW2], GlS[4][16*XROW2];
  __shared__ float acLs[64], acSs[64];

  const int h = blockIdx.x;
  const int c = blockIdx.y >> 2, lt = blockIdx.y & 3;
  const int b = blockIdx.z;
  const int tid = threadIdx.x;
  const int lane = tid & 63, w = tid >> 6;
  const int fr = lane & 15, fg = lane >> 4;

  const size_t seqbase = (size_t)(b*SEQ + c*CHUNK);
  const size_t acbase  = ((size_t)(b*NHEADS + h)*NC + c)*CHUNK;

  bf16x8 cfh[4], cfl[4];
  {
    const size_t cg = (seqbase + lt*64 + w*16 + fr) * 128;
#pragma unroll
    for (int ks = 0; ks < 4; ++ks) {
      int ko = ks*32 + fg*8;
      cfh[ks] = *(const bf16x8*)(Cph + cg + ko);
      cfl[ks] = *(const bf16x8*)(Cpl + cg + ko);
    }
  }
  if (tid < 64) acLs[tid] = acum[acbase + lt*64 + tid];

  f32x4 acc[4] = {};

  for (int st = 0; st <= lt; ++st) {
    __syncthreads();
    {
      const size_t g0 = (seqbase + st*64) * 128;
#pragma unroll
      for (int i = 0; i < 4; ++i) {
        int f = tid + 256*i; int r = f >> 4; int k8 = (f & 15) * 8;
        *(bf16x8*)&BhS[r*CBROW + k8] = *(const bf16x8*)(Bph + g0 + (size_t)r*128 + k8);
        *(bf16x8*)&BlS[r*CBROW + k8] = *(const bf16x8*)(Bpl + g0 + (size_t)r*128 + k8);
      }
    }
#pragma unroll
    for (int i = 0; i < 4; ++i) {
      int f = tid + 256*i; int s = f >> 4; int p0 = (f & 15) * 4;
      size_t row = seqbase + st*64 + s;
      float dtv = dtp[row*NHEADS + h];
      float4 xv = *(const float4*)(hbc + row*CONV_DIM + h*HEAD_DIM + p0);
      float vals[4] = {xv.x*dtv, xv.y*dtv, xv.z*dtv, xv.w*dtv};
#pragma unroll
      for (int j = 0; j < 4; ++j) {
        int p = p0 + j;
        int sw = s ^ (((p >> 2) & 7) << 3);
        ushort_t hh = f2bf(vals[j]);
        ushort_t ll = f2bf(vals[j] - bf2f(hh));
        XhS[p*XROW2 + sw] = hh;
        XlS[p*XROW2 + sw] = ll;
      }
    }
    if (tid < 64) acSs[tid] = acum[acbase + st*64 + tid];
    __syncthreads();

    f32x4 g[4] = {};
#pragma unroll
    for (int ks = 0; ks < 4; ++ks) {
      const int ko = ks*32 + fg*8;
#pragma unroll
      for (int nf = 0; nf < 4; ++nf) {
        const int rb = (nf*16 + fr) * CBROW + ko;
        bf16x8 bh = *(const bf16x8*)&BhS[rb];
        bf16x8 bl = *(const bf16x8*)&BlS[rb];
        g[nf] = __builtin_amdgcn_mfma_f32_16x16x32_bf16(cfh[ks], bh, g[nf], 0, 0, 0);
        g[nf] = __builtin_amdgcn_mfma_f32_16x16x32_bf16(cfh[ks], bl, g[nf], 0, 0, 0);
        g[nf] = __builtin_amdgcn_mfma_f32_16x16x32_bf16(cfl[ks], bh, g[nf], 0, 0, 0);
      }
    }
    {
      const bool full = (st < lt);
#pragma unroll
      for (int nf = 0; nf < 4; ++nf) {
        int sl = nf*16 + fr;
        float aS = acSs[sl];
#pragma unroll
        for (int r = 0; r < 4; ++r) {
          int ll = w*16 + fg*4 + r;
          float v = 0.f;
          if (full || ll >= sl) v = g[nf][r] * __expf(acLs[ll] - aS);
          ushort_t hh = f2bf(v);
          ushort_t lo2 = f2bf(v - bf2f(hh));
          GhS[w][(fg*4 + r)*XROW2 + sl] = hh;
          GlS[w][(fg*4 + r)*XROW2 + sl] = lo2;
        }
      }
    }
    __syncthreads();
#pragma unroll
    for (int ks = 0; ks < 2; ++ks) {
      const int ko = ks*32 + fg*8;
      bf16x8 gh = *(const bf16x8*)&GhS[w][fr*XROW2 + ko];
      bf16x8 gl = *(const bf16x8*)&GlS[w][fr*XROW2 + ko];
#pragma unroll
      for (int nf = 0; nf < 4; ++nf) {
        int p = nf*16 + fr;
        int kb = ko ^ (((p >> 2) & 7) << 3);
        bf16x8 xh = *(const bf16x8*)&XhS[p*XROW2 + kb];
        bf16x8 xl = *(const bf16x8*)&XlS[p*XROW2 + kb];
        acc[nf] = __builtin_amdgcn_mfma_f32_16x16x32_bf16(gh, xh, acc[nf], 0, 0, 0);
        acc[nf] = __builtin_amdgcn_mfma_f32_16x16x32_bf16(gh, xl, acc[nf], 0, 0, 0);
        acc[nf] = __builtin_amdgcn_mfma_f32_16x16x32_bf16(gl, xh, acc[nf], 0, 0, 0);
      }
    }
  }

  const float Dh = Dv[h];
#pragma unroll
  for (int nf = 0; nf < 4; ++nf) {
    int p = nf*16 + fr;
#pragma unroll
    for (int r = 0; r < 4; ++r) {
      size_t row = seqbase + lt*64 + w*16 + fg*4 + r;
      float xval = hbc[row*CONV_DIM + h*HEAD_DIM + p];
      y[row*INTER + h*HEAD_DIM + p] = acc[nf][r] + Dh * xval;
    }
  }
}

// ---------------------------------------------------------------------------
// states via MFMA, per (b,c,h): states[p,n] = sum_l X'[p,l]*B[l,n].
// ---------------------------------------------------------------------------
#define SXROW 72
__global__ __launch_bounds__(256) void states_mfma_kernel(
    const ushort_t* __restrict__ Bph, const ushort_t* __restrict__ Bpl,
    const float* __restrict__ hbc, const float* __restrict__ acum,
    const float* __restrict__ dtp, float* __restrict__ states) {
  __shared__ __align__(16) ushort_t XhS[64*SXROW], XlS[64*SXROW];   // [p][l]
  __shared__ __align__(16) ushort_t BhS[128*SXROW], BlS[128*SXROW]; // [n][l]
  const int h = blockIdx.x, c = blockIdx.y, b = blockIdx.z;
  const int tid = threadIdx.x;
  const int lane = tid & 63, w = tid >> 6;
  const int fr = lane & 15, fg = lane >> 4;
  const size_t seqbase = (size_t)(b*SEQ + c*CHUNK);
  const size_t acbase  = ((size_t)(b*NHEADS + h)*NC + c)*CHUNK;
  const float aclast = acum[acbase + CHUNK - 1];
  f32x4 acc[8] = {};

  for (int lt = 0; lt < 4; ++lt) {
    __syncthreads();
#pragma unroll
    for (int i = 0; i < 4; ++i) {
      int f = tid + 256*i; int l = f >> 4; int p0 = (f & 15) * 4;
      size_t row = seqbase + lt*64 + l;
      float mult = dtp[row*NHEADS + h] * __expf(aclast - acum[acbase + lt*64 + l]);
      float4 xv = *(const float4*)(hbc + row*CONV_DIM + h*HEAD_DIM + p0);
      float vals[4] = {xv.x*mult, xv.y*mult, xv.z*mult, xv.w*mult};
#pragma unroll
      for (int j = 0; j < 4; ++j) {
        int p = p0 + j;
        int sw = l ^ (((p >> 2) & 7) << 3);
        ushort_t hh = f2bf(vals[j]);
        XhS[p*SXROW + sw] = hh;
        XlS[p*SXROW + sw] = f2bf(vals[j] - bf2f(hh));
      }
    }
#pragma unroll
    for (int i = 0; i < 4; ++i) {
      int f = tid + 256*i; int l = f >> 4; int n8 = (f & 15) * 8;
      size_t g0 = (seqbase + lt*64 + l) * 128 + n8;
      bf16x8 bh = *(const bf16x8*)(Bph + g0);
      bf16x8 bl = *(const bf16x8*)(Bpl + g0);
#pragma unroll
      for (int j = 0; j < 8; ++j) {
        int n = n8 + j;
        int sw = l ^ (((n >> 2) & 7) << 3);
        BhS[n*SXROW + sw] = (ushort_t)bh[j];
        BlS[n*SXROW + sw] = (ushort_t)bl[j];
      }
    }
    __syncthreads();
#pragma unroll
    for (int ks = 0; ks < 2; ++ks) {
      const int ko = ks*32 + fg*8;
      const int pa = w*16 + fr;
      const int ka = ko ^ (((pa >> 2) & 7) << 3);
      bf16x8 ah = *(const bf16x8*)&XhS[pa*SXROW + ka];
      bf16x8 al = *(const bf16x8*)&XlS[pa*SXROW + ka];
#pragma unroll
      for (int nf = 0; nf < 8; ++nf) {
        const int nb = nf*16 + fr;
        const int kb = ko ^ (((nb >> 2) & 7) << 3);
        bf16x8 bh = *(const bf16x8*)&BhS[nb*SXROW + kb];
        bf16x8 bl = *(const bf16x8*)&BlS[nb*SXROW + kb];
        acc[nf] = __builtin_amdgcn_mfma_f32_16x16x32_bf16(ah, bh, acc[nf], 0, 0, 0);
        acc[nf] = __builtin_amdgcn_mfma_f32_16x16x32_bf16(ah, bl, acc[nf], 0, 0, 0);
        acc[nf] = __builtin_amdgcn_mfma_f32_16x16x32_bf16(al, bh, acc[nf], 0, 0, 0);
      }
    }
  }
  float* sp = states + ((size_t)(b*NC + c)*NHEADS + h)*HEAD_DIM*NSTATE;
#pragma unroll
  for (int nf = 0; nf < 8; ++nf) {
    int n = nf*16 + fr;
#pragma unroll
    for (int r = 0; r < 4; ++r) {
      int p = w*16 + fg*4 + r;
      sp[(size_t)p*NSTATE + n] = acc[nf][r];
    }
  }
}

// ---------------------------------------------------------------------------
// Inter-chunk scan, IN PLACE, 1024 threads (4x ILP vs 256). Writes the carry
// (state BEFORE chunk c) as split-bf16 hi/lo planes into the same 32KB block.
// Read-all -> barrier -> write within the single block per (b,h) is safe.
// ---------------------------------------------------------------------------
__global__ __launch_bounds__(1024) void scan_kernel(
    float* __restrict__ st, const float* __restrict__ g) {
  const int bh = blockIdx.x;
  const int b = bh >> 5, h = bh & 31;
  const int tid = threadIdx.x;
  float carry[8];
#pragma unroll
  for (int i = 0; i < 8; ++i) carry[i] = 0.f;
  for (int c = 0; c < NC; ++c) {
    const float gc = g[(size_t)(b*NHEADS + h)*NC + c];
    float* base = st + ((size_t)(b*NC + c)*NHEADS + h)*HEAD_DIM*NSTATE;
    ushort_t* ub = (ushort_t*)base;
    float sv[8];
#pragma unroll
    for (int i = 0; i < 8; ++i) sv[i] = base[i*1024 + tid];
    __syncthreads();
#pragma unroll
    for (int i = 0; i < 8; ++i) {
      int e = i*1024 + tid;
      ushort_t hh = f2bf(carry[i]);
      ub[e]        = hh;
      ub[8192 + e] = f2bf(carry[i] - bf2f(hh));
      carry[i] = fmaf(carry[i], gc, sv[i]);
    }
  }
}

// ---------------------------------------------------------------------------
// Yo via MFMA, per (b,c,h): y[l,p] += exp(acum[l]) * sum_n C[l,n]*prev[p,n].
// ---------------------------------------------------------------------------
#define PROW 136
__global__ __launch_bounds__(256) void yo_mfma_kernel(
    const ushort_t* __restrict__ Cph, const ushort_t* __restrict__ Cpl,
    const ushort_t* __restrict__ stp, const float* __restrict__ acum,
    float* __restrict__ y) {
  __shared__ __align__(16) ushort_t PhS[64*PROW], PlS[64*PROW];
  const int h = blockIdx.x, c = blockIdx.y, b = blockIdx.z;
  const int tid = threadIdx.x;
  const int lane = tid & 63, w = tid >> 6;
  const int fr = lane & 15, fg = lane >> 4;
  const size_t seqbase = (size_t)(b*SEQ + c*CHUNK);
  const size_t acbase  = ((size_t)(b*NHEADS + h)*NC + c)*CHUNK;

  const ushort_t* pb = stp + ((size_t)(b*NC + c)*NHEADS + h) * (size_t)(2*HEAD_DIM*NSTATE);
#pragma unroll
  for (int i = 0; i < 4; ++i) {
    int f = tid + 256*i; int r = f >> 4; int k8 = (f & 15) * 8;
    *(bf16x8*)&PhS[r*PROW + k8] = *(const bf16x8*)(pb + (size_t)r*128 + k8);
    *(bf16x8*)&PlS[r*PROW + k8] = *(const bf16x8*)(pb + 8192 + (size_t)r*128 + k8);
  }
  __syncthreads();

  for (int lt = 0; lt < 4; ++lt) {
    const size_t cg = (seqbase + lt*64 + w*16 + fr) * 128;
    f32x4 acc[4] = {};
#pragma unroll
    for (int ks = 0; ks < 4; ++ks) {
      int ko = ks*32 + fg*8;
      bf16x8 ah = *(const bf16x8*)(Cph + cg + ko);
      bf16x8 al = *(const bf16x8*)(Cpl + cg + ko);
#pragma unroll
      for (int nf = 0; nf < 4; ++nf) {
        const int rb = (nf*16 + fr) * PROW + ko;
        bf16x8 bh = *(const bf16x8*)&PhS[rb];
        bf16x8 bl = *(const bf16x8*)&PlS[rb];
        acc[nf] = __builtin_amdgcn_mfma_f32_16x16x32_bf16(ah, bh, acc[nf], 0, 0, 0);
        acc[nf] = __builtin_amdgcn_mfma_f32_16x16x32_bf16(ah, bl, acc[nf], 0, 0, 0);
        acc[nf] = __builtin_amdgcn_mfma_f32_16x16x32_bf16(al, bh, acc[nf], 0, 0, 0);
      }
    }
#pragma unroll
    for (int r = 0; r < 4; ++r) {
      int lrow = lt*64 + w*16 + fg*4 + r;
      float e = __expf(acum[acbase + lrow]);
      float* yrow = y + (seqbase + lrow)*INTER + h*HEAD_DIM;
#pragma unroll
      for (int nf = 0; nf < 4; ++nf) {
        int p = nf*16 + fr;
        yrow[p] += e * acc[nf][r];
      }
    }
  }
}

// ---------------------------------------------------------------------------
// Gated RMSNorm, FUSED output conversion: writes bf16-hi plane of the
// normalized result directly (consumed by the 2-plane out_proj GEMM).
// ---------------------------------------------------------------------------
__global__ __launch_bounds__(256) void rms_kernel(
    const float* __restrict__ y, const float* __restrict__ gate,
    const float* __restrict__ norm_w, ushort_t* __restrict__ yh) {
  const int bs = blockIdx.x;
  const int tid = threadIdx.x;
  const float* yrow = y + (size_t)bs * INTER;
  const float* grow = gate + (size_t)bs * INTER;
  float yf[8];
  float ss = 0.f;
#pragma unroll
  for (int i = 0; i < 8; ++i) {
    int c = tid + i*256;
    float v = yrow[c];
    float gt = grow[c];
    float f = v * (gt / (1.f + expf(-gt)));
    yf[i] = f;
    ss += f*f;
  }
#pragma unroll
  for (int off = 32; off >= 1; off >>= 1) ss += __shfl_xor(ss, off, 64);
  __shared__ float red[4];
  if ((tid & 63) == 0) red[tid >> 6] = ss;
  __syncthreads();
  float total = red[0] + red[1] + red[2] + red[3];
  float sc = rsqrtf(total * (1.f/INTER) + EPS_F);
#pragma unroll
  for (int i = 0; i < 8; ++i) {
    int c = tid + i*256;
    yh[(size_t)bs*INTER + c] = f2bf(norm_w[c] * yf[i] * sc);
  }
}

__global__ void zero_kernel(float* p, size_t n) {
  size_t i = (size_t)blockIdx.x * blockDim.x + threadIdx.x;
  if (i < n) p[i] = 0.f;
}

// ---------------------------------------------------------------------------
extern "C" void kernel_launch(void* const* d_in, const int* in_sizes, int n_in,
                              void* d_out, int out_size, void* d_ws, size_t ws_size,
                              hipStream_t stream) {
  const float* hidden = (const float*)d_in[0];
  const float* in_w   = (const float*)d_in[1];
  const float* conv_w = (const float*)d_in[2];
  const float* conv_b = (const float*)d_in[3];
  const float* dt_b   = (const float*)d_in[4];
  const float* A_log  = (const float*)d_in[5];
  const float* Dv     = (const float*)d_in[6];
  const float* norm_w = (const float*)d_in[7];
  const float* out_w  = (const float*)d_in[8];
  float* out = (float*)d_out;

  const int M = BATCH*SEQ;

  const size_t sz_cin  = (size_t)M * CIN_DIM;
  const size_t sz_hbc  = (size_t)M * CONV_DIM;
  const size_t sz_dtp  = (size_t)M * NHEADS;
  const size_t sz_acum = (size_t)BATCH*NHEADS*NC*CHUNK;
  const size_t sz_gch  = (size_t)BATCH*NHEADS*NC;
  const size_t sz_R    = (size_t)BATCH*NC*NHEADS*HEAD_DIM*NSTATE;
  const size_t need = (sz_cin + sz_hbc + sz_dtp + sz_acum + sz_gch + sz_R) * sizeof(float);

  if (ws_size < need) {
    size_t n = (size_t)out_size;
    zero_kernel<<<(unsigned)((n + 255) / 256), 256, 0, stream>>>(out, n);
    return;
  }

  float* ws = (float*)d_ws;
  size_t o = 0;
  float* cin  = ws + o; o += sz_cin;
  float* hbc  = ws + o; o += sz_hbc;
  float* dtp  = ws + o; o += sz_dtp;
  float* acum = ws + o; o += sz_acum;
  float* gch  = ws + o; o += sz_gch;
  float* R    = ws + o; o += sz_R;

  float* y    = cin;   // cin dead after conv_kernel
  float* gate = hbc;   // hbc dead after step 8 gemm output (gate IS hbc reuse)
  float* st   = R;     // R free between gemms

  ushort_t* hidhi = (ushort_t*)R;
  ushort_t* hidlo = hidhi + (size_t)M * H_SIZE;
  ushort_t* yhR   = (ushort_t*)R;        // rms output hi-plane (R dead after yo)
  ushort_t* wplh  = (ushort_t*)hbc;      // step-10 weight planes (hbc/gate dead after rms)

  // d_out scratch: weights at offset 0 (steps 1,8); B/C bf16 planes at +16MB
  ushort_t* wscr = (ushort_t*)out;
  const size_t MP = (size_t)M * 128;
  ushort_t* bcp  = (ushort_t*)((char*)d_out + (size_t)(16u << 20));
  ushort_t* Bph = bcp;
  ushort_t* Bpl = bcp + MP;
  ushort_t* Cph = bcp + 2*MP;
  ushort_t* Cpl = bcp + 3*MP;

  // 1) in_proj conv-input columns (3-plane: protects dt/decay accuracy)
  {
    int nA4 = (M * H_SIZE) / 4;
    int nW  = CIN_DIM * H_SIZE;
    int nx = (CIN_DIM + 127) / 128;
    convert_hl_kernel<<<2048, 256, 0, stream>>>(hidden, hidhi, hidlo, nA4);
    convert_hl_kernel<<<2048, 256, 0, stream>>>(in_w + (size_t)INTER*H_SIZE, wscr, wscr + nW, nW/4);
    gemm_hl_mfma_kernel<3><<<nx * (M/128), 256, 0, stream>>>(
        hidhi, hidlo, wscr, wscr + nW, cin, M, CIN_DIM, H_SIZE, nx);
  }
  // 2) causal conv + SiLU; softplus(dt)
  conv_kernel<<<dim3(M), 256, 0, stream>>>(cin, conv_w, conv_b, dt_b, hbc, dtp);
  // 2.5) pre-split B/C slabs of hbc to bf16 hi/lo planes
  convert_bc_kernel<<<2048, 256, 0, stream>>>(hbc, Bph, Bpl, Cph, Cpl);
  // 3) per-chunk cumsum of dt*A
  cumsum_kernel<<<dim3(NC, NHEADS, BATCH), 256, 0, stream>>>(dtp, A_log, acum, gch);
  // 4) intra-chunk Yd + D*x -> y  (MFMA)
  yd_mfma_kernel<<<dim3(NHEADS, NC*4, BATCH), 256, 0, stream>>>(
      Bph, Bpl, Cph, Cpl, hbc, acum, dtp, Dv, y);
  // 5) chunk states -> st  (MFMA)
  states_mfma_kernel<<<dim3(NHEADS, NC, BATCH), 256, 0, stream>>>(
      Bph, Bpl, hbc, acum, dtp, st);
  // 6) inter-chunk scan; prev written as split-bf16 planes in place
  scan_kernel<<<dim3(BATCH*NHEADS), 1024, 0, stream>>>(st, gch);
  // 7) inter-chunk Yo -> y (+=)  (MFMA)
  yo_mfma_kernel<<<dim3(NHEADS, NC, BATCH), 256, 0, stream>>>(
      Cph, Cpl, (const ushort_t*)st, acum, y);
  // 8) gate columns of in_proj (2-plane: pure linear path); st dead, reconvert hidden
  {
    int nA4 = (M * H_SIZE) / 4;
    int nW  = INTER * H_SIZE;
    int nx = INTER / 128;
    convert_hl_kernel<<<2048, 256, 0, stream>>>(hidden, hidhi, hidlo, nA4);
    convert_hl_kernel<<<2048, 256, 0, stream>>>(in_w, wscr, wscr + nW, nW/4);
    gemm_hl_mfma_kernel<2><<<nx * (M/128), 256, 0, stream>>>(
        hidhi, hidlo, wscr, wscr + nW, gate, M, INTER, H_SIZE, nx);
  }
  // 9) gated RMSNorm: y,gate -> bf16 hi plane in R (R dead after step 7)
  rms_kernel<<<dim3(M), 256, 0, stream>>>(y, gate, norm_w, yhR);
  // 10) out_proj (2-plane on A=yh; weight planes in hbc region, dead after rms)
  {
    int nW  = H_SIZE * INTER;
    convert_hl_kernel<<<2048, 256, 0, stream>>>(out_w, wplh, wplh + nW, nW/4);
    int nx = H_SIZE / 128;
    gemm_hl_mfma_kernel<2><<<nx * (M/128), 256, 0, stream>>>(
        yhR, yhR, wplh, wplh + nW, out, M, H_SIZE, INTER, nx);
  }
}

// Round 12
// 659.609 us; speedup vs baseline: 3.5378x; 1.1142x over previous
//
#include <hip/hip_runtime.h>
#include <hip/hip_bf16.h>
#include <math.h>

#define H_SIZE   1024
#define INTER    2048
#define NHEADS   32
#define HEAD_DIM 64
#define NSTATE   128
#define KCONV    4
#define CHUNK    256
#define CONV_DIM (INTER + 2*NSTATE)            // 2304
#define CIN_DIM  (CONV_DIM + NHEADS)           // 2336 (hBC + dt)
#define PROJ_DIM (2*INTER + 2*NSTATE + NHEADS) // 4384
#define BATCH    2
#define SEQ      4096
#define NC       (SEQ/CHUNK)                   // 16
#define EPS_F    1e-5f

typedef __attribute__((ext_vector_type(8))) short bf16x8;   // 8 bf16 in 4 VGPRs
typedef __attribute__((ext_vector_type(4))) float f32x4;
typedef unsigned short ushort_t;

__device__ __forceinline__ ushort_t f2bf(float x) {   // RNE float->bf16 bits
  unsigned u = __float_as_uint(x);
  u += 0x7fffu + ((u >> 16) & 1u);
  return (ushort_t)(u >> 16);
}
__device__ __forceinline__ float bf2f(ushort_t h) {
  return __uint_as_float((unsigned)h << 16);
}

// ---------------------------------------------------------------------------
// Split fp32 x into hi+lo bf16 planes: x ~= hi + lo (rel err ~2^-17).
// ---------------------------------------------------------------------------
__global__ __launch_bounds__(256) void convert_hl_kernel(
    const float* __restrict__ x, ushort_t* __restrict__ hi,
    ushort_t* __restrict__ lo, int n4) {
  int idx = blockIdx.x * 256 + threadIdx.x;
  int stride = gridDim.x * 256;
  for (int i = idx; i < n4; i += stride) {
    const float* p = x + (size_t)i * 4;
    float v0 = p[0], v1 = p[1], v2 = p[2], v3 = p[3];
    ushort_t h0 = f2bf(v0), h1 = f2bf(v1), h2 = f2bf(v2), h3 = f2bf(v3);
    ushort_t l0 = f2bf(v0 - bf2f(h0));
    ushort_t l1 = f2bf(v1 - bf2f(h1));
    ushort_t l2 = f2bf(v2 - bf2f(h2));
    ushort_t l3 = f2bf(v3 - bf2f(h3));
    *(uint2*)(hi + (size_t)i * 4) =
        make_uint2((unsigned)h0 | ((unsigned)h1 << 16), (unsigned)h2 | ((unsigned)h3 << 16));
    *(uint2*)(lo + (size_t)i * 4) =
        make_uint2((unsigned)l0 | ((unsigned)l1 << 16), (unsigned)l2 | ((unsigned)l3 << 16));
  }
}

// ---------------------------------------------------------------------------
// C[m,n] = sum_k A[m,k]*W[n,k] via split-bf16 MFMA.
// PLANES=3: Ah*Wh + Ah*Wl + Al*Wh (rel err ~2^-17).
// PLANES=2: Ah*Wh + Ah*Wl        (rel err ~2^-9; A-lo never loaded).
// 128x128 tile, BK=32, 256 threads = 4 waves (2x2), wave tile 64x64.
// 1D grid, bijective XCD chunking + G=4 M-grouping (nwg%8==0, (M/128)%4==0).
// Output stride ldc decoupled from logical N (for sliced outputs).
// ---------------------------------------------------------------------------
#define LROW 40
template<int PLANES>
__global__ __launch_bounds__(256) void gemm_hl_mfma_kernel(
    const ushort_t* __restrict__ Ahi, const ushort_t* __restrict__ Alo,
    const ushort_t* __restrict__ Whi, const ushort_t* __restrict__ Wlo,
    float* __restrict__ C, int M, int N, int K, int nx, int ldc) {
  __shared__ __align__(16) ushort_t Ah[128*LROW];
  __shared__ __align__(16) ushort_t Al[(PLANES==3) ? 128*LROW : 8];
  __shared__ __align__(16) ushort_t Wh[128*LROW], Wl[128*LROW];
  const int tid = threadIdx.x;
  const int lane = tid & 63, wid = tid >> 6;
  const int wr = wid >> 1, wc = wid & 1;
  const int fr = lane & 15, fg = lane >> 4;

  const int cpx = gridDim.x >> 3;
  const int logical = (blockIdx.x & 7) * cpx + (blockIdx.x >> 3);
  const int grp = logical / (nx * 4);
  const int rem = logical - grp * (nx * 4);
  const int bx = rem >> 2;
  const int by = grp * 4 + (rem & 3);
  const int m0 = by * 128, n0 = bx * 128;

  const int r0 = tid >> 2;
  const int kseg = (tid & 3) * 8;
  const int r1 = r0 + 64;
  const size_t a0 = (size_t)(m0 + r0) * K + kseg;
  const size_t a1 = (size_t)(m0 + r1) * K + kseg;
  const size_t w0 = (size_t)(n0 + r0) * K + kseg;
  const size_t w1 = (size_t)(n0 + r1) * K + kseg;
  const bool wv0 = (n0 + r0) < N, wv1 = (n0 + r1) < N;

  bf16x8 gA0, gA1, gAl0, gAl1, gW0, gW1, gWl0, gWl1;
  const bf16x8 z8 = {};
  f32x4 acc[4][4] = {};

  auto glod = [&](int k0) {
    gA0  = *(const bf16x8*)(Ahi + a0 + k0);
    gA1  = *(const bf16x8*)(Ahi + a1 + k0);
    if constexpr (PLANES == 3) {
      gAl0 = *(const bf16x8*)(Alo + a0 + k0);
      gAl1 = *(const bf16x8*)(Alo + a1 + k0);
    }
    gW0  = wv0 ? *(const bf16x8*)(Whi + w0 + k0) : z8;
    gW1  = wv1 ? *(const bf16x8*)(Whi + w1 + k0) : z8;
    gWl0 = wv0 ? *(const bf16x8*)(Wlo + w0 + k0) : z8;
    gWl1 = wv1 ? *(const bf16x8*)(Wlo + w1 + k0) : z8;
  };

  glod(0);
  for (int k0 = 0; k0 < K; k0 += 32) {
    __syncthreads();
    *(bf16x8*)&Ah[r0*LROW + kseg] = gA0;
    *(bf16x8*)&Ah[r1*LROW + kseg] = gA1;
    if constexpr (PLANES == 3) {
      *(bf16x8*)&Al[r0*LROW + kseg] = gAl0;
      *(bf16x8*)&Al[r1*LROW + kseg] = gAl1;
    }
    *(bf16x8*)&Wh[r0*LROW + kseg] = gW0;
    *(bf16x8*)&Wh[r1*LROW + kseg] = gW1;
    *(bf16x8*)&Wl[r0*LROW + kseg] = gWl0;
    *(bf16x8*)&Wl[r1*LROW + kseg] = gWl1;
    __syncthreads();
    if (k0 + 32 < K) glod(k0 + 32);

    bf16x8 wh[4], wl[4];
#pragma unroll
    for (int nf = 0; nf < 4; ++nf) {
      int off = (wc*64 + nf*16 + fr) * LROW + 8*fg;
      wh[nf] = *(const bf16x8*)&Wh[off];
      wl[nf] = *(const bf16x8*)&Wl[off];
    }
#pragma unroll
    for (int mf = 0; mf < 4; ++mf) {
      int aoff = (wr*64 + mf*16 + fr) * LROW + 8*fg;
      bf16x8 ah = *(const bf16x8*)&Ah[aoff];
      bf16x8 al;
      if constexpr (PLANES == 3) al = *(const bf16x8*)&Al[aoff];
#pragma unroll
      for (int nf = 0; nf < 4; ++nf) {
        acc[mf][nf] = __builtin_amdgcn_mfma_f32_16x16x32_bf16(ah, wh[nf], acc[mf][nf], 0, 0, 0);
        acc[mf][nf] = __builtin_amdgcn_mfma_f32_16x16x32_bf16(ah, wl[nf], acc[mf][nf], 0, 0, 0);
        if constexpr (PLANES == 3)
          acc[mf][nf] = __builtin_amdgcn_mfma_f32_16x16x32_bf16(al, wh[nf], acc[mf][nf], 0, 0, 0);
      }
    }
  }

#pragma unroll
  for (int mf = 0; mf < 4; ++mf)
#pragma unroll
    for (int nf = 0; nf < 4; ++nf) {
      int col = n0 + wc*64 + nf*16 + fr;
      if (col < N) {
        size_t base = (size_t)(m0 + wr*64 + mf*16 + fg*4) * ldc + col;
        f32x4 v = acc[mf][nf];
        C[base]                 = v[0];
        C[base + (size_t)ldc]   = v[1];
        C[base + 2*(size_t)ldc] = v[2];
        C[base + 3*(size_t)ldc] = v[3];
      }
    }
}

// ---------------------------------------------------------------------------
// Causal depthwise conv (K=4) + bias + SiLU, sliding-window (1.37x read).
// Thread owns channel c; 8-row tile. x channels (c<2048) -> hbc fp32;
// B/C channels (2048<=c<2304) -> bf16 hi/lo planes directly (fused split).
// cin stride CIN_DIM; hbc stride CONV_DIM.
// ---------------------------------------------------------------------------
__global__ __launch_bounds__(256) void conv2_kernel(
    const float* __restrict__ cin, const float* __restrict__ cw,
    const float* __restrict__ cb, float* __restrict__ hbc,
    ushort_t* __restrict__ Bph, ushort_t* __restrict__ Bpl,
    ushort_t* __restrict__ Cph, ushort_t* __restrict__ Cpl) {
  const int c = blockIdx.x * 256 + threadIdx.x;   // 0..2303
  const int r0 = blockIdx.y * 8;                  // global row tile base
  const int s0 = r0 & (SEQ - 1);                  // in-sequence position
  const float w0 = cw[c*KCONV+0], w1 = cw[c*KCONV+1];
  const float w2 = cw[c*KCONV+2], w3 = cw[c*KCONV+3];
  const float bias = cb[c];
  const float* cp = cin + (size_t)r0 * CIN_DIM + c;
  float xm3 = (s0 > 0) ? cp[-3*CIN_DIM] : 0.f;
  float xm2 = (s0 > 0) ? cp[-2*CIN_DIM] : 0.f;
  float xm1 = (s0 > 0) ? cp[-1*CIN_DIM] : 0.f;
#pragma unroll
  for (int i = 0; i < 8; ++i) {
    float x0 = cp[(size_t)i * CIN_DIM];
    float acc = fmaf(w0, xm3, fmaf(w1, xm2, fmaf(w2, xm1, fmaf(w3, x0, bias))));
    acc = acc / (1.f + expf(-acc));  // silu
    size_t row = (size_t)(r0 + i);
    if (c < INTER) {
      hbc[row*CONV_DIM + c] = acc;
    } else {
      ushort_t hh = f2bf(acc);
      ushort_t ll = f2bf(acc - bf2f(hh));
      int cc = c - INTER;
      if (cc < NSTATE) { Bph[row*NSTATE + cc] = hh; Bpl[row*NSTATE + cc] = ll; }
      else { Cph[row*NSTATE + (cc-NSTATE)] = hh; Cpl[row*NSTATE + (cc-NSTATE)] = ll; }
    }
    xm3 = xm2; xm2 = xm1; xm1 = x0;
  }
}

// ---------------------------------------------------------------------------
// Per (b,h,chunk): dt = softplus(cin_dt + dt_bias) -> dtp; a = dt*A;
// inclusive cumsum -> acum; g = exp(last).
// ---------------------------------------------------------------------------
__global__ __launch_bounds__(256) void cumsum_kernel(
    const float* __restrict__ cin, const float* __restrict__ A_log,
    const float* __restrict__ dtb, float* __restrict__ dtp,
    float* __restrict__ acum, float* __restrict__ gch) {
  const int c = blockIdx.x, h = blockIdx.y, b = blockIdx.z;
  const int tid = threadIdx.x;
  __shared__ float sm[CHUNK];
  const float A = -expf(A_log[h]);
  const int s = c * CHUNK + tid;
  const size_t row = (size_t)(b*SEQ + s);
  float draw = cin[row*CIN_DIM + CONV_DIM + h] + dtb[h];
  float d = (draw > 20.f) ? draw : log1pf(expf(draw));   // softplus
  dtp[row*NHEADS + h] = d;
  float a = d * A;
  sm[tid] = a;
  __syncthreads();
  for (int off = 1; off < CHUNK; off <<= 1) {
    float v = 0.f;
    if (tid >= off) v = sm[tid - off];
    __syncthreads();
    sm[tid] += v;
    __syncthreads();
  }
  float ac = sm[tid];
  acum[((size_t)(b*NHEADS + h)*NC + c)*CHUNK + tid] = ac;
  if (tid == CHUNK-1) gch[(size_t)(b*NHEADS + h)*NC + c] = expf(ac);
}

// ---------------------------------------------------------------------------
// Yd (intra-chunk) via MFMA, per (b, c, lt, h). 4 waves, each a 16-row strip.
// C fragments in registers; B in LDS; X transposed+swizzled in LDS.
// ---------------------------------------------------------------------------
#define CBROW 136
#define XROW2 72
__global__ __launch_bounds__(256) void yd_mfma_kernel(
    const ushort_t* __restrict__ Bph, const ushort_t* __restrict__ Bpl,
    const ushort_t* __restrict__ Cph, const ushort_t* __restrict__ Cpl,
    const float* __restrict__ hbc, const float* __restrict__ acum,
    const float* __restrict__ dtp, const float* __restrict__ Dv,
    float* __restrict__ y) {
  __shared__ __align__(16) ushort_t BhS[64*CBROW], BlS[64*CBROW];
  __shared__ __align__(16) ushort_t XhS[64*XROW2], XlS[64*XROW2];
  __shared__ __align__(16) ushort_t GhS[4][16*XROW2], GlS[4][16*XROW2];
  __shared__ float acLs[64], acSs[64];

  const int h = blockIdx.x;
  const int c = blockIdx.y >> 2, lt = blockIdx.y & 3;
  const int b = blockIdx.z;
  const int tid = threadIdx.x;
  const int lane = tid & 63, w = tid >> 6;
  const int fr = lane & 15, fg = lane >> 4;

  const size_t seqbase = (size_t)(b*SEQ + c*CHUNK);
  const size_t acbase  = ((size_t)(b*NHEADS + h)*NC + c)*CHUNK;

  bf16x8 cfh[4], cfl[4];
  {
    const size_t cg = (seqbase + lt*64 + w*16 + fr) * 128;
#pragma unroll
    for (int ks = 0; ks < 4; ++ks) {
      int ko = ks*32 + fg*8;
      cfh[ks] = *(const bf16x8*)(Cph + cg + ko);
      cfl[ks] = *(const bf16x8*)(Cpl + cg + ko);
    }
  }
  if (tid < 64) acLs[tid] = acum[acbase + lt*64 + tid];

  f32x4 acc[4] = {};

  for (int st = 0; st <= lt; ++st) {
    __syncthreads();
    {
      const size_t g0 = (seqbase + st*64) * 128;
#pragma unroll
      for (int i = 0; i < 4; ++i) {
        int f = tid + 256*i; int r = f >> 4; int k8 = (f & 15) * 8;
        *(bf16x8*)&BhS[r*CBROW + k8] = *(const bf16x8*)(Bph + g0 + (size_t)r*128 + k8);
        *(bf16x8*)&BlS[r*CBROW + k8] = *(const bf16x8*)(Bpl + g0 + (size_t)r*128 + k8);
      }
    }
#pragma unroll
    for (int i = 0; i < 4; ++i) {
      int f = tid + 256*i; int s = f >> 4; int p0 = (f & 15) * 4;
      size_t row = seqbase + st*64 + s;
      float dtv = dtp[row*NHEADS + h];
      float4 xv = *(const float4*)(hbc + row*CONV_DIM + h*HEAD_DIM + p0);
      float vals[4] = {xv.x*dtv, xv.y*dtv, xv.z*dtv, xv.w*dtv};
#pragma unroll
      for (int j = 0; j < 4; ++j) {
        int p = p0 + j;
        int sw = s ^ (((p >> 2) & 7) << 3);
        ushort_t hh = f2bf(vals[j]);
        ushort_t ll = f2bf(vals[j] - bf2f(hh));
        XhS[p*XROW2 + sw] = hh;
        XlS[p*XROW2 + sw] = ll;
      }
    }
    if (tid < 64) acSs[tid] = acum[acbase + st*64 + tid];
    __syncthreads();

    f32x4 g[4] = {};
#pragma unroll
    for (int ks = 0; ks < 4; ++ks) {
      const int ko = ks*32 + fg*8;
#pragma unroll
      for (int nf = 0; nf < 4; ++nf) {
        const int rb = (nf*16 + fr) * CBROW + ko;
        bf16x8 bh = *(const bf16x8*)&BhS[rb];
        bf16x8 bl = *(const bf16x8*)&BlS[rb];
        g[nf] = __builtin_amdgcn_mfma_f32_16x16x32_bf16(cfh[ks], bh, g[nf], 0, 0, 0);
        g[nf] = __builtin_amdgcn_mfma_f32_16x16x32_bf16(cfh[ks], bl, g[nf], 0, 0, 0);
        g[nf] = __builtin_amdgcn_mfma_f32_16x16x32_bf16(cfl[ks], bh, g[nf], 0, 0, 0);
      }
    }
    {
      const bool full = (st < lt);
#pragma unroll
      for (int nf = 0; nf < 4; ++nf) {
        int sl = nf*16 + fr;
        float aS = acSs[sl];
#pragma unroll
        for (int r = 0; r < 4; ++r) {
          int ll = w*16 + fg*4 + r;
          float v = 0.f;
          if (full || ll >= sl) v = g[nf][r] * __expf(acLs[ll] - aS);
          ushort_t hh = f2bf(v);
          ushort_t lo2 = f2bf(v - bf2f(hh));
          GhS[w][(fg*4 + r)*XROW2 + sl] = hh;
          GlS[w][(fg*4 + r)*XROW2 + sl] = lo2;
        }
      }
    }
    __syncthreads();
#pragma unroll
    for (int ks = 0; ks < 2; ++ks) {
      const int ko = ks*32 + fg*8;
      bf16x8 gh = *(const bf16x8*)&GhS[w][fr*XROW2 + ko];
      bf16x8 gl = *(const bf16x8*)&GlS[w][fr*XROW2 + ko];
#pragma unroll
      for (int nf = 0; nf < 4; ++nf) {
        int p = nf*16 + fr;
        int kb = ko ^ (((p >> 2) & 7) << 3);
        bf16x8 xh = *(const bf16x8*)&XhS[p*XROW2 + kb];
        bf16x8 xl = *(const bf16x8*)&XlS[p*XROW2 + kb];
        acc[nf] = __builtin_amdgcn_mfma_f32_16x16x32_bf16(gh, xh, acc[nf], 0, 0, 0);
        acc[nf] = __builtin_amdgcn_mfma_f32_16x16x32_bf16(gh, xl, acc[nf], 0, 0, 0);
        acc[nf] = __builtin_amdgcn_mfma_f32_16x16x32_bf16(gl, xh, acc[nf], 0, 0, 0);
      }
    }
  }

  const float Dh = Dv[h];
#pragma unroll
  for (int nf = 0; nf < 4; ++nf) {
    int p = nf*16 + fr;
#pragma unroll
    for (int r = 0; r < 4; ++r) {
      size_t row = seqbase + lt*64 + w*16 + fg*4 + r;
      float xval = hbc[row*CONV_DIM + h*HEAD_DIM + p];
      y[row*INTER + h*HEAD_DIM + p] = acc[nf][r] + Dh * xval;
    }
  }
}

// ---------------------------------------------------------------------------
// states via MFMA, per (b,c,h): states[p,n] = sum_l X'[p,l]*B[l,n].
// ---------------------------------------------------------------------------
#define SXROW 72
__global__ __launch_bounds__(256) void states_mfma_kernel(
    const ushort_t* __restrict__ Bph, const ushort_t* __restrict__ Bpl,
    const float* __restrict__ hbc, const float* __restrict__ acum,
    const float* __restrict__ dtp, float* __restrict__ states) {
  __shared__ __align__(16) ushort_t XhS[64*SXROW], XlS[64*SXROW];   // [p][l]
  __shared__ __align__(16) ushort_t BhS[128*SXROW], BlS[128*SXROW]; // [n][l]
  const int h = blockIdx.x, c = blockIdx.y, b = blockIdx.z;
  const int tid = threadIdx.x;
  const int lane = tid & 63, w = tid >> 6;
  const int fr = lane & 15, fg = lane >> 4;
  const size_t seqbase = (size_t)(b*SEQ + c*CHUNK);
  const size_t acbase  = ((size_t)(b*NHEADS + h)*NC + c)*CHUNK;
  const float aclast = acum[acbase + CHUNK - 1];
  f32x4 acc[8] = {};

  for (int lt = 0; lt < 4; ++lt) {
    __syncthreads();
#pragma unroll
    for (int i = 0; i < 4; ++i) {
      int f = tid + 256*i; int l = f >> 4; int p0 = (f & 15) * 4;
      size_t row = seqbase + lt*64 + l;
      float mult = dtp[row*NHEADS + h] * __expf(aclast - acum[acbase + lt*64 + l]);
      float4 xv = *(const float4*)(hbc + row*CONV_DIM + h*HEAD_DIM + p0);
      float vals[4] = {xv.x*mult, xv.y*mult, xv.z*mult, xv.w*mult};
#pragma unroll
      for (int j = 0; j < 4; ++j) {
        int p = p0 + j;
        int sw = l ^ (((p >> 2) & 7) << 3);
        ushort_t hh = f2bf(vals[j]);
        XhS[p*SXROW + sw] = hh;
        XlS[p*SXROW + sw] = f2bf(vals[j] - bf2f(hh));
      }
    }
#pragma unroll
    for (int i = 0; i < 4; ++i) {
      int f = tid + 256*i; int l = f >> 4; int n8 = (f & 15) * 8;
      size_t g0 = (seqbase + lt*64 + l) * 128 + n8;
      bf16x8 bh = *(const bf16x8*)(Bph + g0);
      bf16x8 bl = *(const bf16x8*)(Bpl + g0);
#pragma unroll
      for (int j = 0; j < 8; ++j) {
        int n = n8 + j;
        int sw = l ^ (((n >> 2) & 7) << 3);
        BhS[n*SXROW + sw] = (ushort_t)bh[j];
        BlS[n*SXROW + sw] = (ushort_t)bl[j];
      }
    }
    __syncthreads();
#pragma unroll
    for (int ks = 0; ks < 2; ++ks) {
      const int ko = ks*32 + fg*8;
      const int pa = w*16 + fr;
      const int ka = ko ^ (((pa >> 2) & 7) << 3);
      bf16x8 ah = *(const bf16x8*)&XhS[pa*SXROW + ka];
      bf16x8 al = *(const bf16x8*)&XlS[pa*SXROW + ka];
#pragma unroll
      for (int nf = 0; nf < 8; ++nf) {
        const int nb = nf*16 + fr;
        const int kb = ko ^ (((nb >> 2) & 7) << 3);
        bf16x8 bh = *(const bf16x8*)&BhS[nb*SXROW + kb];
        bf16x8 bl = *(const bf16x8*)&BlS[nb*SXROW + kb];
        acc[nf] = __builtin_amdgcn_mfma_f32_16x16x32_bf16(ah, bh, acc[nf], 0, 0, 0);
        acc[nf] = __builtin_amdgcn_mfma_f32_16x16x32_bf16(ah, bl, acc[nf], 0, 0, 0);
        acc[nf] = __builtin_amdgcn_mfma_f32_16x16x32_bf16(al, bh, acc[nf], 0, 0, 0);
      }
    }
  }
  float* sp = states + ((size_t)(b*NC + c)*NHEADS + h)*HEAD_DIM*NSTATE;
#pragma unroll
  for (int nf = 0; nf < 8; ++nf) {
    int n = nf*16 + fr;
#pragma unroll
    for (int r = 0; r < 4; ++r) {
      int p = w*16 + fg*4 + r;
      sp[(size_t)p*NSTATE + n] = acc[nf][r];
    }
  }
}

// ---------------------------------------------------------------------------
// Inter-chunk scan, IN PLACE, 1024 threads. Writes the carry (state BEFORE
// chunk c) as split-bf16 hi/lo planes into the same 32KB block.
// ---------------------------------------------------------------------------
__global__ __launch_bounds__(1024) void scan_kernel(
    float* __restrict__ st, const float* __restrict__ g) {
  const int bh = blockIdx.x;
  const int b = bh >> 5, h = bh & 31;
  const int tid = threadIdx.x;
  float carry[8];
#pragma unroll
  for (int i = 0; i < 8; ++i) carry[i] = 0.f;
  for (int c = 0; c < NC; ++c) {
    const float gc = g[(size_t)(b*NHEADS + h)*NC + c];
    float* base = st + ((size_t)(b*NC + c)*NHEADS + h)*HEAD_DIM*NSTATE;
    ushort_t* ub = (ushort_t*)base;
    float sv[8];
#pragma unroll
    for (int i = 0; i < 8; ++i) sv[i] = base[i*1024 + tid];
    __syncthreads();
#pragma unroll
    for (int i = 0; i < 8; ++i) {
      int e = i*1024 + tid;
      ushort_t hh = f2bf(carry[i]);
      ub[e]        = hh;
      ub[8192 + e] = f2bf(carry[i] - bf2f(hh));
      carry[i] = fmaf(carry[i], gc, sv[i]);
    }
  }
}

// ---------------------------------------------------------------------------
// Yo via MFMA, per (b,c,h): y[l,p] += exp(acum[l]) * sum_n C[l,n]*prev[p,n].
// ---------------------------------------------------------------------------
#define PROW 136
__global__ __launch_bounds__(256) void yo_mfma_kernel(
    const ushort_t* __restrict__ Cph, const ushort_t* __restrict__ Cpl,
    const ushort_t* __restrict__ stp, const float* __restrict__ acum,
    float* __restrict__ y) {
  __shared__ __align__(16) ushort_t PhS[64*PROW], PlS[64*PROW];
  const int h = blockIdx.x, c = blockIdx.y, b = blockIdx.z;
  const int tid = threadIdx.x;
  const int lane = tid & 63, w = tid >> 6;
  const int fr = lane & 15, fg = lane >> 4;
  const size_t seqbase = (size_t)(b*SEQ + c*CHUNK);
  const size_t acbase  = ((size_t)(b*NHEADS + h)*NC + c)*CHUNK;

  const ushort_t* pb = stp + ((size_t)(b*NC + c)*NHEADS + h) * (size_t)(2*HEAD_DIM*NSTATE);
#pragma unroll
  for (int i = 0; i < 4; ++i) {
    int f = tid + 256*i; int r = f >> 4; int k8 = (f & 15) * 8;
    *(bf16x8*)&PhS[r*PROW + k8] = *(const bf16x8*)(pb + (size_t)r*128 + k8);
    *(bf16x8*)&PlS[r*PROW + k8] = *(const bf16x8*)(pb + 8192 + (size_t)r*128 + k8);
  }
  __syncthreads();

  for (int lt = 0; lt < 4; ++lt) {
    const size_t cg = (seqbase + lt*64 + w*16 + fr) * 128;
    f32x4 acc[4] = {};
#pragma unroll
    for (int ks = 0; ks < 4; ++ks) {
      int ko = ks*32 + fg*8;
      bf16x8 ah = *(const bf16x8*)(Cph + cg + ko);
      bf16x8 al = *(const bf16x8*)(Cpl + cg + ko);
#pragma unroll
      for (int nf = 0; nf < 4; ++nf) {
        const int rb = (nf*16 + fr) * PROW + ko;
        bf16x8 bh = *(const bf16x8*)&PhS[rb];
        bf16x8 bl = *(const bf16x8*)&PlS[rb];
        acc[nf] = __builtin_amdgcn_mfma_f32_16x16x32_bf16(ah, bh, acc[nf], 0, 0, 0);
        acc[nf] = __builtin_amdgcn_mfma_f32_16x16x32_bf16(ah, bl, acc[nf], 0, 0, 0);
        acc[nf] = __builtin_amdgcn_mfma_f32_16x16x32_bf16(al, bh, acc[nf], 0, 0, 0);
      }
    }
#pragma unroll
    for (int r = 0; r < 4; ++r) {
      int lrow = lt*64 + w*16 + fg*4 + r;
      float e = __expf(acum[acbase + lrow]);
      float* yrow = y + (seqbase + lrow)*INTER + h*HEAD_DIM;
#pragma unroll
      for (int nf = 0; nf < 4; ++nf) {
        int p = nf*16 + fr;
        yrow[p] += e * acc[nf][r];
      }
    }
  }
}

// ---------------------------------------------------------------------------
// Gated RMSNorm, FUSED output conversion: writes bf16-hi plane of the
// normalized result directly (consumed by the 2-plane out_proj GEMM).
// ---------------------------------------------------------------------------
__global__ __launch_bounds__(256) void rms_kernel(
    const float* __restrict__ y, const float* __restrict__ gate,
    const float* __restrict__ norm_w, ushort_t* __restrict__ yh) {
  const int bs = blockIdx.x;
  const int tid = threadIdx.x;
  const float* yrow = y + (size_t)bs * INTER;
  const float* grow = gate + (size_t)bs * INTER;
  float yf[8];
  float ss = 0.f;
#pragma unroll
  for (int i = 0; i < 8; ++i) {
    int c = tid + i*256;
    float v = yrow[c];
    float gt = grow[c];
    float f = v * (gt / (1.f + expf(-gt)));
    yf[i] = f;
    ss += f*f;
  }
#pragma unroll
  for (int off = 32; off >= 1; off >>= 1) ss += __shfl_xor(ss, off, 64);
  __shared__ float red[4];
  if ((tid & 63) == 0) red[tid >> 6] = ss;
  __syncthreads();
  float total = red[0] + red[1] + red[2] + red[3];
  float sc = rsqrtf(total * (1.f/INTER) + EPS_F);
#pragma unroll
  for (int i = 0; i < 8; ++i) {
    int c = tid + i*256;
    yh[(size_t)bs*INTER + c] = f2bf(norm_w[c] * yf[i] * sc);
  }
}

__global__ void zero_kernel(float* p, size_t n) {
  size_t i = (size_t)blockIdx.x * blockDim.x + threadIdx.x;
  if (i < n) p[i] = 0.f;
}

// ---------------------------------------------------------------------------
extern "C" void kernel_launch(void* const* d_in, const int* in_sizes, int n_in,
                              void* d_out, int out_size, void* d_ws, size_t ws_size,
                              hipStream_t stream) {
  const float* hidden = (const float*)d_in[0];
  const float* in_w   = (const float*)d_in[1];
  const float* conv_w = (const float*)d_in[2];
  const float* conv_b = (const float*)d_in[3];
  const float* dt_b   = (const float*)d_in[4];
  const float* A_log  = (const float*)d_in[5];
  const float* Dv     = (const float*)d_in[6];
  const float* norm_w = (const float*)d_in[7];
  const float* out_w  = (const float*)d_in[8];
  float* out = (float*)d_out;

  const int M = BATCH*SEQ;

  const size_t sz_cin  = (size_t)M * CIN_DIM;
  const size_t sz_hbc  = (size_t)M * CONV_DIM;
  const size_t sz_dtp  = (size_t)M * NHEADS;
  const size_t sz_acum = (size_t)BATCH*NHEADS*NC*CHUNK;
  const size_t sz_gch  = (size_t)BATCH*NHEADS*NC;
  const size_t sz_R    = (size_t)BATCH*NC*NHEADS*HEAD_DIM*NSTATE;
  const size_t need = (sz_cin + sz_hbc + sz_dtp + sz_acum + sz_gch + sz_R) * sizeof(float);

  if (ws_size < need) {
    size_t n = (size_t)out_size;
    zero_kernel<<<(unsigned)((n + 255) / 256), 256, 0, stream>>>(out, n);
    return;
  }

  float* ws = (float*)d_ws;
  size_t o = 0;
  float* cin  = ws + o; o += sz_cin;
  float* hbc  = ws + o; o += sz_hbc;
  float* dtp  = ws + o; o += sz_dtp;
  float* acum = ws + o; o += sz_acum;
  float* gch  = ws + o; o += sz_gch;
  float* R    = ws + o; o += sz_R;

  float* y    = cin;   // cin dead (as conv input) after conv2
  float* gate = hbc;   // hbc x-slab dead after yo; gate reuses region
  float* st   = R;

  ushort_t* hidhi = (ushort_t*)R;
  ushort_t* hidlo = hidhi + (size_t)M * H_SIZE;
  ushort_t* yhR   = (ushort_t*)R;        // rms output hi-plane (R dead after yo)
  ushort_t* wplh  = (ushort_t*)hbc;      // step-10 weight planes (hbc dead after rms)

  // d_out scratch: weights at offset 0 (steps 1,8); B/C bf16 planes at +16MB
  ushort_t* wscr = (ushort_t*)out;
  const size_t MP = (size_t)M * 128;
  ushort_t* bcp  = (ushort_t*)((char*)d_out + (size_t)(16u << 20));
  ushort_t* Bph = bcp;
  ushort_t* Bpl = bcp + MP;
  ushort_t* Cph = bcp + 2*MP;
  ushort_t* Cpl = bcp + 3*MP;

  // 1) in_proj conv-input columns, precision routed per consumer:
  //    x slab (N=2048, linear path)  -> 2-plane
  //    B/C + dt slab (N=288)         -> 3-plane (dt feeds exp chains)
  {
    int nA4 = (M * H_SIZE) / 4;
    int nW  = CIN_DIM * H_SIZE;                  // 2336 rows of weights
    convert_hl_kernel<<<2048, 256, 0, stream>>>(hidden, hidhi, hidlo, nA4);
    convert_hl_kernel<<<2048, 256, 0, stream>>>(in_w + (size_t)INTER*H_SIZE, wscr, wscr + nW, nW/4);
    gemm_hl_mfma_kernel<2><<<16 * (M/128), 256, 0, stream>>>(
        hidhi, hidlo, wscr, wscr + nW, cin, M, 2048, H_SIZE, 16, CIN_DIM);
    gemm_hl_mfma_kernel<3><<<3 * (M/128), 256, 0, stream>>>(
        hidhi, hidlo, wscr + (size_t)2048*H_SIZE, wscr + nW + (size_t)2048*H_SIZE,
        cin + 2048, M, 288, H_SIZE, 3, CIN_DIM);
  }
  // 2) causal conv + SiLU (sliding window); B/C planes fused in epilogue
  conv2_kernel<<<dim3(CONV_DIM/256, M/8), 256, 0, stream>>>(
      cin, conv_w, conv_b, hbc, Bph, Bpl, Cph, Cpl);
  // 3) softplus(dt)+cumsum (reads raw dt from cin tail cols)
  cumsum_kernel<<<dim3(NC, NHEADS, BATCH), 256, 0, stream>>>(
      cin, A_log, dt_b, dtp, acum, gch);
  // 4) intra-chunk Yd + D*x -> y  (MFMA)
  yd_mfma_kernel<<<dim3(NHEADS, NC*4, BATCH), 256, 0, stream>>>(
      Bph, Bpl, Cph, Cpl, hbc, acum, dtp, Dv, y);
  // 5) chunk states -> st  (MFMA)
  states_mfma_kernel<<<dim3(NHEADS, NC, BATCH), 256, 0, stream>>>(
      Bph, Bpl, hbc, acum, dtp, st);
  // 6) inter-chunk scan; prev written as split-bf16 planes in place
  scan_kernel<<<dim3(BATCH*NHEADS), 1024, 0, stream>>>(st, gch);
  // 7) inter-chunk Yo -> y (+=)  (MFMA)
  yo_mfma_kernel<<<dim3(NHEADS, NC, BATCH), 256, 0, stream>>>(
      Cph, Cpl, (const ushort_t*)st, acum, y);
  // 8) gate columns of in_proj (2-plane); st dead, reconvert hidden into R
  {
    int nA4 = (M * H_SIZE) / 4;
    int nW  = INTER * H_SIZE;
    convert_hl_kernel<<<2048, 256, 0, stream>>>(hidden, hidhi, hidlo, nA4);
    convert_hl_kernel<<<2048, 256, 0, stream>>>(in_w, wscr, wscr + nW, nW/4);
    gemm_hl_mfma_kernel<2><<<16 * (M/128), 256, 0, stream>>>(
        hidhi, hidlo, wscr, wscr + nW, gate, M, INTER, H_SIZE, 16, INTER);
  }
  // 9) gated RMSNorm: y,gate -> bf16 hi plane in R
  rms_kernel<<<dim3(M), 256, 0, stream>>>(y, gate, norm_w, yhR);
  // 10) out_proj (2-plane on A=yh; weight planes in hbc region)
  {
    int nW  = H_SIZE * INTER;
    convert_hl_kernel<<<2048, 256, 0, stream>>>(out_w, wplh, wplh + nW, nW/4);
    gemm_hl_mfma_kernel<2><<<8 * (M/128), 256, 0, stream>>>(
        yhR, yhR, wplh, wplh + nW, out, M, H_SIZE, INTER, 8, H_SIZE);
  }
}